// Round 3
// baseline (6277.071 us; speedup 1.0000x reference)
//
#include <hip/hip_runtime.h>
#include <hip/hip_bf16.h>

// EGNN layer (CamadaEquivariante), round 3:
//  - pre_kernel: per-node Hr = h@We1[0:64]+b1, Hc = h@We1[64:128]  (hoists 26 GFLOP
//    of per-edge work into a 3.3 GFLOP node GEMM).
//  - edge kernel: thread-per-edge, NO LDS, fully-unrolled register MLP;
//    streams m_ij (bf16) + trans (f32). No atomics.
//  - CSR build per launch: histogram -> chunked shfl scan -> scatter perm.
//  - agg kernel: one wave per node via CSR.
//  - node kernel: thread-per-node, fully-unrolled register MLPs, no LDS.
// Fallback to atomic path if ws_size too small.

__device__ __forceinline__ float fast_tanh(float x) {
    float e = __expf(2.0f * x);
    return 1.0f - 2.0f * __builtin_amdgcn_rcpf(e + 1.0f);
}

// ------------------------------------------------------------- precompute ---
template<int BLK>
__global__ __launch_bounds__(BLK, 2)
void pre_kernel(const float* __restrict__ h,
                const float* __restrict__ we_w1, const float* __restrict__ we_b1,
                float* __restrict__ Hr, float* __restrict__ Hc, int N)
{
    const int n = blockIdx.x * BLK + threadIdx.x;
    if (n >= N) return;
    const float* hn = h + (size_t)n * 64;

    float hv[64];
    #pragma unroll
    for (int k = 0; k < 64; k++) hv[k] = hn[k];

    float A[64];
    // Hr = h @ We1[0:64] + b1   (bias folded here)
    #pragma unroll
    for (int j = 0; j < 64; j++) A[j] = we_b1[j];
    #pragma unroll
    for (int k = 0; k < 64; k++) {
        const float a = hv[k];
        const float* w = we_w1 + k * 64;
        #pragma unroll
        for (int j = 0; j < 64; j++) A[j] += a * w[j];
    }
    {
        float* o = Hr + (size_t)n * 64;
        #pragma unroll
        for (int j = 0; j < 64; j++) o[j] = A[j];
    }
    // Hc = h @ We1[64:128]
    #pragma unroll
    for (int j = 0; j < 64; j++) A[j] = 0.0f;
    #pragma unroll
    for (int k = 0; k < 64; k++) {
        const float a = hv[k];
        const float* w = we_w1 + (64 + k) * 64;
        #pragma unroll
        for (int j = 0; j < 64; j++) A[j] += a * w[j];
    }
    {
        float* o = Hc + (size_t)n * 64;
        #pragma unroll
        for (int j = 0; j < 64; j++) o[j] = A[j];
    }
}

// ---------------------------------------------------------------- edge MLP ---
template<int BLK>
__global__ __launch_bounds__(BLK, 2)
void edge_fast_kernel(const float* __restrict__ x,
                      const float* __restrict__ eattr,
                      const int* __restrict__ rows, const int* __restrict__ cols,
                      const float* __restrict__ Hr, const float* __restrict__ Hc,
                      const float* __restrict__ we_w1,   // rows 128..136 used
                      const float* __restrict__ we_w2, const float* __restrict__ we_b2,
                      const float* __restrict__ wx_w1, const float* __restrict__ wx_b1,
                      const float* __restrict__ wx_w2, const float* __restrict__ wx_b2,
                      __hip_bfloat16* __restrict__ mij, float* __restrict__ trans,
                      int E)
{
    const int e = blockIdx.x * BLK + threadIdx.x;
    if (e >= E) return;

    const int r = rows[e];
    const int c = cols[e];

    const float d0 = x[(size_t)r*3+0] - x[(size_t)c*3+0];
    const float d1 = x[(size_t)r*3+1] - x[(size_t)c*3+1];
    const float d2 = x[(size_t)r*3+2] - x[(size_t)c*3+2];
    const float rad = d0*d0 + d1*d1 + d2*d2;

    const float* hrp = Hr + (size_t)r * 64;
    const float* hcp = Hc + (size_t)c * 64;
    const float* wrad = we_w1 + 128 * 64;

    float A[64];
    #pragma unroll
    for (int j = 0; j < 64; j++) A[j] = hrp[j] + hcp[j] + rad * wrad[j];

    const float* ea = eattr + (size_t)e * 8;
    #pragma unroll
    for (int k = 0; k < 8; k++) {
        const float a = ea[k];
        const float* w = we_w1 + (129 + k) * 64;
        #pragma unroll
        for (int j = 0; j < 64; j++) A[j] += a * w[j];
    }
    #pragma unroll
    for (int j = 0; j < 64; j++) A[j] = fast_tanh(A[j]);

    // ---- phi_e layer 2: m_ij = tanh(A @ we_w2 + b2), full unroll, regs only ----
    float B[64];
    #pragma unroll
    for (int j = 0; j < 64; j++) B[j] = we_b2[j];
    #pragma unroll
    for (int k = 0; k < 64; k++) {
        const float a = A[k];
        const float* w = we_w2 + k * 64;
        #pragma unroll
        for (int j = 0; j < 64; j++) B[j] += a * w[j];
    }
    #pragma unroll
    for (int j = 0; j < 64; j++) B[j] = fast_tanh(B[j]);   // B = m_ij

    // stream m_ij as bf16
    {
        __hip_bfloat162* mo = (__hip_bfloat162*)(mij + (size_t)e * 64);
        #pragma unroll
        for (int jj = 0; jj < 32; jj++) {
            __hip_bfloat162 p;
            p.x = __float2bfloat16(B[2*jj]);
            p.y = __float2bfloat16(B[2*jj+1]);
            mo[jj] = p;
        }
    }

    // ---- phi_x layer 1: tanh(m_ij @ wx_w1 + bx1) ----
    #pragma unroll
    for (int j = 0; j < 64; j++) A[j] = wx_b1[j];
    #pragma unroll
    for (int k = 0; k < 64; k++) {
        const float a = B[k];
        const float* w = wx_w1 + k * 64;
        #pragma unroll
        for (int j = 0; j < 64; j++) A[j] += a * w[j];
    }
    // ---- phi_x layer 2: scalar ----
    float px = wx_b2[0];
    #pragma unroll
    for (int j = 0; j < 64; j++) px += fast_tanh(A[j]) * wx_w2[j];
    px = fast_tanh(px);

    trans[(size_t)e*3+0] = d0 * px;
    trans[(size_t)e*3+1] = d1 * px;
    trans[(size_t)e*3+2] = d2 * px;
}

// ------------------------------------------- fallback edge kernel (atomics) ---
template<int BLK>
__global__ __launch_bounds__(BLK)
void edge_atomic_kernel(const float* __restrict__ h, const float* __restrict__ x,
                 const float* __restrict__ eattr,
                 const int* __restrict__ rows, const int* __restrict__ cols,
                 const float* __restrict__ we_w1, const float* __restrict__ we_b1,
                 const float* __restrict__ we_w2, const float* __restrict__ we_b2,
                 const float* __restrict__ wx_w1, const float* __restrict__ wx_b1,
                 const float* __restrict__ wx_w2, const float* __restrict__ wx_b2,
                 float* __restrict__ agg, float* __restrict__ cnt, float* __restrict__ mi,
                 int E)
{
    __shared__ float act[64][BLK];
    const int tid = threadIdx.x;
    const int e = blockIdx.x * BLK + tid;
    if (e >= E) return;

    const int r = rows[e];
    const int c = cols[e];
    const float d0 = x[(size_t)r*3+0] - x[(size_t)c*3+0];
    const float d1 = x[(size_t)r*3+1] - x[(size_t)c*3+1];
    const float d2 = x[(size_t)r*3+2] - x[(size_t)c*3+2];
    const float rad = d0*d0 + d1*d1 + d2*d2;

    float A[64];
    #pragma unroll
    for (int j = 0; j < 64; j++) A[j] = we_b1[j];
    const float* hr = h + (size_t)r * 64;
    const float* hc = h + (size_t)c * 64;
    #pragma unroll 4
    for (int k = 0; k < 64; k++) {
        const float a0 = hr[k];
        const float a1 = hc[k];
        const float* w0 = we_w1 + k * 64;
        const float* w1 = we_w1 + (64 + k) * 64;
        #pragma unroll
        for (int j = 0; j < 64; j++) A[j] += a0 * w0[j] + a1 * w1[j];
    }
    {
        const float* w = we_w1 + 128 * 64;
        #pragma unroll
        for (int j = 0; j < 64; j++) A[j] += rad * w[j];
    }
    const float* ea = eattr + (size_t)e * 8;
    #pragma unroll
    for (int k = 0; k < 8; k++) {
        const float a = ea[k];
        const float* w = we_w1 + (129 + k) * 64;
        #pragma unroll
        for (int j = 0; j < 64; j++) A[j] += a * w[j];
    }
    #pragma unroll
    for (int j = 0; j < 64; j++) act[j][tid] = fast_tanh(A[j]);

    float B[64];
    #pragma unroll
    for (int j = 0; j < 64; j++) B[j] = we_b2[j];
    #pragma unroll 4
    for (int k = 0; k < 64; k++) {
        const float a = act[k][tid];
        const float* w = we_w2 + k * 64;
        #pragma unroll
        for (int j = 0; j < 64; j++) B[j] += a * w[j];
    }
    #pragma unroll
    for (int j = 0; j < 64; j++) act[j][tid] = fast_tanh(B[j]);

    #pragma unroll
    for (int j = 0; j < 64; j++) A[j] = wx_b1[j];
    #pragma unroll 4
    for (int k = 0; k < 64; k++) {
        const float a = act[k][tid];
        const float* w = wx_w1 + k * 64;
        #pragma unroll
        for (int j = 0; j < 64; j++) A[j] += a * w[j];
    }
    float px = wx_b2[0];
    #pragma unroll
    for (int j = 0; j < 64; j++) px += fast_tanh(A[j]) * wx_w2[j];
    px = fast_tanh(px);

    atomicAdd(&agg[(size_t)r*3+0], d0 * px);
    atomicAdd(&agg[(size_t)r*3+1], d1 * px);
    atomicAdd(&agg[(size_t)r*3+2], d2 * px);
    atomicAdd(&cnt[r], 1.0f);
    float* mir = mi + (size_t)r * 64;
    #pragma unroll
    for (int j = 0; j < 64; j++) atomicAdd(&mir[j], act[j][tid]);
}

// ---------------------------------------------------------------- CSR build ---
__global__ void hist_kernel(const int* __restrict__ rows, int* __restrict__ hist, int E) {
    int e = blockIdx.x * blockDim.x + threadIdx.x;
    if (e < E) atomicAdd(&hist[rows[e]], 1);
}

__global__ __launch_bounds__(1024)
void scan_kernel(const int* __restrict__ hist, int* __restrict__ offs,
                 int* __restrict__ cursor, int N) {
    // chunk-per-thread serial sum -> block scan (wave shfl + LDS) -> write back
    const int tid = threadIdx.x;
    const int chunk = (N + 1023) / 1024;
    const int beg = tid * chunk;
    const int end = (beg + chunk < N) ? beg + chunk : N;

    int s = 0;
    for (int i = beg; i < end; i++) s += hist[i];

    __shared__ int wsum[16];
    const int lane = tid & 63, wid = tid >> 6;
    int inc = s;
    #pragma unroll
    for (int off = 1; off < 64; off <<= 1) {
        int t = __shfl_up(inc, off, 64);
        if (lane >= off) inc += t;
    }
    if (lane == 63) wsum[wid] = inc;
    __syncthreads();
    if (wid == 0 && lane < 16) {
        int v = wsum[lane];
        #pragma unroll
        for (int off = 1; off < 16; off <<= 1) {
            int t = __shfl_up(v, off, 64);
            if (lane >= off) v += t;
        }
        wsum[lane] = v;
    }
    __syncthreads();
    const int wbase = (wid > 0) ? wsum[wid - 1] : 0;
    int run = wbase + inc - s;      // exclusive prefix of this chunk
    for (int i = beg; i < end; i++) {
        cursor[i] = run;
        run += hist[i];
        offs[i + 1] = run;
    }
    if (tid == 0) offs[0] = 0;
}

__global__ void scatter_kernel(const int* __restrict__ rows, int* __restrict__ cursor,
                               int* __restrict__ perm, int E) {
    int e = blockIdx.x * blockDim.x + threadIdx.x;
    if (e < E) {
        int p = atomicAdd(&cursor[rows[e]], 1);
        perm[p] = e;
    }
}

// ------------------------------------------------------------- aggregation ---
__global__ __launch_bounds__(256)
void agg_kernel(const __hip_bfloat16* __restrict__ mij, const float* __restrict__ trans,
                const int* __restrict__ offs, const int* __restrict__ perm,
                float* __restrict__ mi, float* __restrict__ agg, int N)
{
    const int lane = threadIdx.x & 63;
    const int n = blockIdx.x * 4 + (threadIdx.x >> 6);
    if (n >= N) return;

    int beg = __builtin_amdgcn_readfirstlane(offs[n]);
    int end = __builtin_amdgcn_readfirstlane(offs[n + 1]);

    float msum = 0.0f;
    float tsum = 0.0f;
    for (int i = beg; i < end; i++) {
        const int e = perm[i];                       // wave-uniform
        msum += __bfloat162float(mij[(size_t)e * 64 + lane]);
        if (lane < 3) tsum += trans[(size_t)e * 3 + lane];
    }
    mi[(size_t)n * 64 + lane] = msum;
    if (lane < 3) {
        const float cf = (float)(end - beg);
        agg[(size_t)n * 3 + lane] = tsum / fmaxf(cf, 1.0f);  // mean
    }
}

// -------------------------------------------------------------- node update ---
template<int BLK, bool AGG_IS_MEAN>
__global__ __launch_bounds__(BLK, 2)
void node_kernel(const float* __restrict__ h, const float* __restrict__ x,
                 const float* __restrict__ vel,
                 const float* __restrict__ wh_w1, const float* __restrict__ wh_b1,
                 const float* __restrict__ wh_w2, const float* __restrict__ wh_b2,
                 const float* __restrict__ wv_w1, const float* __restrict__ wv_b1,
                 const float* __restrict__ wv_w2, const float* __restrict__ wv_b2,
                 const float* __restrict__ agg, const float* __restrict__ cnt,
                 const float* __restrict__ mi,
                 float* __restrict__ out_h, float* __restrict__ out_x, float* __restrict__ out_v,
                 int N)
{
    const int n = blockIdx.x * BLK + threadIdx.x;
    if (n >= N) return;

    const float* hn = h + (size_t)n * 64;
    const float* mn = mi + (size_t)n * 64;

    float A[64];

    // ---- phi_v: tanh(h @ wv_w1 + b1) @ wv_w2 + b2   (NO outer tanh) ----
    #pragma unroll
    for (int j = 0; j < 64; j++) A[j] = wv_b1[j];
    #pragma unroll
    for (int k = 0; k < 64; k++) {
        const float a = hn[k];
        const float* w = wv_w1 + k * 64;
        #pragma unroll
        for (int j = 0; j < 64; j++) A[j] += a * w[j];
    }
    float pv = wv_b2[0];
    #pragma unroll
    for (int j = 0; j < 64; j++) pv += fast_tanh(A[j]) * wv_w2[j];

    // ---- phi_h layer 1: tanh([h, m_i] @ wh_w1 + b1) ----
    #pragma unroll
    for (int j = 0; j < 64; j++) A[j] = wh_b1[j];
    #pragma unroll
    for (int k = 0; k < 64; k++) {
        const float a0 = hn[k];
        const float a1 = mn[k];
        const float* w0 = wh_w1 + k * 64;
        const float* w1 = wh_w1 + (64 + k) * 64;
        #pragma unroll
        for (int j = 0; j < 64; j++) A[j] += a0 * w0[j] + a1 * w1[j];
    }
    #pragma unroll
    for (int j = 0; j < 64; j++) A[j] = fast_tanh(A[j]);

    // ---- phi_h layer 2: A @ wh_w2 + b2   (NO outer tanh) ----
    float B[64];
    #pragma unroll
    for (int j = 0; j < 64; j++) B[j] = wh_b2[j];
    #pragma unroll
    for (int k = 0; k < 64; k++) {
        const float a = A[k];
        const float* w = wh_w2 + k * 64;
        #pragma unroll
        for (int j = 0; j < 64; j++) B[j] += a * w[j];
    }
    float* oh = out_h + (size_t)n * 64;
    #pragma unroll
    for (int j = 0; j < 64; j++) oh[j] = B[j];

    // ---- coordinate / velocity update ----
    float inv = 1.0f;
    if (!AGG_IS_MEAN) inv = 1.0f / fmaxf(cnt[n], 1.0f);
    #pragma unroll
    for (int d = 0; d < 3; d++) {
        const float am = agg[(size_t)n*3 + d] * inv;
        const float vn = vel[(size_t)n*3 + d] * pv + am;
        out_v[(size_t)n*3 + d] = vn;
        out_x[(size_t)n*3 + d] = x[(size_t)n*3 + d] + vn;
    }
}

// ------------------------------------------------------------------ launch ---
extern "C" void kernel_launch(void* const* d_in, const int* in_sizes, int n_in,
                              void* d_out, int out_size, void* d_ws, size_t ws_size,
                              hipStream_t stream) {
    const float* h      = (const float*)d_in[0];
    const float* x      = (const float*)d_in[1];
    const float* vel    = (const float*)d_in[2];
    const float* eattr  = (const float*)d_in[3];
    const float* we_w1  = (const float*)d_in[4];
    const float* we_b1  = (const float*)d_in[5];
    const float* we_w2  = (const float*)d_in[6];
    const float* we_b2  = (const float*)d_in[7];
    const float* wx_w1  = (const float*)d_in[8];
    const float* wx_b1  = (const float*)d_in[9];
    const float* wx_w2  = (const float*)d_in[10];
    const float* wx_b2  = (const float*)d_in[11];
    const float* wh_w1  = (const float*)d_in[12];
    const float* wh_b1  = (const float*)d_in[13];
    const float* wh_w2  = (const float*)d_in[14];
    const float* wh_b2  = (const float*)d_in[15];
    const float* wv_w1  = (const float*)d_in[16];
    const float* wv_b1  = (const float*)d_in[17];
    const float* wv_w2  = (const float*)d_in[18];
    const float* wv_b2  = (const float*)d_in[19];
    const int*   ar     = (const int*)d_in[20];

    const int N = in_sizes[0] / 64;
    const int E = in_sizes[20] / 2;
    const int* rows = ar;
    const int* cols = ar + E;

    float* out_h = (float*)d_out;            // N*64
    float* out_x = out_h + (size_t)N * 64;   // N*3
    float* out_v = out_x + (size_t)N * 3;    // N*3

    // --- workspace layout (streaming path) ---
    char* p = (char*)d_ws;
    __hip_bfloat16* mij = (__hip_bfloat16*)p;  p += (size_t)E * 64 * sizeof(__hip_bfloat16);
    float* trans = (float*)p;                  p += (size_t)E * 3 * sizeof(float);
    float* mi    = (float*)p;                  p += (size_t)N * 64 * sizeof(float);
    float* agg   = (float*)p;                  p += (size_t)N * 3 * sizeof(float);
    float* Hr    = (float*)p;                  p += (size_t)N * 64 * sizeof(float);
    float* Hc    = (float*)p;                  p += (size_t)N * 64 * sizeof(float);
    int*   offs  = (int*)p;                    p += (size_t)(N + 1) * sizeof(int);
    int*   cursor= (int*)p;                    p += (size_t)N * sizeof(int);
    int*   hist  = (int*)p;                    p += (size_t)N * sizeof(int);
    int*   perm  = (int*)p;                    p += (size_t)E * sizeof(int);
    const size_t needed = (size_t)(p - (char*)d_ws);

    if (ws_size >= needed) {
        hipMemsetAsync(hist, 0, (size_t)N * sizeof(int), stream);
        hist_kernel<<<(E + 255) / 256, 256, 0, stream>>>(rows, hist, E);
        scan_kernel<<<1, 1024, 0, stream>>>(hist, offs, cursor, N);
        scatter_kernel<<<(E + 255) / 256, 256, 0, stream>>>(rows, cursor, perm, E);

        pre_kernel<256><<<(N + 255) / 256, 256, 0, stream>>>(h, we_w1, we_b1, Hr, Hc, N);

        edge_fast_kernel<256><<<(E + 255) / 256, 256, 0, stream>>>(
            x, eattr, rows, cols, Hr, Hc,
            we_w1, we_w2, we_b2,
            wx_w1, wx_b1, wx_w2, wx_b2,
            mij, trans, E);

        agg_kernel<<<(N + 3) / 4, 256, 0, stream>>>(mij, trans, offs, perm, mi, agg, N);

        node_kernel<256, true><<<(N + 255) / 256, 256, 0, stream>>>(
            h, x, vel,
            wh_w1, wh_b1, wh_w2, wh_b2,
            wv_w1, wv_b1, wv_w2, wv_b2,
            agg, nullptr, mi, out_h, out_x, out_v, N);
    } else {
        // --- fallback: atomic path ---
        float* agg2 = (float*)d_ws;               // N*3
        float* cnt2 = agg2 + (size_t)N * 3;       // N
        float* mi2  = cnt2 + N;                   // N*64
        hipMemsetAsync(d_ws, 0, (size_t)N * 68 * sizeof(float), stream);

        edge_atomic_kernel<128><<<(E + 127) / 128, 128, 0, stream>>>(
            h, x, eattr, rows, cols,
            we_w1, we_b1, we_w2, we_b2,
            wx_w1, wx_b1, wx_w2, wx_b2,
            agg2, cnt2, mi2, E);

        node_kernel<128, false><<<(N + 127) / 128, 128, 0, stream>>>(
            h, x, vel,
            wh_w1, wh_b1, wh_w2, wh_b2,
            wv_w1, wv_b1, wv_w2, wv_b2,
            agg2, cnt2, mi2, out_h, out_x, out_v, N);
    }
}

// Round 4
// 2105.263 us; speedup vs baseline: 2.9816x; 2.9816x over previous
//
#include <hip/hip_runtime.h>
#include <hip/hip_bf16.h>

// EGNN layer (CamadaEquivariante), round 4:
//  - pre_kernel: Hr = h@We1[0:64]+b1 (f32, stored in d_out's out_h region as scratch),
//    Hc = h@We1[64:128] (bf16 in ws).  Hoists 26 GFLOP of per-edge work.
//  - edge kernel: thread-per-edge, NO LDS, fully-unrolled register MLP;
//    streams m_ij (bf16) + px (f32). No atomics.
//  - CSR build per launch: histogram -> chunked shfl scan (3 barriers) -> scatter perm.
//  - agg kernel: one wave per node via CSR; recomputes d = x[n]-x[cols[e]].
//  - node kernel: thread-per-node, fully-unrolled register MLPs, no LDS;
//    overwrites the Hr scratch region with the real out_h at the end.
// Workspace total: 258.4 MB (fits 256 MiB). Fallback to atomic path if ws too small.

__device__ __forceinline__ float fast_tanh(float x) {
    float e = __expf(2.0f * x);
    return 1.0f - 2.0f * __builtin_amdgcn_rcpf(e + 1.0f);
}

__device__ __forceinline__ float bf16lo(unsigned u) { return __uint_as_float(u << 16); }
__device__ __forceinline__ float bf16hi(unsigned u) { return __uint_as_float(u & 0xffff0000u); }

// ------------------------------------------------------------- precompute ---
template<int BLK>
__global__ __launch_bounds__(BLK, 2)
void pre_kernel(const float* __restrict__ h,
                const float* __restrict__ we_w1, const float* __restrict__ we_b1,
                float* __restrict__ Hr, __hip_bfloat16* __restrict__ Hc, int N)
{
    const int n = blockIdx.x * BLK + threadIdx.x;
    if (n >= N) return;

    float hv[64];
    {
        const float4* h4 = (const float4*)(h + (size_t)n * 64);
        #pragma unroll
        for (int q = 0; q < 16; q++) {
            float4 v = h4[q];
            hv[4*q+0] = v.x; hv[4*q+1] = v.y; hv[4*q+2] = v.z; hv[4*q+3] = v.w;
        }
    }

    float A[64];
    // Hr = h @ We1[0:64] + b1  (bias folded)
    #pragma unroll
    for (int j = 0; j < 64; j++) A[j] = we_b1[j];
    #pragma unroll
    for (int k = 0; k < 64; k++) {
        const float a = hv[k];
        const float* w = we_w1 + k * 64;
        #pragma unroll
        for (int j = 0; j < 64; j++) A[j] += a * w[j];
    }
    {
        float4* o = (float4*)(Hr + (size_t)n * 64);
        #pragma unroll
        for (int q = 0; q < 16; q++) o[q] = make_float4(A[4*q], A[4*q+1], A[4*q+2], A[4*q+3]);
    }
    // Hc = h @ We1[64:128]  -> bf16
    #pragma unroll
    for (int j = 0; j < 64; j++) A[j] = 0.0f;
    #pragma unroll
    for (int k = 0; k < 64; k++) {
        const float a = hv[k];
        const float* w = we_w1 + (64 + k) * 64;
        #pragma unroll
        for (int j = 0; j < 64; j++) A[j] += a * w[j];
    }
    {
        __hip_bfloat162* o = (__hip_bfloat162*)(Hc + (size_t)n * 64);
        #pragma unroll
        for (int q = 0; q < 32; q++) {
            __hip_bfloat162 p;
            p.x = __float2bfloat16(A[2*q]);
            p.y = __float2bfloat16(A[2*q+1]);
            o[q] = p;
        }
    }
}

// ---------------------------------------------------------------- edge MLP ---
template<int BLK>
__global__ __launch_bounds__(BLK, 2)
void edge_fast_kernel(const float* __restrict__ x,
                      const float* __restrict__ eattr,
                      const int* __restrict__ rows, const int* __restrict__ cols,
                      const float* __restrict__ Hr, const __hip_bfloat16* __restrict__ Hc,
                      const float* __restrict__ we_w1,   // rows 128..136 used
                      const float* __restrict__ we_w2, const float* __restrict__ we_b2,
                      const float* __restrict__ wx_w1, const float* __restrict__ wx_b1,
                      const float* __restrict__ wx_w2, const float* __restrict__ wx_b2,
                      __hip_bfloat16* __restrict__ mij, float* __restrict__ px_out,
                      int E)
{
    const int e = blockIdx.x * BLK + threadIdx.x;
    if (e >= E) return;

    const int r = rows[e];
    const int c = cols[e];

    const float d0 = x[(size_t)r*3+0] - x[(size_t)c*3+0];
    const float d1 = x[(size_t)r*3+1] - x[(size_t)c*3+1];
    const float d2 = x[(size_t)r*3+2] - x[(size_t)c*3+2];
    const float rad = d0*d0 + d1*d1 + d2*d2;

    float A[64];
    // init from Hr (f32, vectorized)
    {
        const float4* hr4 = (const float4*)(Hr + (size_t)r * 64);
        #pragma unroll
        for (int q = 0; q < 16; q++) {
            float4 v = hr4[q];
            A[4*q+0] = v.x; A[4*q+1] = v.y; A[4*q+2] = v.z; A[4*q+3] = v.w;
        }
    }
    // add Hc (bf16, vectorized: 8 x uint4 = 64 bf16)
    {
        const uint4* hc4 = (const uint4*)(Hc + (size_t)c * 64);
        #pragma unroll
        for (int q = 0; q < 8; q++) {
            uint4 u = hc4[q];
            A[8*q+0] += bf16lo(u.x); A[8*q+1] += bf16hi(u.x);
            A[8*q+2] += bf16lo(u.y); A[8*q+3] += bf16hi(u.y);
            A[8*q+4] += bf16lo(u.z); A[8*q+5] += bf16hi(u.z);
            A[8*q+6] += bf16lo(u.w); A[8*q+7] += bf16hi(u.w);
        }
    }
    // + rad * w_rad   (row 128)
    {
        const float* w = we_w1 + 128 * 64;
        #pragma unroll
        for (int j = 0; j < 64; j++) A[j] += rad * w[j];
    }
    // + eattr @ W[129:137]
    {
        const float4* ea4 = (const float4*)(eattr + (size_t)e * 8);
        float ea[8];
        float4 v0 = ea4[0], v1 = ea4[1];
        ea[0]=v0.x; ea[1]=v0.y; ea[2]=v0.z; ea[3]=v0.w;
        ea[4]=v1.x; ea[5]=v1.y; ea[6]=v1.z; ea[7]=v1.w;
        #pragma unroll
        for (int k = 0; k < 8; k++) {
            const float a = ea[k];
            const float* w = we_w1 + (129 + k) * 64;
            #pragma unroll
            for (int j = 0; j < 64; j++) A[j] += a * w[j];
        }
    }
    #pragma unroll
    for (int j = 0; j < 64; j++) A[j] = fast_tanh(A[j]);

    // ---- phi_e layer 2: m_ij = tanh(A @ we_w2 + b2) ----
    float B[64];
    #pragma unroll
    for (int j = 0; j < 64; j++) B[j] = we_b2[j];
    #pragma unroll
    for (int k = 0; k < 64; k++) {
        const float a = A[k];
        const float* w = we_w2 + k * 64;
        #pragma unroll
        for (int j = 0; j < 64; j++) B[j] += a * w[j];
    }
    #pragma unroll
    for (int j = 0; j < 64; j++) B[j] = fast_tanh(B[j]);   // B = m_ij

    // stream m_ij as bf16
    {
        __hip_bfloat162* mo = (__hip_bfloat162*)(mij + (size_t)e * 64);
        #pragma unroll
        for (int jj = 0; jj < 32; jj++) {
            __hip_bfloat162 p;
            p.x = __float2bfloat16(B[2*jj]);
            p.y = __float2bfloat16(B[2*jj+1]);
            mo[jj] = p;
        }
    }

    // ---- phi_x layer 1: tanh(m_ij @ wx_w1 + bx1) ----
    #pragma unroll
    for (int j = 0; j < 64; j++) A[j] = wx_b1[j];
    #pragma unroll
    for (int k = 0; k < 64; k++) {
        const float a = B[k];
        const float* w = wx_w1 + k * 64;
        #pragma unroll
        for (int j = 0; j < 64; j++) A[j] += a * w[j];
    }
    // ---- phi_x layer 2: scalar ----
    float px = wx_b2[0];
    #pragma unroll
    for (int j = 0; j < 64; j++) px += fast_tanh(A[j]) * wx_w2[j];
    px_out[e] = fast_tanh(px);
}

// ------------------------------------------- fallback edge kernel (atomics) ---
template<int BLK>
__global__ __launch_bounds__(BLK)
void edge_atomic_kernel(const float* __restrict__ h, const float* __restrict__ x,
                 const float* __restrict__ eattr,
                 const int* __restrict__ rows, const int* __restrict__ cols,
                 const float* __restrict__ we_w1, const float* __restrict__ we_b1,
                 const float* __restrict__ we_w2, const float* __restrict__ we_b2,
                 const float* __restrict__ wx_w1, const float* __restrict__ wx_b1,
                 const float* __restrict__ wx_w2, const float* __restrict__ wx_b2,
                 float* __restrict__ agg, float* __restrict__ cnt, float* __restrict__ mi,
                 int E)
{
    __shared__ float act[64][BLK];
    const int tid = threadIdx.x;
    const int e = blockIdx.x * BLK + tid;
    if (e >= E) return;

    const int r = rows[e];
    const int c = cols[e];
    const float d0 = x[(size_t)r*3+0] - x[(size_t)c*3+0];
    const float d1 = x[(size_t)r*3+1] - x[(size_t)c*3+1];
    const float d2 = x[(size_t)r*3+2] - x[(size_t)c*3+2];
    const float rad = d0*d0 + d1*d1 + d2*d2;

    float A[64];
    #pragma unroll
    for (int j = 0; j < 64; j++) A[j] = we_b1[j];
    const float* hr = h + (size_t)r * 64;
    const float* hc = h + (size_t)c * 64;
    #pragma unroll 4
    for (int k = 0; k < 64; k++) {
        const float a0 = hr[k];
        const float a1 = hc[k];
        const float* w0 = we_w1 + k * 64;
        const float* w1 = we_w1 + (64 + k) * 64;
        #pragma unroll
        for (int j = 0; j < 64; j++) A[j] += a0 * w0[j] + a1 * w1[j];
    }
    {
        const float* w = we_w1 + 128 * 64;
        #pragma unroll
        for (int j = 0; j < 64; j++) A[j] += rad * w[j];
    }
    const float* ea = eattr + (size_t)e * 8;
    #pragma unroll
    for (int k = 0; k < 8; k++) {
        const float a = ea[k];
        const float* w = we_w1 + (129 + k) * 64;
        #pragma unroll
        for (int j = 0; j < 64; j++) A[j] += a * w[j];
    }
    #pragma unroll
    for (int j = 0; j < 64; j++) act[j][tid] = fast_tanh(A[j]);

    float B[64];
    #pragma unroll
    for (int j = 0; j < 64; j++) B[j] = we_b2[j];
    #pragma unroll 4
    for (int k = 0; k < 64; k++) {
        const float a = act[k][tid];
        const float* w = we_w2 + k * 64;
        #pragma unroll
        for (int j = 0; j < 64; j++) B[j] += a * w[j];
    }
    #pragma unroll
    for (int j = 0; j < 64; j++) act[j][tid] = fast_tanh(B[j]);

    #pragma unroll
    for (int j = 0; j < 64; j++) A[j] = wx_b1[j];
    #pragma unroll 4
    for (int k = 0; k < 64; k++) {
        const float a = act[k][tid];
        const float* w = wx_w1 + k * 64;
        #pragma unroll
        for (int j = 0; j < 64; j++) A[j] += a * w[j];
    }
    float px = wx_b2[0];
    #pragma unroll
    for (int j = 0; j < 64; j++) px += fast_tanh(A[j]) * wx_w2[j];
    px = fast_tanh(px);

    atomicAdd(&agg[(size_t)r*3+0], d0 * px);
    atomicAdd(&agg[(size_t)r*3+1], d1 * px);
    atomicAdd(&agg[(size_t)r*3+2], d2 * px);
    atomicAdd(&cnt[r], 1.0f);
    float* mir = mi + (size_t)r * 64;
    #pragma unroll
    for (int j = 0; j < 64; j++) atomicAdd(&mir[j], act[j][tid]);
}

// ---------------------------------------------------------------- CSR build ---
__global__ void hist_kernel(const int* __restrict__ rows, int* __restrict__ hist, int E) {
    int e = blockIdx.x * blockDim.x + threadIdx.x;
    if (e < E) atomicAdd(&hist[rows[e]], 1);
}

__global__ __launch_bounds__(1024)
void scan_kernel(const int* __restrict__ hist, int* __restrict__ offs,
                 int* __restrict__ cursor, int N) {
    // chunk-per-thread serial sum -> block scan (wave shfl + LDS) -> write back
    const int tid = threadIdx.x;
    const int chunk = (N + 1023) / 1024;
    const int beg = tid * chunk;
    const int end = (beg + chunk < N) ? beg + chunk : N;

    int s = 0;
    for (int i = beg; i < end; i++) s += hist[i];

    __shared__ int wsum[16];
    const int lane = tid & 63, wid = tid >> 6;
    int inc = s;
    #pragma unroll
    for (int off = 1; off < 64; off <<= 1) {
        int t = __shfl_up(inc, off, 64);
        if (lane >= off) inc += t;
    }
    if (lane == 63) wsum[wid] = inc;
    __syncthreads();
    if (wid == 0 && lane < 16) {
        int v = wsum[lane];
        #pragma unroll
        for (int off = 1; off < 16; off <<= 1) {
            int t = __shfl_up(v, off, 64);
            if (lane >= off) v += t;
        }
        wsum[lane] = v;
    }
    __syncthreads();
    const int wbase = (wid > 0) ? wsum[wid - 1] : 0;
    int run = wbase + inc - s;      // exclusive prefix of this chunk
    for (int i = beg; i < end; i++) {
        cursor[i] = run;
        run += hist[i];
        offs[i + 1] = run;
    }
    if (tid == 0) offs[0] = 0;
}

__global__ void scatter_kernel(const int* __restrict__ rows, int* __restrict__ cursor,
                               int* __restrict__ perm, int E) {
    int e = blockIdx.x * blockDim.x + threadIdx.x;
    if (e < E) {
        int p = atomicAdd(&cursor[rows[e]], 1);
        perm[p] = e;
    }
}

// ------------------------------------------------------------- aggregation ---
// one wave per node: lane j sums column j of m_ij over the node's edges;
// lanes 0..2 recompute d = x[n]-x[cols[e]] and sum d*px. Writes mi and agg (MEAN).
__global__ __launch_bounds__(256)
void agg_kernel(const __hip_bfloat16* __restrict__ mij, const float* __restrict__ px,
                const int* __restrict__ cols, const float* __restrict__ x,
                const int* __restrict__ offs, const int* __restrict__ perm,
                float* __restrict__ mi, float* __restrict__ agg, int N)
{
    const int lane = threadIdx.x & 63;
    const int n = blockIdx.x * 4 + (threadIdx.x >> 6);
    if (n >= N) return;

    int beg = __builtin_amdgcn_readfirstlane(offs[n]);
    int end = __builtin_amdgcn_readfirstlane(offs[n + 1]);

    const float xn = (lane < 3) ? x[(size_t)n * 3 + lane] : 0.0f;

    float msum = 0.0f;
    float tsum = 0.0f;
    for (int i = beg; i < end; i++) {
        const int e = perm[i];                       // wave-uniform
        msum += __bfloat162float(mij[(size_t)e * 64 + lane]);
        if (lane < 3) {
            const int c = cols[e];
            tsum += (xn - x[(size_t)c * 3 + lane]) * px[e];
        }
    }
    mi[(size_t)n * 64 + lane] = msum;
    if (lane < 3) {
        const float cf = (float)(end - beg);
        agg[(size_t)n * 3 + lane] = tsum / fmaxf(cf, 1.0f);  // mean
    }
}

// -------------------------------------------------------------- node update ---
template<int BLK, bool AGG_IS_MEAN>
__global__ __launch_bounds__(BLK, 2)
void node_kernel(const float* __restrict__ h, const float* __restrict__ x,
                 const float* __restrict__ vel,
                 const float* __restrict__ wh_w1, const float* __restrict__ wh_b1,
                 const float* __restrict__ wh_w2, const float* __restrict__ wh_b2,
                 const float* __restrict__ wv_w1, const float* __restrict__ wv_b1,
                 const float* __restrict__ wv_w2, const float* __restrict__ wv_b2,
                 const float* __restrict__ agg, const float* __restrict__ cnt,
                 const float* __restrict__ mi,
                 float* __restrict__ out_h, float* __restrict__ out_x, float* __restrict__ out_v,
                 int N)
{
    const int n = blockIdx.x * BLK + threadIdx.x;
    if (n >= N) return;

    const float* hn = h + (size_t)n * 64;
    const float* mn = mi + (size_t)n * 64;

    float A[64];

    // ---- phi_v: tanh(h @ wv_w1 + b1) @ wv_w2 + b2   (NO outer tanh) ----
    #pragma unroll
    for (int j = 0; j < 64; j++) A[j] = wv_b1[j];
    #pragma unroll
    for (int k = 0; k < 64; k++) {
        const float a = hn[k];
        const float* w = wv_w1 + k * 64;
        #pragma unroll
        for (int j = 0; j < 64; j++) A[j] += a * w[j];
    }
    float pv = wv_b2[0];
    #pragma unroll
    for (int j = 0; j < 64; j++) pv += fast_tanh(A[j]) * wv_w2[j];

    // ---- phi_h layer 1: tanh([h, m_i] @ wh_w1 + b1) ----
    #pragma unroll
    for (int j = 0; j < 64; j++) A[j] = wh_b1[j];
    #pragma unroll
    for (int k = 0; k < 64; k++) {
        const float a0 = hn[k];
        const float a1 = mn[k];
        const float* w0 = wh_w1 + k * 64;
        const float* w1 = wh_w1 + (64 + k) * 64;
        #pragma unroll
        for (int j = 0; j < 64; j++) A[j] += a0 * w0[j] + a1 * w1[j];
    }
    #pragma unroll
    for (int j = 0; j < 64; j++) A[j] = fast_tanh(A[j]);

    // ---- phi_h layer 2: A @ wh_w2 + b2   (NO outer tanh) ----
    float B[64];
    #pragma unroll
    for (int j = 0; j < 64; j++) B[j] = wh_b2[j];
    #pragma unroll
    for (int k = 0; k < 64; k++) {
        const float a = A[k];
        const float* w = wh_w2 + k * 64;
        #pragma unroll
        for (int j = 0; j < 64; j++) B[j] += a * w[j];
    }
    float* oh = out_h + (size_t)n * 64;
    #pragma unroll
    for (int j = 0; j < 64; j++) oh[j] = B[j];

    // ---- coordinate / velocity update ----
    float inv = 1.0f;
    if (!AGG_IS_MEAN) inv = 1.0f / fmaxf(cnt[n], 1.0f);
    #pragma unroll
    for (int d = 0; d < 3; d++) {
        const float am = agg[(size_t)n*3 + d] * inv;
        const float vn = vel[(size_t)n*3 + d] * pv + am;
        out_v[(size_t)n*3 + d] = vn;
        out_x[(size_t)n*3 + d] = x[(size_t)n*3 + d] + vn;
    }
}

// ------------------------------------------------------------------ launch ---
extern "C" void kernel_launch(void* const* d_in, const int* in_sizes, int n_in,
                              void* d_out, int out_size, void* d_ws, size_t ws_size,
                              hipStream_t stream) {
    const float* h      = (const float*)d_in[0];
    const float* x      = (const float*)d_in[1];
    const float* vel    = (const float*)d_in[2];
    const float* eattr  = (const float*)d_in[3];
    const float* we_w1  = (const float*)d_in[4];
    const float* we_b1  = (const float*)d_in[5];
    const float* we_w2  = (const float*)d_in[6];
    const float* we_b2  = (const float*)d_in[7];
    const float* wx_w1  = (const float*)d_in[8];
    const float* wx_b1  = (const float*)d_in[9];
    const float* wx_w2  = (const float*)d_in[10];
    const float* wx_b2  = (const float*)d_in[11];
    const float* wh_w1  = (const float*)d_in[12];
    const float* wh_b1  = (const float*)d_in[13];
    const float* wh_w2  = (const float*)d_in[14];
    const float* wh_b2  = (const float*)d_in[15];
    const float* wv_w1  = (const float*)d_in[16];
    const float* wv_b1  = (const float*)d_in[17];
    const float* wv_w2  = (const float*)d_in[18];
    const float* wv_b2  = (const float*)d_in[19];
    const int*   ar     = (const int*)d_in[20];

    const int N = in_sizes[0] / 64;
    const int E = in_sizes[20] / 2;
    const int* rows = ar;
    const int* cols = ar + E;

    float* out_h = (float*)d_out;            // N*64 (also used as Hr scratch)
    float* out_x = out_h + (size_t)N * 64;   // N*3
    float* out_v = out_x + (size_t)N * 3;    // N*3

    // --- workspace layout (streaming path): 258.4 MB for N=1e5, E=1.6e6 ---
    char* p = (char*)d_ws;
    __hip_bfloat16* mij = (__hip_bfloat16*)p;  p += (size_t)E * 64 * sizeof(__hip_bfloat16);
    float* px    = (float*)p;                  p += (size_t)E * sizeof(float);
    float* mi    = (float*)p;                  p += (size_t)N * 64 * sizeof(float);
    float* agg   = (float*)p;                  p += (size_t)N * 3 * sizeof(float);
    __hip_bfloat16* Hc = (__hip_bfloat16*)p;   p += (size_t)N * 64 * sizeof(__hip_bfloat16);
    int*   offs  = (int*)p;                    p += (size_t)(N + 1) * sizeof(int);
    int*   cursor= (int*)p;                    p += (size_t)N * sizeof(int);
    int*   hist  = (int*)p;                    p += (size_t)N * sizeof(int);
    int*   perm  = (int*)p;                    p += (size_t)E * sizeof(int);
    const size_t needed = (size_t)(p - (char*)d_ws);

    float* Hr = out_h;                         // f32 Hr scratch lives in d_out; node_kernel
                                               // overwrites it with the real out_h last.

    if (ws_size >= needed) {
        hipMemsetAsync(hist, 0, (size_t)N * sizeof(int), stream);
        hist_kernel<<<(E + 255) / 256, 256, 0, stream>>>(rows, hist, E);
        scan_kernel<<<1, 1024, 0, stream>>>(hist, offs, cursor, N);
        scatter_kernel<<<(E + 255) / 256, 256, 0, stream>>>(rows, cursor, perm, E);

        pre_kernel<256><<<(N + 255) / 256, 256, 0, stream>>>(h, we_w1, we_b1, Hr, Hc, N);

        edge_fast_kernel<256><<<(E + 255) / 256, 256, 0, stream>>>(
            x, eattr, rows, cols, Hr, Hc,
            we_w1, we_w2, we_b2,
            wx_w1, wx_b1, wx_w2, wx_b2,
            mij, px, E);

        agg_kernel<<<(N + 3) / 4, 256, 0, stream>>>(mij, px, cols, x, offs, perm, mi, agg, N);

        node_kernel<256, true><<<(N + 255) / 256, 256, 0, stream>>>(
            h, x, vel,
            wh_w1, wh_b1, wh_w2, wh_b2,
            wv_w1, wv_b1, wv_w2, wv_b2,
            agg, nullptr, mi, out_h, out_x, out_v, N);
    } else {
        // --- fallback: atomic path ---
        float* agg2 = (float*)d_ws;               // N*3
        float* cnt2 = agg2 + (size_t)N * 3;       // N
        float* mi2  = cnt2 + N;                   // N*64
        hipMemsetAsync(d_ws, 0, (size_t)N * 68 * sizeof(float), stream);

        edge_atomic_kernel<128><<<(E + 127) / 128, 128, 0, stream>>>(
            h, x, eattr, rows, cols,
            we_w1, we_b1, we_w2, we_b2,
            wx_w1, wx_b1, wx_w2, wx_b2,
            agg2, cnt2, mi2, E);

        node_kernel<128, false><<<(N + 127) / 128, 128, 0, stream>>>(
            h, x, vel,
            wh_w1, wh_b1, wh_w2, wh_b2,
            wv_w1, wv_b1, wv_w2, wv_b2,
            agg2, cnt2, mi2, out_h, out_x, out_v, N);
    }
}

// Round 5
// 1939.928 us; speedup vs baseline: 3.2357x; 1.0852x over previous
//
#include <hip/hip_runtime.h>

// EGNN layer (CamadaEquivariante), round 5:
//  - edge kernel: MFMA bf16. Block = 64 edges (4 waves x 16). Phase A computes
//    tanh(attr@We1+b1) via hoisted Hr(f32, in d_out scratch)+Hc(bf16) -> LDS X1
//    (bf16, XOR-swizzled). Layer2 and phi_x-L1 are 16x16x32 bf16 MFMAs with
//    weight frags (pre-transposed) in registers; bias via C-init. phi_x-L2 via
//    shfl_xor reduce. mij/px written at CSR slot pos[e] -> agg reads sequential.
//  - pre/node kernels: 16-out chunked, bf16-packed operand caches, no spills.
// ws = 264.8 MB. Fallback to atomic path if ws too small.

typedef unsigned int uint;
typedef unsigned short u16;
typedef __attribute__((ext_vector_type(8))) short short8;
typedef __attribute__((ext_vector_type(4))) float f32x4;

#define UB_LO(u) __uint_as_float((u) << 16)
#define UB_HI(u) __uint_as_float((u) & 0xffff0000u)

__device__ __forceinline__ float fast_tanh(float x) {
    float e = __expf(2.0f * x);
    return 1.0f - 2.0f * __builtin_amdgcn_rcpf(e + 1.0f);
}
__device__ __forceinline__ u16 bf16rne(float f) {
    uint u = __float_as_uint(f);
    return (u16)((u + 0x7fffu + ((u >> 16) & 1u)) >> 16);
}
__device__ __forceinline__ uint packbf(float a, float b) {
    return (uint)bf16rne(a) | ((uint)bf16rne(b) << 16);
}
// XOR-swizzle within a [64][64]-bf16 (128B-row) LDS tile: byte ^= ((row&7)<<4)
__device__ __forceinline__ int swzb(int b) { return b ^ ((b >> 3) & 0x70); }

// ------------------------------------------------- weight transpose (bf16) ---
__global__ void wprep_kernel(const float* __restrict__ we_w2,
                             const float* __restrict__ wx_w1,
                             u16* __restrict__ we2t, u16* __restrict__ wx1t) {
    int t = blockIdx.x * 256 + threadIdx.x;
    if (t < 4096) {
        int n = t >> 6, k = t & 63;
        we2t[n * 64 + k] = bf16rne(we_w2[k * 64 + n]);
        wx1t[n * 64 + k] = bf16rne(wx_w1[k * 64 + n]);
    }
}

// ------------------------------------------------------------- precompute ---
// Hr = h@We1[0:64]+b1 (f32, into d_out scratch), Hc = h@We1[64:128] (bf16, ws)
__global__ __launch_bounds__(256, 4)
void pre_kernel(const float* __restrict__ h,
                const float* __restrict__ we_w1, const float* __restrict__ we_b1,
                float* __restrict__ Hr, u16* __restrict__ Hc, int N)
{
    const int n = blockIdx.x * 256 + threadIdx.x;
    if (n >= N) return;
    uint hpk[32];
    {
        const float2* h2 = (const float2*)(h + (size_t)n * 64);
        #pragma unroll
        for (int q = 0; q < 32; q++) { float2 v = h2[q]; hpk[q] = packbf(v.x, v.y); }
    }
    // Hr
    #pragma unroll
    for (int jc = 0; jc < 4; jc++) {
        float acc[16];
        #pragma unroll
        for (int i = 0; i < 16; i++) acc[i] = we_b1[jc * 16 + i];
        #pragma unroll
        for (int k = 0; k < 64; k++) {
            const float a = (k & 1) ? UB_HI(hpk[k >> 1]) : UB_LO(hpk[k >> 1]);
            const float* w = we_w1 + k * 64 + jc * 16;
            #pragma unroll
            for (int i = 0; i < 16; i++) acc[i] += a * w[i];
        }
        float4* o = (float4*)(Hr + (size_t)n * 64 + jc * 16);
        #pragma unroll
        for (int q = 0; q < 4; q++) o[q] = make_float4(acc[4*q], acc[4*q+1], acc[4*q+2], acc[4*q+3]);
    }
    // Hc (bf16)
    #pragma unroll
    for (int jc = 0; jc < 4; jc++) {
        float acc[16];
        #pragma unroll
        for (int i = 0; i < 16; i++) acc[i] = 0.0f;
        #pragma unroll
        for (int k = 0; k < 64; k++) {
            const float a = (k & 1) ? UB_HI(hpk[k >> 1]) : UB_LO(hpk[k >> 1]);
            const float* w = we_w1 + (64 + k) * 64 + jc * 16;
            #pragma unroll
            for (int i = 0; i < 16; i++) acc[i] += a * w[i];
        }
        uint pk[8];
        #pragma unroll
        for (int q = 0; q < 8; q++) pk[q] = packbf(acc[2*q], acc[2*q+1]);
        uint4* o = (uint4*)(Hc + (size_t)n * 64 + jc * 16);
        o[0] = make_uint4(pk[0], pk[1], pk[2], pk[3]);
        o[1] = make_uint4(pk[4], pk[5], pk[6], pk[7]);
    }
}

// --------------------------------------------------------- edge MFMA kernel ---
__global__ __launch_bounds__(256, 4)
void edge_mfma_kernel(const float* __restrict__ x, const float* __restrict__ eattr,
                      const int* __restrict__ rows, const int* __restrict__ cols,
                      const float* __restrict__ Hr, const u16* __restrict__ Hc,
                      const float* __restrict__ we_w1,
                      const u16* __restrict__ we2t, const float* __restrict__ we_b2,
                      const u16* __restrict__ wx1t, const float* __restrict__ wx_b1,
                      const float* __restrict__ wx_w2, const float* __restrict__ wx_b2,
                      const int* __restrict__ pos,
                      u16* __restrict__ mij, float* __restrict__ px_s, int E)
{
    __shared__ u16 X1[4096];   // [64 edges][64] bf16, swizzled
    __shared__ u16 X2[4096];
    __shared__ int posS[64];

    const int tid = threadIdx.x;
    const int lane = tid & 63;
    const int wv = tid >> 6;
    const int eb = blockIdx.x * 64;

    const int fn  = lane & 15;        // frag n / m index
    const int fk8 = (lane >> 4) * 8;  // frag k-base

    // weight fragments (B-operand: BT[n][k] rows, 8 consecutive k per lane)
    uint4 w2f[8], x1f[8];
    #pragma unroll
    for (int n0 = 0; n0 < 4; n0++)
        #pragma unroll
        for (int kk = 0; kk < 2; kk++) {
            w2f[n0*2+kk] = *(const uint4*)(we2t + (n0*16 + fn) * 64 + kk*32 + fk8);
            x1f[n0*2+kk] = *(const uint4*)(wx1t + (n0*16 + fn) * 64 + kk*32 + fk8);
        }

    if (tid < 64) posS[tid] = (eb + tid < E) ? pos[eb + tid] : 0;

    // ---- phase A: layer-1 activations -> X1 (4 threads/edge, 16 outs each) ----
    const int el = tid >> 2;
    const int jg = tid & 3;
    const int e  = eb + el;
    float acc[16];
    if (e < E) {
        const int r = rows[e], c = cols[e];
        const float d0 = x[(size_t)r*3+0] - x[(size_t)c*3+0];
        const float d1 = x[(size_t)r*3+1] - x[(size_t)c*3+1];
        const float d2 = x[(size_t)r*3+2] - x[(size_t)c*3+2];
        const float rad = d0*d0 + d1*d1 + d2*d2;

        const float4* hr4 = (const float4*)(Hr + (size_t)r * 64 + jg * 16);
        float hrv[16];
        #pragma unroll
        for (int q = 0; q < 4; q++) {
            float4 v = hr4[q];
            hrv[4*q+0]=v.x; hrv[4*q+1]=v.y; hrv[4*q+2]=v.z; hrv[4*q+3]=v.w;
        }
        uint4 ca = *(const uint4*)(Hc + (size_t)c * 64 + jg * 16);
        uint4 cb = *(const uint4*)(Hc + (size_t)c * 64 + jg * 16 + 8);
        uint cw[8] = {ca.x, ca.y, ca.z, ca.w, cb.x, cb.y, cb.z, cb.w};
        const float* wrad = we_w1 + 128 * 64 + jg * 16;
        #pragma unroll
        for (int i = 0; i < 16; i++) {
            const float hcv = (i & 1) ? UB_HI(cw[i >> 1]) : UB_LO(cw[i >> 1]);
            acc[i] = hrv[i] + hcv + rad * wrad[i];
        }
        const float4* ea4 = (const float4*)(eattr + (size_t)e * 8);
        float4 v0 = ea4[0], v1 = ea4[1];
        float ea[8] = {v0.x, v0.y, v0.z, v0.w, v1.x, v1.y, v1.z, v1.w};
        #pragma unroll
        for (int k = 0; k < 8; k++) {
            const float* w = we_w1 + (129 + k) * 64 + jg * 16;
            #pragma unroll
            for (int i = 0; i < 16; i++) acc[i] += ea[k] * w[i];
        }
        #pragma unroll
        for (int i = 0; i < 16; i++) acc[i] = fast_tanh(acc[i]);
    } else {
        #pragma unroll
        for (int i = 0; i < 16; i++) acc[i] = 0.0f;
    }
    {
        uint pk[8];
        #pragma unroll
        for (int q = 0; q < 8; q++) pk[q] = packbf(acc[2*q], acc[2*q+1]);
        const int b0 = swzb(el * 128 + jg * 32);
        const int b1 = swzb(el * 128 + jg * 32 + 16);
        *(uint4*)(&X1[b0 >> 1]) = make_uint4(pk[0], pk[1], pk[2], pk[3]);
        *(uint4*)(&X1[b1 >> 1]) = make_uint4(pk[4], pk[5], pk[6], pk[7]);
    }
    __syncthreads();

    // ---- layer 2 MFMA: X2 = tanh(X1 @ We2 + b2) ----
    const int mb = wv * 16;
    short8 a0, a1;
    {
        const int ba = swzb((mb + fn) * 128 + fk8 * 2);
        const int bb = swzb((mb + fn) * 128 + 64 + fk8 * 2);
        a0 = *(const short8*)(&X1[ba >> 1]);
        a1 = *(const short8*)(&X1[bb >> 1]);
    }
    #pragma unroll
    for (int n0 = 0; n0 < 4; n0++) {
        const float bias = we_b2[n0 * 16 + fn];
        f32x4 q = {bias, bias, bias, bias};
        q = __builtin_amdgcn_mfma_f32_16x16x32_bf16(a0, __builtin_bit_cast(short8, w2f[n0*2+0]), q, 0, 0, 0);
        q = __builtin_amdgcn_mfma_f32_16x16x32_bf16(a1, __builtin_bit_cast(short8, w2f[n0*2+1]), q, 0, 0, 0);
        #pragma unroll
        for (int r2 = 0; r2 < 4; r2++) {
            const int m = mb + (lane >> 4) * 4 + r2;
            const int n = n0 * 16 + fn;
            X2[swzb(m * 128 + n * 2) >> 1] = bf16rne(fast_tanh(q[r2]));
        }
    }
    __syncthreads();

    // ---- coalesced mij write (CSR slot order) ----
    {
        const int b0 = swzb(el * 128 + jg * 32);
        const int b1 = swzb(el * 128 + jg * 32 + 16);
        uint4 v0 = *(const uint4*)(&X2[b0 >> 1]);
        uint4 v1 = *(const uint4*)(&X2[b1 >> 1]);
        if (e < E) {
            u16* mo = mij + (size_t)posS[el] * 64 + jg * 16;
            *(uint4*)(mo) = v0;
            *(uint4*)(mo + 8) = v1;
        }
    }

    // ---- phi_x: S = X2 @ Wx1 + b1; px = tanh(tanh(S) @ wx2 + b2) ----
    short8 c0, c1;
    {
        const int ba = swzb((mb + fn) * 128 + fk8 * 2);
        const int bb = swzb((mb + fn) * 128 + 64 + fk8 * 2);
        c0 = *(const short8*)(&X2[ba >> 1]);
        c1 = *(const short8*)(&X2[bb >> 1]);
    }
    float pxp[4] = {0.f, 0.f, 0.f, 0.f};
    #pragma unroll
    for (int n0 = 0; n0 < 4; n0++) {
        const float bias = wx_b1[n0 * 16 + fn];
        f32x4 q = {bias, bias, bias, bias};
        q = __builtin_amdgcn_mfma_f32_16x16x32_bf16(c0, __builtin_bit_cast(short8, x1f[n0*2+0]), q, 0, 0, 0);
        q = __builtin_amdgcn_mfma_f32_16x16x32_bf16(c1, __builtin_bit_cast(short8, x1f[n0*2+1]), q, 0, 0, 0);
        const float wqn = wx_w2[n0 * 16 + fn];
        #pragma unroll
        for (int r2 = 0; r2 < 4; r2++) pxp[r2] += fast_tanh(q[r2]) * wqn;
    }
    #pragma unroll
    for (int off = 1; off < 16; off <<= 1) {
        #pragma unroll
        for (int r2 = 0; r2 < 4; r2++) pxp[r2] += __shfl_xor(pxp[r2], off, 64);
    }
    if (fn == 0) {
        const float bx2 = wx_b2[0];
        #pragma unroll
        for (int r2 = 0; r2 < 4; r2++) {
            const int m = mb + (lane >> 4) * 4 + r2;
            if (eb + m < E) px_s[posS[m]] = fast_tanh(pxp[r2] + bx2);
        }
    }
}

// ------------------------------------------- fallback edge kernel (atomics) ---
template<int BLK>
__global__ __launch_bounds__(BLK)
void edge_atomic_kernel(const float* __restrict__ h, const float* __restrict__ x,
                 const float* __restrict__ eattr,
                 const int* __restrict__ rows, const int* __restrict__ cols,
                 const float* __restrict__ we_w1, const float* __restrict__ we_b1,
                 const float* __restrict__ we_w2, const float* __restrict__ we_b2,
                 const float* __restrict__ wx_w1, const float* __restrict__ wx_b1,
                 const float* __restrict__ wx_w2, const float* __restrict__ wx_b2,
                 float* __restrict__ agg, float* __restrict__ cnt, float* __restrict__ mi,
                 int E)
{
    __shared__ float act[64][BLK];
    const int tid = threadIdx.x;
    const int e = blockIdx.x * BLK + tid;
    if (e >= E) return;

    const int r = rows[e];
    const int c = cols[e];
    const float d0 = x[(size_t)r*3+0] - x[(size_t)c*3+0];
    const float d1 = x[(size_t)r*3+1] - x[(size_t)c*3+1];
    const float d2 = x[(size_t)r*3+2] - x[(size_t)c*3+2];
    const float rad = d0*d0 + d1*d1 + d2*d2;

    float A[64];
    #pragma unroll
    for (int j = 0; j < 64; j++) A[j] = we_b1[j];
    const float* hr = h + (size_t)r * 64;
    const float* hc = h + (size_t)c * 64;
    #pragma unroll 4
    for (int k = 0; k < 64; k++) {
        const float a0 = hr[k];
        const float a1 = hc[k];
        const float* w0 = we_w1 + k * 64;
        const float* w1 = we_w1 + (64 + k) * 64;
        #pragma unroll
        for (int j = 0; j < 64; j++) A[j] += a0 * w0[j] + a1 * w1[j];
    }
    {
        const float* w = we_w1 + 128 * 64;
        #pragma unroll
        for (int j = 0; j < 64; j++) A[j] += rad * w[j];
    }
    const float* ea = eattr + (size_t)e * 8;
    #pragma unroll
    for (int k = 0; k < 8; k++) {
        const float a = ea[k];
        const float* w = we_w1 + (129 + k) * 64;
        #pragma unroll
        for (int j = 0; j < 64; j++) A[j] += a * w[j];
    }
    #pragma unroll
    for (int j = 0; j < 64; j++) act[j][tid] = fast_tanh(A[j]);

    float B[64];
    #pragma unroll
    for (int j = 0; j < 64; j++) B[j] = we_b2[j];
    #pragma unroll 4
    for (int k = 0; k < 64; k++) {
        const float a = act[k][tid];
        const float* w = we_w2 + k * 64;
        #pragma unroll
        for (int j = 0; j < 64; j++) B[j] += a * w[j];
    }
    #pragma unroll
    for (int j = 0; j < 64; j++) act[j][tid] = fast_tanh(B[j]);

    #pragma unroll
    for (int j = 0; j < 64; j++) A[j] = wx_b1[j];
    #pragma unroll 4
    for (int k = 0; k < 64; k++) {
        const float a = act[k][tid];
        const float* w = wx_w1 + k * 64;
        #pragma unroll
        for (int j = 0; j < 64; j++) A[j] += a * w[j];
    }
    float px = wx_b2[0];
    #pragma unroll
    for (int j = 0; j < 64; j++) px += fast_tanh(A[j]) * wx_w2[j];
    px = fast_tanh(px);

    atomicAdd(&agg[(size_t)r*3+0], d0 * px);
    atomicAdd(&agg[(size_t)r*3+1], d1 * px);
    atomicAdd(&agg[(size_t)r*3+2], d2 * px);
    atomicAdd(&cnt[r], 1.0f);
    float* mir = mi + (size_t)r * 64;
    #pragma unroll
    for (int j = 0; j < 64; j++) atomicAdd(&mir[j], act[j][tid]);
}

// ---------------------------------------------------------------- CSR build ---
__global__ void hist_kernel(const int* __restrict__ rows, int* __restrict__ hist, int E) {
    int e = blockIdx.x * blockDim.x + threadIdx.x;
    if (e < E) atomicAdd(&hist[rows[e]], 1);
}

__global__ __launch_bounds__(1024)
void scan_kernel(const int* __restrict__ hist, int* __restrict__ offs,
                 int* __restrict__ cursor, int N) {
    const int tid = threadIdx.x;
    const int chunk = (N + 1023) / 1024;
    const int beg = tid * chunk;
    const int end = (beg + chunk < N) ? beg + chunk : N;

    int s = 0;
    for (int i = beg; i < end; i++) s += hist[i];

    __shared__ int wsum[16];
    const int lane = tid & 63, wid = tid >> 6;
    int inc = s;
    #pragma unroll
    for (int off = 1; off < 64; off <<= 1) {
        int t = __shfl_up(inc, off, 64);
        if (lane >= off) inc += t;
    }
    if (lane == 63) wsum[wid] = inc;
    __syncthreads();
    if (wid == 0 && lane < 16) {
        int v = wsum[lane];
        #pragma unroll
        for (int off = 1; off < 16; off <<= 1) {
            int t = __shfl_up(v, off, 64);
            if (lane >= off) v += t;
        }
        wsum[lane] = v;
    }
    __syncthreads();
    const int wbase = (wid > 0) ? wsum[wid - 1] : 0;
    int run = wbase + inc - s;
    for (int i = beg; i < end; i++) {
        cursor[i] = run;
        run += hist[i];
        offs[i + 1] = run;
    }
    if (tid == 0) offs[0] = 0;
}

// scatter: pos[e] = CSR slot of edge e; colp[slot] = cols[e]
__global__ void scatter_kernel(const int* __restrict__ rows, const int* __restrict__ cols,
                               int* __restrict__ cursor,
                               int* __restrict__ pos, int* __restrict__ colp, int E) {
    int e = blockIdx.x * blockDim.x + threadIdx.x;
    if (e < E) {
        int p = atomicAdd(&cursor[rows[e]], 1);
        pos[e] = p;
        colp[p] = cols[e];
    }
}

// ------------------------------------------------------------- aggregation ---
// one wave per node; fully sequential reads (mij/px/colp in CSR order)
__global__ __launch_bounds__(256)
void agg_kernel(const u16* __restrict__ mij, const float* __restrict__ px_s,
                const int* __restrict__ colp, const float* __restrict__ x,
                const int* __restrict__ offs,
                float* __restrict__ mi, float* __restrict__ agg, int N)
{
    const int lane = threadIdx.x & 63;
    const int n = blockIdx.x * 4 + (threadIdx.x >> 6);
    if (n >= N) return;

    const int beg = __builtin_amdgcn_readfirstlane(offs[n]);
    const int end = __builtin_amdgcn_readfirstlane(offs[n + 1]);

    const float xn = (lane < 3) ? x[(size_t)n * 3 + lane] : 0.0f;

    float msum = 0.0f;
    float tsum = 0.0f;
    for (int i = beg; i < end; i++) {
        msum += UB_LO((uint)mij[(size_t)i * 64 + lane]);
        if (lane < 3) {
            const int c = colp[i];
            tsum += (xn - x[(size_t)c * 3 + lane]) * px_s[i];
        }
    }
    mi[(size_t)n * 64 + lane] = msum;
    if (lane < 3) {
        const float cf = (float)(end - beg);
        agg[(size_t)n * 3 + lane] = tsum / fmaxf(cf, 1.0f);
    }
}

// -------------------------------------------------------------- node update ---
template<int BLK, bool AGG_IS_MEAN>
__global__ __launch_bounds__(BLK, 4)
void node_kernel(const float* __restrict__ h, const float* __restrict__ x,
                 const float* __restrict__ vel,
                 const float* __restrict__ wh_w1, const float* __restrict__ wh_b1,
                 const float* __restrict__ wh_w2, const float* __restrict__ wh_b2,
                 const float* __restrict__ wv_w1, const float* __restrict__ wv_b1,
                 const float* __restrict__ wv_w2, const float* __restrict__ wv_b2,
                 const float* __restrict__ agg, const float* __restrict__ cnt,
                 const float* __restrict__ mi,
                 float* __restrict__ out_h, float* __restrict__ out_x, float* __restrict__ out_v,
                 int N)
{
    const int n = blockIdx.x * BLK + threadIdx.x;
    if (n >= N) return;

    uint hpk[32], mpk[32];
    {
        const float2* h2 = (const float2*)(h  + (size_t)n * 64);
        const float2* m2 = (const float2*)(mi + (size_t)n * 64);
        #pragma unroll
        for (int q = 0; q < 32; q++) {
            float2 a = h2[q]; hpk[q] = packbf(a.x, a.y);
            float2 b = m2[q]; mpk[q] = packbf(b.x, b.y);
        }
    }

    // ---- phi_v ----
    float pv = wv_b2[0];
    #pragma unroll
    for (int jc = 0; jc < 4; jc++) {
        float acc[16];
        #pragma unroll
        for (int i = 0; i < 16; i++) acc[i] = wv_b1[jc * 16 + i];
        #pragma unroll
        for (int k = 0; k < 64; k++) {
            const float a = (k & 1) ? UB_HI(hpk[k >> 1]) : UB_LO(hpk[k >> 1]);
            const float* w = wv_w1 + k * 64 + jc * 16;
            #pragma unroll
            for (int i = 0; i < 16; i++) acc[i] += a * w[i];
        }
        #pragma unroll
        for (int i = 0; i < 16; i++) pv += fast_tanh(acc[i]) * wv_w2[jc * 16 + i];
    }

    // ---- phi_h layer 1 -> actPk (bf16 packed) ----
    uint actPk[32];
    #pragma unroll
    for (int jc = 0; jc < 4; jc++) {
        float acc[16];
        #pragma unroll
        for (int i = 0; i < 16; i++) acc[i] = wh_b1[jc * 16 + i];
        #pragma unroll
        for (int k = 0; k < 64; k++) {
            const float a0 = (k & 1) ? UB_HI(hpk[k >> 1]) : UB_LO(hpk[k >> 1]);
            const float a1 = (k & 1) ? UB_HI(mpk[k >> 1]) : UB_LO(mpk[k >> 1]);
            const float* w0 = wh_w1 + k * 64 + jc * 16;
            const float* w1 = wh_w1 + (64 + k) * 64 + jc * 16;
            #pragma unroll
            for (int i = 0; i < 16; i++) acc[i] += a0 * w0[i] + a1 * w1[i];
        }
        #pragma unroll
        for (int q = 0; q < 8; q++)
            actPk[jc * 8 + q] = packbf(fast_tanh(acc[2*q]), fast_tanh(acc[2*q+1]));
    }

    // ---- phi_h layer 2 ----
    #pragma unroll
    for (int jc = 0; jc < 4; jc++) {
        float acc[16];
        #pragma unroll
        for (int i = 0; i < 16; i++) acc[i] = wh_b2[jc * 16 + i];
        #pragma unroll
        for (int k = 0; k < 64; k++) {
            const float a = (k & 1) ? UB_HI(actPk[k >> 1]) : UB_LO(actPk[k >> 1]);
            const float* w = wh_w2 + k * 64 + jc * 16;
            #pragma unroll
            for (int i = 0; i < 16; i++) acc[i] += a * w[i];
        }
        float4* o = (float4*)(out_h + (size_t)n * 64 + jc * 16);
        #pragma unroll
        for (int q = 0; q < 4; q++) o[q] = make_float4(acc[4*q], acc[4*q+1], acc[4*q+2], acc[4*q+3]);
    }

    // ---- coordinate / velocity update ----
    float inv = 1.0f;
    if (!AGG_IS_MEAN) inv = 1.0f / fmaxf(cnt[n], 1.0f);
    #pragma unroll
    for (int d = 0; d < 3; d++) {
        const float am = agg[(size_t)n*3 + d] * inv;
        const float vn = vel[(size_t)n*3 + d] * pv + am;
        out_v[(size_t)n*3 + d] = vn;
        out_x[(size_t)n*3 + d] = x[(size_t)n*3 + d] + vn;
    }
}

// ------------------------------------------------------------------ launch ---
extern "C" void kernel_launch(void* const* d_in, const int* in_sizes, int n_in,
                              void* d_out, int out_size, void* d_ws, size_t ws_size,
                              hipStream_t stream) {
    const float* h      = (const float*)d_in[0];
    const float* x      = (const float*)d_in[1];
    const float* vel    = (const float*)d_in[2];
    const float* eattr  = (const float*)d_in[3];
    const float* we_w1  = (const float*)d_in[4];
    const float* we_b1  = (const float*)d_in[5];
    const float* we_w2  = (const float*)d_in[6];
    const float* we_b2  = (const float*)d_in[7];
    const float* wx_w1  = (const float*)d_in[8];
    const float* wx_b1  = (const float*)d_in[9];
    const float* wx_w2  = (const float*)d_in[10];
    const float* wx_b2  = (const float*)d_in[11];
    const float* wh_w1  = (const float*)d_in[12];
    const float* wh_b1  = (const float*)d_in[13];
    const float* wh_w2  = (const float*)d_in[14];
    const float* wh_b2  = (const float*)d_in[15];
    const float* wv_w1  = (const float*)d_in[16];
    const float* wv_b1  = (const float*)d_in[17];
    const float* wv_w2  = (const float*)d_in[18];
    const float* wv_b2  = (const float*)d_in[19];
    const int*   ar     = (const int*)d_in[20];

    const int N = in_sizes[0] / 64;
    const int E = in_sizes[20] / 2;
    const int* rows = ar;
    const int* cols = ar + E;

    float* out_h = (float*)d_out;            // N*64 (Hr f32 scratch first)
    float* out_x = out_h + (size_t)N * 64;   // N*3
    float* out_v = out_x + (size_t)N * 3;    // N*3

    // --- workspace layout (streaming path): ~264.8 MB ---
    char* p = (char*)d_ws;
    u16*  mij   = (u16*)p;    p += (size_t)E * 64 * sizeof(u16);
    float* px_s = (float*)p;  p += (size_t)E * sizeof(float);
    float* mi   = (float*)p;  p += (size_t)N * 64 * sizeof(float);
    float* agg  = (float*)p;  p += (size_t)N * 3 * sizeof(float);
    u16*  Hc    = (u16*)p;    p += (size_t)N * 64 * sizeof(u16);
    int*  pos   = (int*)p;    p += (size_t)E * sizeof(int);
    int*  colp  = (int*)p;    p += (size_t)E * sizeof(int);
    u16*  we2t  = (u16*)p;    p += 4096 * sizeof(u16);
    u16*  wx1t  = (u16*)p;    p += 4096 * sizeof(u16);
    int*  offs  = (int*)p;    p += (size_t)(N + 1) * sizeof(int);
    int*  cursor= (int*)p;    p += (size_t)N * sizeof(int);
    int*  hist  = (int*)p;    p += (size_t)N * sizeof(int);
    const size_t needed = (size_t)(p - (char*)d_ws);

    float* Hr = out_h;   // f32 Hr scratch in d_out; node_kernel overwrites last

    if (ws_size >= needed) {
        hipMemsetAsync(hist, 0, (size_t)N * sizeof(int), stream);
        hist_kernel<<<(E + 255) / 256, 256, 0, stream>>>(rows, hist, E);
        scan_kernel<<<1, 1024, 0, stream>>>(hist, offs, cursor, N);
        scatter_kernel<<<(E + 255) / 256, 256, 0, stream>>>(rows, cols, cursor, pos, colp, E);

        wprep_kernel<<<16, 256, 0, stream>>>(we_w2, wx_w1, we2t, wx1t);
        pre_kernel<<<(N + 255) / 256, 256, 0, stream>>>(h, we_w1, we_b1, Hr, Hc, N);

        edge_mfma_kernel<<<(E + 63) / 64, 256, 0, stream>>>(
            x, eattr, rows, cols, Hr, Hc,
            we_w1, we2t, we_b2, wx1t, wx_b1, wx_w2, wx_b2,
            pos, mij, px_s, E);

        agg_kernel<<<(N + 3) / 4, 256, 0, stream>>>(mij, px_s, colp, x, offs, mi, agg, N);

        node_kernel<256, true><<<(N + 255) / 256, 256, 0, stream>>>(
            h, x, vel,
            wh_w1, wh_b1, wh_w2, wh_b2,
            wv_w1, wv_b1, wv_w2, wv_b2,
            agg, nullptr, mi, out_h, out_x, out_v, N);
    } else {
        // --- fallback: atomic path ---
        float* agg2 = (float*)d_ws;               // N*3
        float* cnt2 = agg2 + (size_t)N * 3;       // N
        float* mi2  = cnt2 + N;                   // N*64
        hipMemsetAsync(d_ws, 0, (size_t)N * 68 * sizeof(float), stream);

        edge_atomic_kernel<128><<<(E + 127) / 128, 128, 0, stream>>>(
            h, x, eattr, rows, cols,
            we_w1, we_b1, we_w2, we_b2,
            wx_w1, wx_b1, wx_w2, wx_b2,
            agg2, cnt2, mi2, E);

        node_kernel<128, false><<<(N + 127) / 128, 128, 0, stream>>>(
            h, x, vel,
            wh_w1, wh_b1, wh_w2, wh_b2,
            wv_w1, wv_b1, wv_w2, wv_b2,
            agg2, cnt2, mi2, out_h, out_x, out_v, N);
    }
}

// Round 6
// 1424.609 us; speedup vs baseline: 4.4062x; 1.3617x over previous
//
#include <hip/hip_runtime.h>

// EGNN layer (CamadaEquivariante), round 6:
//  - pre_mfma: Hr=h@We1[0:64]+b1, Hc=h@We1[64:128] as bf16 MFMA GEMM; outputs
//    (bf16) live in d_out's out_h region as scratch (node kernel overwrites last).
//  - edge_mfma: iterates CSR SLOT order (rowp sorted -> Hr gather L2-friendly;
//    mij + trans writes fully sequential). trans=d*px staged via LDS, 3 bf16 planes.
//  - agg: one wave/node, all reads sequential, no indirection.
//  - node4: 4 threads/node, LDS tile exchange, shfl pv-reduce.
// launch_bounds(256,2) on hot kernels to avoid forced spills (r5: VGPR=64 cap).

typedef unsigned int uint;
typedef unsigned short u16;
typedef __attribute__((ext_vector_type(8))) short short8;
typedef __attribute__((ext_vector_type(4))) float f32x4;

#define UB_LO(u) __uint_as_float((u) << 16)
#define UB_HI(u) __uint_as_float((u) & 0xffff0000u)

__device__ __forceinline__ float fast_tanh(float x) {
    float e = __expf(2.0f * x);
    return 1.0f - 2.0f * __builtin_amdgcn_rcpf(e + 1.0f);
}
__device__ __forceinline__ u16 bf16rne(float f) {
    uint u = __float_as_uint(f);
    return (u16)((u + 0x7fffu + ((u >> 16) & 1u)) >> 16);
}
__device__ __forceinline__ uint packbf(float a, float b) {
    return (uint)bf16rne(a) | ((uint)bf16rne(b) << 16);
}
// XOR-swizzle within a [64][64]-bf16 (128B-row) LDS tile: byte ^= ((row&7)<<4)
__device__ __forceinline__ int swzb(int b) { return b ^ ((b >> 3) & 0x70); }

// ------------------------------------------------- weight transpose (bf16) ---
// we1t[j][k] (64x128), we2t[n][k] (64x64), wx1t[n][k] (64x64)
__global__ void wprep_kernel(const float* __restrict__ we_w1,
                             const float* __restrict__ we_w2,
                             const float* __restrict__ wx_w1,
                             u16* __restrict__ we1t, u16* __restrict__ we2t,
                             u16* __restrict__ wx1t) {
    int t = blockIdx.x * 256 + threadIdx.x;
    if (t < 8192) { int j = t >> 7, k = t & 127; we1t[j * 128 + k] = bf16rne(we_w1[k * 64 + j]); }
    if (t < 4096) {
        int n = t >> 6, k = t & 63;
        we2t[n * 64 + k] = bf16rne(we_w2[k * 64 + n]);
        wx1t[n * 64 + k] = bf16rne(wx_w1[k * 64 + n]);
    }
}

// --------------------------------------------------------- pre MFMA kernel ---
__global__ __launch_bounds__(256, 2)
void pre_mfma_kernel(const float* __restrict__ h, const float* __restrict__ we_b1,
                     const u16* __restrict__ we1t,
                     u16* __restrict__ HrB, u16* __restrict__ HcB, int N)
{
    __shared__ u16 X1[4096];
    __shared__ u16 X2[4096];
    const int tid = threadIdx.x, lane = tid & 63, wv = tid >> 6;
    const int nb = blockIdx.x * 64;
    const int el = tid >> 2, jg = tid & 3;
    const int fn = lane & 15, fk8 = (lane >> 4) * 8;

    // stage h tile (coalesced 64B/thread) -> X1 bf16 swizzled
    {
        uint pk[8];
        if (nb + el < N) {
            const float4* h4 = (const float4*)(h + (size_t)(nb + el) * 64 + jg * 16);
            #pragma unroll
            for (int q = 0; q < 4; q++) {
                float4 v = h4[q];
                pk[2*q]   = packbf(v.x, v.y);
                pk[2*q+1] = packbf(v.z, v.w);
            }
        } else {
            #pragma unroll
            for (int q = 0; q < 8; q++) pk[q] = 0;
        }
        const int b0 = swzb(el * 128 + jg * 32), b1 = swzb(el * 128 + jg * 32 + 16);
        *(uint4*)(&X1[b0 >> 1]) = make_uint4(pk[0], pk[1], pk[2], pk[3]);
        *(uint4*)(&X1[b1 >> 1]) = make_uint4(pk[4], pk[5], pk[6], pk[7]);
    }
    __syncthreads();

    const int mb = wv * 16;
    short8 a0, a1;
    {
        const int ba = swzb((mb + fn) * 128 + fk8 * 2);
        const int bb = swzb((mb + fn) * 128 + 64 + fk8 * 2);
        a0 = *(const short8*)(&X1[ba >> 1]);
        a1 = *(const short8*)(&X1[bb >> 1]);
    }
    // ---- Hr = h @ We1[0:64] + b1 ----
    #pragma unroll
    for (int n0 = 0; n0 < 4; n0++) {
        uint4 bw0 = *(const uint4*)(we1t + (n0*16 + fn) * 128 + fk8);
        uint4 bw1 = *(const uint4*)(we1t + (n0*16 + fn) * 128 + 32 + fk8);
        const float bias = we_b1[n0 * 16 + fn];
        f32x4 q = {bias, bias, bias, bias};
        q = __builtin_amdgcn_mfma_f32_16x16x32_bf16(a0, __builtin_bit_cast(short8, bw0), q, 0, 0, 0);
        q = __builtin_amdgcn_mfma_f32_16x16x32_bf16(a1, __builtin_bit_cast(short8, bw1), q, 0, 0, 0);
        #pragma unroll
        for (int r2 = 0; r2 < 4; r2++) {
            const int m = mb + (lane >> 4) * 4 + r2;
            X2[swzb(m * 128 + (n0*16 + fn) * 2) >> 1] = bf16rne(q[r2]);
        }
    }
    __syncthreads();
    if (nb + el < N) {
        const int b0 = swzb(el * 128 + jg * 32), b1 = swzb(el * 128 + jg * 32 + 16);
        uint4 v0 = *(const uint4*)(&X2[b0 >> 1]);
        uint4 v1 = *(const uint4*)(&X2[b1 >> 1]);
        u16* o = HrB + (size_t)(nb + el) * 64 + jg * 16;
        *(uint4*)o = v0; *(uint4*)(o + 8) = v1;
    }
    __syncthreads();
    // ---- Hc = h @ We1[64:128] ----
    #pragma unroll
    for (int n0 = 0; n0 < 4; n0++) {
        uint4 bw0 = *(const uint4*)(we1t + (n0*16 + fn) * 128 + 64 + fk8);
        uint4 bw1 = *(const uint4*)(we1t + (n0*16 + fn) * 128 + 96 + fk8);
        f32x4 q = {0.f, 0.f, 0.f, 0.f};
        q = __builtin_amdgcn_mfma_f32_16x16x32_bf16(a0, __builtin_bit_cast(short8, bw0), q, 0, 0, 0);
        q = __builtin_amdgcn_mfma_f32_16x16x32_bf16(a1, __builtin_bit_cast(short8, bw1), q, 0, 0, 0);
        #pragma unroll
        for (int r2 = 0; r2 < 4; r2++) {
            const int m = mb + (lane >> 4) * 4 + r2;
            X2[swzb(m * 128 + (n0*16 + fn) * 2) >> 1] = bf16rne(q[r2]);
        }
    }
    __syncthreads();
    if (nb + el < N) {
        const int b0 = swzb(el * 128 + jg * 32), b1 = swzb(el * 128 + jg * 32 + 16);
        uint4 v0 = *(const uint4*)(&X2[b0 >> 1]);
        uint4 v1 = *(const uint4*)(&X2[b1 >> 1]);
        u16* o = HcB + (size_t)(nb + el) * 64 + jg * 16;
        *(uint4*)o = v0; *(uint4*)(o + 8) = v1;
    }
}

// --------------------------------------------------------- edge MFMA kernel ---
// Iterates CSR slot order: s = sb + el; r=rowp[s] (sorted), c=colp[s], e=perm[s].
__global__ __launch_bounds__(256, 2)
void edge_mfma_kernel(const float* __restrict__ x, const float* __restrict__ eattr,
                      const int* __restrict__ perm, const int* __restrict__ rowp,
                      const int* __restrict__ colp,
                      const u16* __restrict__ HrB, const u16* __restrict__ HcB,
                      const float* __restrict__ we_w1,
                      const u16* __restrict__ we2t, const float* __restrict__ we_b2,
                      const u16* __restrict__ wx1t, const float* __restrict__ wx_b1,
                      const float* __restrict__ wx_w2, const float* __restrict__ wx_b2,
                      u16* __restrict__ mij,
                      u16* __restrict__ t0p, u16* __restrict__ t1p, u16* __restrict__ t2p,
                      int E)
{
    __shared__ u16 X1[4096];
    __shared__ u16 X2[4096];
    __shared__ float dS[64][3];
    __shared__ float pxS[64];

    const int tid = threadIdx.x, lane = tid & 63, wv = tid >> 6;
    const int sb = blockIdx.x * 64;
    const int fn = lane & 15, fk8 = (lane >> 4) * 8;

    const int el = tid >> 2, jg = tid & 3;
    const int s = sb + el;

    // ---- phase A: layer-1 activations -> X1 ----
    float acc[16];
    if (s < E) {
        const int r = rowp[s], c = colp[s], e = perm[s];
        const float d0 = x[(size_t)r*3+0] - x[(size_t)c*3+0];
        const float d1 = x[(size_t)r*3+1] - x[(size_t)c*3+1];
        const float d2 = x[(size_t)r*3+2] - x[(size_t)c*3+2];
        const float rad = d0*d0 + d1*d1 + d2*d2;
        if (jg == 0) { dS[el][0] = d0; dS[el][1] = d1; dS[el][2] = d2; }

        uint4 ra = *(const uint4*)(HrB + (size_t)r * 64 + jg * 16);
        uint4 rb = *(const uint4*)(HrB + (size_t)r * 64 + jg * 16 + 8);
        uint4 ca = *(const uint4*)(HcB + (size_t)c * 64 + jg * 16);
        uint4 cb = *(const uint4*)(HcB + (size_t)c * 64 + jg * 16 + 8);
        uint rw[8] = {ra.x, ra.y, ra.z, ra.w, rb.x, rb.y, rb.z, rb.w};
        uint cw[8] = {ca.x, ca.y, ca.z, ca.w, cb.x, cb.y, cb.z, cb.w};
        const float* wrad = we_w1 + 128 * 64 + jg * 16;
        #pragma unroll
        for (int i = 0; i < 16; i++) {
            const float hr = (i & 1) ? UB_HI(rw[i >> 1]) : UB_LO(rw[i >> 1]);
            const float hc = (i & 1) ? UB_HI(cw[i >> 1]) : UB_LO(cw[i >> 1]);
            acc[i] = hr + hc + rad * wrad[i];
        }
        const float4* ea4 = (const float4*)(eattr + (size_t)e * 8);
        float4 v0 = ea4[0], v1 = ea4[1];
        float ea[8] = {v0.x, v0.y, v0.z, v0.w, v1.x, v1.y, v1.z, v1.w};
        #pragma unroll
        for (int k = 0; k < 8; k++) {
            const float* w = we_w1 + (129 + k) * 64 + jg * 16;
            #pragma unroll
            for (int i = 0; i < 16; i++) acc[i] += ea[k] * w[i];
        }
        #pragma unroll
        for (int i = 0; i < 16; i++) acc[i] = fast_tanh(acc[i]);
    } else {
        #pragma unroll
        for (int i = 0; i < 16; i++) acc[i] = 0.0f;
    }
    {
        uint pk[8];
        #pragma unroll
        for (int q = 0; q < 8; q++) pk[q] = packbf(acc[2*q], acc[2*q+1]);
        const int b0 = swzb(el * 128 + jg * 32), b1 = swzb(el * 128 + jg * 32 + 16);
        *(uint4*)(&X1[b0 >> 1]) = make_uint4(pk[0], pk[1], pk[2], pk[3]);
        *(uint4*)(&X1[b1 >> 1]) = make_uint4(pk[4], pk[5], pk[6], pk[7]);
    }
    __syncthreads();

    // ---- layer 2 MFMA: X2 = tanh(X1 @ We2 + b2) ----
    const int mb = wv * 16;
    short8 a0, a1;
    {
        const int ba = swzb((mb + fn) * 128 + fk8 * 2);
        const int bb = swzb((mb + fn) * 128 + 64 + fk8 * 2);
        a0 = *(const short8*)(&X1[ba >> 1]);
        a1 = *(const short8*)(&X1[bb >> 1]);
    }
    #pragma unroll
    for (int n0 = 0; n0 < 4; n0++) {
        uint4 bw0 = *(const uint4*)(we2t + (n0*16 + fn) * 64 + fk8);
        uint4 bw1 = *(const uint4*)(we2t + (n0*16 + fn) * 64 + 32 + fk8);
        const float bias = we_b2[n0 * 16 + fn];
        f32x4 q = {bias, bias, bias, bias};
        q = __builtin_amdgcn_mfma_f32_16x16x32_bf16(a0, __builtin_bit_cast(short8, bw0), q, 0, 0, 0);
        q = __builtin_amdgcn_mfma_f32_16x16x32_bf16(a1, __builtin_bit_cast(short8, bw1), q, 0, 0, 0);
        #pragma unroll
        for (int r2 = 0; r2 < 4; r2++) {
            const int m = mb + (lane >> 4) * 4 + r2;
            X2[swzb(m * 128 + (n0*16 + fn) * 2) >> 1] = bf16rne(fast_tanh(q[r2]));
        }
    }
    __syncthreads();

    // ---- mij write: slot-sequential, fully coalesced ----
    {
        const int b0 = swzb(el * 128 + jg * 32), b1 = swzb(el * 128 + jg * 32 + 16);
        uint4 v0 = *(const uint4*)(&X2[b0 >> 1]);
        uint4 v1 = *(const uint4*)(&X2[b1 >> 1]);
        if (s < E) {
            u16* mo = mij + (size_t)s * 64 + jg * 16;
            *(uint4*)(mo) = v0;
            *(uint4*)(mo + 8) = v1;
        }
    }

    // ---- phi_x: S = X2 @ Wx1 + b1; px = tanh(tanh(S) @ wx2 + b2) ----
    short8 c0, c1;
    {
        const int ba = swzb((mb + fn) * 128 + fk8 * 2);
        const int bb = swzb((mb + fn) * 128 + 64 + fk8 * 2);
        c0 = *(const short8*)(&X2[ba >> 1]);
        c1 = *(const short8*)(&X2[bb >> 1]);
    }
    float pxp[4] = {0.f, 0.f, 0.f, 0.f};
    #pragma unroll
    for (int n0 = 0; n0 < 4; n0++) {
        uint4 bw0 = *(const uint4*)(wx1t + (n0*16 + fn) * 64 + fk8);
        uint4 bw1 = *(const uint4*)(wx1t + (n0*16 + fn) * 64 + 32 + fk8);
        const float bias = wx_b1[n0 * 16 + fn];
        f32x4 q = {bias, bias, bias, bias};
        q = __builtin_amdgcn_mfma_f32_16x16x32_bf16(c0, __builtin_bit_cast(short8, bw0), q, 0, 0, 0);
        q = __builtin_amdgcn_mfma_f32_16x16x32_bf16(c1, __builtin_bit_cast(short8, bw1), q, 0, 0, 0);
        const float wqn = wx_w2[n0 * 16 + fn];
        #pragma unroll
        for (int r2 = 0; r2 < 4; r2++) pxp[r2] += fast_tanh(q[r2]) * wqn;
    }
    #pragma unroll
    for (int off = 1; off < 16; off <<= 1) {
        #pragma unroll
        for (int r2 = 0; r2 < 4; r2++) pxp[r2] += __shfl_xor(pxp[r2], off, 64);
    }
    if (fn == 0) {
        const float bx2 = wx_b2[0];
        #pragma unroll
        for (int r2 = 0; r2 < 4; r2++) {
            const int m = mb + (lane >> 4) * 4 + r2;
            pxS[m] = fast_tanh(pxp[r2] + bx2);
        }
    }
    __syncthreads();

    // ---- trans = d * px, 3 bf16 planes, slot-sequential ----
    if (tid < 64 && sb + tid < E) {
        const float px = pxS[tid];
        t0p[sb + tid] = bf16rne(dS[tid][0] * px);
        t1p[sb + tid] = bf16rne(dS[tid][1] * px);
        t2p[sb + tid] = bf16rne(dS[tid][2] * px);
    }
}

// ---------------------------------------------------------------- CSR build ---
__global__ void hist_kernel(const int* __restrict__ rows, int* __restrict__ hist, int E) {
    int e = blockIdx.x * blockDim.x + threadIdx.x;
    if (e < E) atomicAdd(&hist[rows[e]], 1);
}

__global__ __launch_bounds__(1024)
void scan_kernel(const int* __restrict__ hist, int* __restrict__ offs,
                 int* __restrict__ cursor, int N) {
    const int tid = threadIdx.x;
    const int chunk = (N + 1023) / 1024;
    const int beg = tid * chunk;
    const int end = (beg + chunk < N) ? beg + chunk : N;

    int s = 0;
    for (int i = beg; i < end; i++) s += hist[i];

    __shared__ int wsum[16];
    const int lane = tid & 63, wid = tid >> 6;
    int inc = s;
    #pragma unroll
    for (int off = 1; off < 64; off <<= 1) {
        int t = __shfl_up(inc, off, 64);
        if (lane >= off) inc += t;
    }
    if (lane == 63) wsum[wid] = inc;
    __syncthreads();
    if (wid == 0 && lane < 16) {
        int v = wsum[lane];
        #pragma unroll
        for (int off = 1; off < 16; off <<= 1) {
            int t = __shfl_up(v, off, 64);
            if (lane >= off) v += t;
        }
        wsum[lane] = v;
    }
    __syncthreads();
    const int wbase = (wid > 0) ? wsum[wid - 1] : 0;
    int run = wbase + inc - s;
    for (int i = beg; i < end; i++) {
        cursor[i] = run;
        run += hist[i];
        offs[i + 1] = run;
    }
    if (tid == 0) offs[0] = 0;
}

// scatter: perm[slot]=e, rowp[slot]=row, colp[slot]=col
__global__ void scatter_kernel(const int* __restrict__ rows, const int* __restrict__ cols,
                               int* __restrict__ cursor,
                               int* __restrict__ perm, int* __restrict__ rowp,
                               int* __restrict__ colp, int E) {
    int e = blockIdx.x * blockDim.x + threadIdx.x;
    if (e < E) {
        int r = rows[e];
        int p = atomicAdd(&cursor[r], 1);
        perm[p] = e;
        rowp[p] = r;
        colp[p] = cols[e];
    }
}

// ------------------------------------------------------------- aggregation ---
// one wave per node; ALL reads sequential (slot order)
__global__ __launch_bounds__(256)
void agg_kernel(const u16* __restrict__ mij,
                const u16* __restrict__ t0p, const u16* __restrict__ t1p,
                const u16* __restrict__ t2p,
                const int* __restrict__ offs,
                float* __restrict__ mi, float* __restrict__ agg, int N)
{
    const int lane = threadIdx.x & 63;
    const int n = blockIdx.x * 4 + (threadIdx.x >> 6);
    if (n >= N) return;

    const int beg = __builtin_amdgcn_readfirstlane(offs[n]);
    const int end = __builtin_amdgcn_readfirstlane(offs[n + 1]);

    const u16* tp = (lane == 0) ? t0p : (lane == 1) ? t1p : t2p;

    float msum = 0.0f, tsum = 0.0f;
    for (int i = beg; i < end; i++) {
        msum += UB_LO((uint)mij[(size_t)i * 64 + lane]);
        if (lane < 3) tsum += UB_LO((uint)tp[i]);
    }
    mi[(size_t)n * 64 + lane] = msum;
    if (lane < 3) {
        const float cf = (float)(end - beg);
        agg[(size_t)n * 3 + lane] = tsum / fmaxf(cf, 1.0f);
    }
}

// ---------------------------------------------------- node update (4 thr/n) ---
__global__ __launch_bounds__(256, 2)
void node4_kernel(const float* __restrict__ h, const float* __restrict__ x,
                  const float* __restrict__ vel,
                  const float* __restrict__ wh_w1, const float* __restrict__ wh_b1,
                  const float* __restrict__ wh_w2, const float* __restrict__ wh_b2,
                  const float* __restrict__ wv_w1, const float* __restrict__ wv_b1,
                  const float* __restrict__ wv_w2, const float* __restrict__ wv_b2,
                  const float* __restrict__ agg, const float* __restrict__ mi,
                  float* __restrict__ out_h, float* __restrict__ out_x,
                  float* __restrict__ out_v, int N)
{
    __shared__ uint hT[64 * 36];   // [node][32 packed + 4 pad] -> bank-safe
    __shared__ uint mT[64 * 36];
    __shared__ uint aT[64 * 36];
    const int tid = threadIdx.x;
    const int nl = tid >> 2, jg = tid & 3;
    const int n = blockIdx.x * 64 + nl;

    // stage h/mi tiles (coalesced 64B/thread)
    {
        uint pk[8], qk[8];
        if (n < N) {
            const float4* h4 = (const float4*)(h  + (size_t)n * 64 + jg * 16);
            const float4* m4 = (const float4*)(mi + (size_t)n * 64 + jg * 16);
            #pragma unroll
            for (int q = 0; q < 4; q++) {
                float4 a = h4[q]; pk[2*q] = packbf(a.x, a.y); pk[2*q+1] = packbf(a.z, a.w);
                float4 b = m4[q]; qk[2*q] = packbf(b.x, b.y); qk[2*q+1] = packbf(b.z, b.w);
            }
        } else {
            #pragma unroll
            for (int q = 0; q < 8; q++) { pk[q] = 0; qk[q] = 0; }
        }
        uint4* hp = (uint4*)&hT[nl * 36 + jg * 8];
        hp[0] = make_uint4(pk[0], pk[1], pk[2], pk[3]);
        hp[1] = make_uint4(pk[4], pk[5], pk[6], pk[7]);
        uint4* mp = (uint4*)&mT[nl * 36 + jg * 8];
        mp[0] = make_uint4(qk[0], qk[1], qk[2], qk[3]);
        mp[1] = make_uint4(qk[4], qk[5], qk[6], qk[7]);
    }
    __syncthreads();

    // ---- phi_v: quarter outputs per thread, shfl-reduce over jg ----
    float pv = 0.0f;
    {
        float acc[16];
        #pragma unroll
        for (int i = 0; i < 16; i++) acc[i] = wv_b1[jg * 16 + i];
        #pragma unroll
        for (int k = 0; k < 64; k++) {
            const uint u = hT[nl * 36 + (k >> 1)];
            const float a = (k & 1) ? UB_HI(u) : UB_LO(u);
            const float* w = wv_w1 + k * 64 + jg * 16;
            #pragma unroll
            for (int i = 0; i < 16; i++) acc[i] += a * w[i];
        }
        #pragma unroll
        for (int i = 0; i < 16; i++) pv += fast_tanh(acc[i]) * wv_w2[jg * 16 + i];
    }
    pv += __shfl_xor(pv, 1, 64);
    pv += __shfl_xor(pv, 2, 64);
    pv += wv_b2[0];

    // ---- phi_h layer 1 -> aT (bf16 packed) ----
    {
        float acc[16];
        #pragma unroll
        for (int i = 0; i < 16; i++) acc[i] = wh_b1[jg * 16 + i];
        #pragma unroll
        for (int k = 0; k < 64; k++) {
            const uint uh = hT[nl * 36 + (k >> 1)];
            const uint um = mT[nl * 36 + (k >> 1)];
            const float a0 = (k & 1) ? UB_HI(uh) : UB_LO(uh);
            const float a1 = (k & 1) ? UB_HI(um) : UB_LO(um);
            const float* w0 = wh_w1 + k * 64 + jg * 16;
            const float* w1 = wh_w1 + (64 + k) * 64 + jg * 16;
            #pragma unroll
            for (int i = 0; i < 16; i++) acc[i] += a0 * w0[i] + a1 * w1[i];
        }
        uint4* ap = (uint4*)&aT[nl * 36 + jg * 8];
        uint pk[8];
        #pragma unroll
        for (int q = 0; q < 8; q++) pk[q] = packbf(fast_tanh(acc[2*q]), fast_tanh(acc[2*q+1]));
        ap[0] = make_uint4(pk[0], pk[1], pk[2], pk[3]);
        ap[1] = make_uint4(pk[4], pk[5], pk[6], pk[7]);
    }
    __syncthreads();

    // ---- phi_h layer 2 -> out_h ----
    {
        float acc[16];
        #pragma unroll
        for (int i = 0; i < 16; i++) acc[i] = wh_b2[jg * 16 + i];
        #pragma unroll
        for (int k = 0; k < 64; k++) {
            const uint u = aT[nl * 36 + (k >> 1)];
            const float a = (k & 1) ? UB_HI(u) : UB_LO(u);
            const float* w = wh_w2 + k * 64 + jg * 16;
            #pragma unroll
            for (int i = 0; i < 16; i++) acc[i] += a * w[i];
        }
        if (n < N) {
            float4* o = (float4*)(out_h + (size_t)n * 64 + jg * 16);
            #pragma unroll
            for (int q = 0; q < 4; q++) o[q] = make_float4(acc[4*q], acc[4*q+1], acc[4*q+2], acc[4*q+3]);
        }
    }

    // ---- coordinate / velocity update ----
    if (jg == 0 && n < N) {
        #pragma unroll
        for (int d = 0; d < 3; d++) {
            const float am = agg[(size_t)n * 3 + d];
            const float vn = vel[(size_t)n * 3 + d] * pv + am;
            out_v[(size_t)n * 3 + d] = vn;
            out_x[(size_t)n * 3 + d] = x[(size_t)n * 3 + d] + vn;
        }
    }
}

// ------------------------------------------- fallback kernels (atomic path) ---
template<int BLK>
__global__ __launch_bounds__(BLK)
void edge_atomic_kernel(const float* __restrict__ h, const float* __restrict__ x,
                 const float* __restrict__ eattr,
                 const int* __restrict__ rows, const int* __restrict__ cols,
                 const float* __restrict__ we_w1, const float* __restrict__ we_b1,
                 const float* __restrict__ we_w2, const float* __restrict__ we_b2,
                 const float* __restrict__ wx_w1, const float* __restrict__ wx_b1,
                 const float* __restrict__ wx_w2, const float* __restrict__ wx_b2,
                 float* __restrict__ agg, float* __restrict__ cnt, float* __restrict__ mi,
                 int E)
{
    __shared__ float act[64][BLK];
    const int tid = threadIdx.x;
    const int e = blockIdx.x * BLK + tid;
    if (e >= E) return;

    const int r = rows[e];
    const int c = cols[e];
    const float d0 = x[(size_t)r*3+0] - x[(size_t)c*3+0];
    const float d1 = x[(size_t)r*3+1] - x[(size_t)c*3+1];
    const float d2 = x[(size_t)r*3+2] - x[(size_t)c*3+2];
    const float rad = d0*d0 + d1*d1 + d2*d2;

    float A[64];
    #pragma unroll
    for (int j = 0; j < 64; j++) A[j] = we_b1[j];
    const float* hr = h + (size_t)r * 64;
    const float* hc = h + (size_t)c * 64;
    #pragma unroll 4
    for (int k = 0; k < 64; k++) {
        const float a0 = hr[k];
        const float a1 = hc[k];
        const float* w0 = we_w1 + k * 64;
        const float* w1 = we_w1 + (64 + k) * 64;
        #pragma unroll
        for (int j = 0; j < 64; j++) A[j] += a0 * w0[j] + a1 * w1[j];
    }
    {
        const float* w = we_w1 + 128 * 64;
        #pragma unroll
        for (int j = 0; j < 64; j++) A[j] += rad * w[j];
    }
    const float* ea = eattr + (size_t)e * 8;
    #pragma unroll
    for (int k = 0; k < 8; k++) {
        const float a = ea[k];
        const float* w = we_w1 + (129 + k) * 64;
        #pragma unroll
        for (int j = 0; j < 64; j++) A[j] += a * w[j];
    }
    #pragma unroll
    for (int j = 0; j < 64; j++) act[j][tid] = fast_tanh(A[j]);

    float B[64];
    #pragma unroll
    for (int j = 0; j < 64; j++) B[j] = we_b2[j];
    #pragma unroll 4
    for (int k = 0; k < 64; k++) {
        const float a = act[k][tid];
        const float* w = we_w2 + k * 64;
        #pragma unroll
        for (int j = 0; j < 64; j++) B[j] += a * w[j];
    }
    #pragma unroll
    for (int j = 0; j < 64; j++) act[j][tid] = fast_tanh(B[j]);

    #pragma unroll
    for (int j = 0; j < 64; j++) A[j] = wx_b1[j];
    #pragma unroll 4
    for (int k = 0; k < 64; k++) {
        const float a = act[k][tid];
        const float* w = wx_w1 + k * 64;
        #pragma unroll
        for (int j = 0; j < 64; j++) A[j] += a * w[j];
    }
    float px = wx_b2[0];
    #pragma unroll
    for (int j = 0; j < 64; j++) px += fast_tanh(A[j]) * wx_w2[j];
    px = fast_tanh(px);

    atomicAdd(&agg[(size_t)r*3+0], d0 * px);
    atomicAdd(&agg[(size_t)r*3+1], d1 * px);
    atomicAdd(&agg[(size_t)r*3+2], d2 * px);
    atomicAdd(&cnt[r], 1.0f);
    float* mir = mi + (size_t)r * 64;
    #pragma unroll
    for (int j = 0; j < 64; j++) atomicAdd(&mir[j], act[j][tid]);
}

template<int BLK>
__global__ __launch_bounds__(BLK, 2)
void node_fb_kernel(const float* __restrict__ h, const float* __restrict__ x,
                 const float* __restrict__ vel,
                 const float* __restrict__ wh_w1, const float* __restrict__ wh_b1,
                 const float* __restrict__ wh_w2, const float* __restrict__ wh_b2,
                 const float* __restrict__ wv_w1, const float* __restrict__ wv_b1,
                 const float* __restrict__ wv_w2, const float* __restrict__ wv_b2,
                 const float* __restrict__ agg, const float* __restrict__ cnt,
                 const float* __restrict__ mi,
                 float* __restrict__ out_h, float* __restrict__ out_x, float* __restrict__ out_v,
                 int N)
{
    const int n = blockIdx.x * BLK + threadIdx.x;
    if (n >= N) return;

    const float* hn = h + (size_t)n * 64;
    const float* mn = mi + (size_t)n * 64;

    float A[64];
    #pragma unroll
    for (int j = 0; j < 64; j++) A[j] = wv_b1[j];
    #pragma unroll
    for (int k = 0; k < 64; k++) {
        const float a = hn[k];
        const float* w = wv_w1 + k * 64;
        #pragma unroll
        for (int j = 0; j < 64; j++) A[j] += a * w[j];
    }
    float pv = wv_b2[0];
    #pragma unroll
    for (int j = 0; j < 64; j++) pv += fast_tanh(A[j]) * wv_w2[j];

    #pragma unroll
    for (int j = 0; j < 64; j++) A[j] = wh_b1[j];
    #pragma unroll
    for (int k = 0; k < 64; k++) {
        const float a0 = hn[k];
        const float a1 = mn[k];
        const float* w0 = wh_w1 + k * 64;
        const float* w1 = wh_w1 + (64 + k) * 64;
        #pragma unroll
        for (int j = 0; j < 64; j++) A[j] += a0 * w0[j] + a1 * w1[j];
    }
    #pragma unroll
    for (int j = 0; j < 64; j++) A[j] = fast_tanh(A[j]);

    float B[64];
    #pragma unroll
    for (int j = 0; j < 64; j++) B[j] = wh_b2[j];
    #pragma unroll
    for (int k = 0; k < 64; k++) {
        const float a = A[k];
        const float* w = wh_w2 + k * 64;
        #pragma unroll
        for (int j = 0; j < 64; j++) B[j] += a * w[j];
    }
    float* oh = out_h + (size_t)n * 64;
    #pragma unroll
    for (int j = 0; j < 64; j++) oh[j] = B[j];

    const float inv = 1.0f / fmaxf(cnt[n], 1.0f);
    #pragma unroll
    for (int d = 0; d < 3; d++) {
        const float am = agg[(size_t)n*3 + d] * inv;
        const float vn = vel[(size_t)n*3 + d] * pv + am;
        out_v[(size_t)n*3 + d] = vn;
        out_x[(size_t)n*3 + d] = x[(size_t)n*3 + d] + vn;
    }
}

// ------------------------------------------------------------------ launch ---
extern "C" void kernel_launch(void* const* d_in, const int* in_sizes, int n_in,
                              void* d_out, int out_size, void* d_ws, size_t ws_size,
                              hipStream_t stream) {
    const float* h      = (const float*)d_in[0];
    const float* x      = (const float*)d_in[1];
    const float* vel    = (const float*)d_in[2];
    const float* eattr  = (const float*)d_in[3];
    const float* we_w1  = (const float*)d_in[4];
    const float* we_b1  = (const float*)d_in[5];
    const float* we_w2  = (const float*)d_in[6];
    const float* we_b2  = (const float*)d_in[7];
    const float* wx_w1  = (const float*)d_in[8];
    const float* wx_b1  = (const float*)d_in[9];
    const float* wx_w2  = (const float*)d_in[10];
    const float* wx_b2  = (const float*)d_in[11];
    const float* wh_w1  = (const float*)d_in[12];
    const float* wh_b1  = (const float*)d_in[13];
    const float* wh_w2  = (const float*)d_in[14];
    const float* wh_b2  = (const float*)d_in[15];
    const float* wv_w1  = (const float*)d_in[16];
    const float* wv_b1  = (const float*)d_in[17];
    const float* wv_w2  = (const float*)d_in[18];
    const float* wv_b2  = (const float*)d_in[19];
    const int*   ar     = (const int*)d_in[20];

    const int N = in_sizes[0] / 64;
    const int E = in_sizes[20] / 2;
    const int* rows = ar;
    const int* cols = ar + E;

    float* out_h = (float*)d_out;            // N*64 (HrB/HcB bf16 scratch first)
    float* out_x = out_h + (size_t)N * 64;   // N*3
    float* out_v = out_x + (size_t)N * 3;    // N*3

    // HrB (bf16 N*64) + HcB (bf16 N*64) exactly fill the out_h f32 region.
    u16* HrB = (u16*)d_out;
    u16* HcB = HrB + (size_t)N * 64;

    // --- workspace layout: ~260.6 MB ---
    char* p = (char*)d_ws;
    auto align64 = [&]() { p = (char*)(((uintptr_t)p + 63) & ~(uintptr_t)63); };
    u16*  mij  = (u16*)p;   p += (size_t)E * 64 * sizeof(u16);
    u16*  t0p  = (u16*)p;   p += (size_t)E * sizeof(u16);
    u16*  t1p  = (u16*)p;   p += (size_t)E * sizeof(u16);
    u16*  t2p  = (u16*)p;   p += (size_t)E * sizeof(u16);
    float* mi  = (float*)p; p += (size_t)N * 64 * sizeof(float);
    float* agg = (float*)p; p += (size_t)N * 3 * sizeof(float);
    int*  perm = (int*)p;   p += (size_t)E * sizeof(int);
    int*  rowp = (int*)p;   p += (size_t)E * sizeof(int);
    int*  colp = (int*)p;   p += (size_t)E * sizeof(int);
    int*  offs = (int*)p;   p += (size_t)(N + 1) * sizeof(int);
    int*  cursor = (int*)p; p += (size_t)N * sizeof(int);
    int*  hist = (int*)p;   p += (size_t)N * sizeof(int);
    align64();
    u16*  we1t = (u16*)p;   p += 64 * 128 * sizeof(u16);
    u16*  we2t = (u16*)p;   p += 64 * 64 * sizeof(u16);
    u16*  wx1t = (u16*)p;   p += 64 * 64 * sizeof(u16);
    const size_t needed = (size_t)(p - (char*)d_ws);

    if (ws_size >= needed) {
        hipMemsetAsync(hist, 0, (size_t)N * sizeof(int), stream);
        hist_kernel<<<(E + 255) / 256, 256, 0, stream>>>(rows, hist, E);
        scan_kernel<<<1, 1024, 0, stream>>>(hist, offs, cursor, N);
        scatter_kernel<<<(E + 255) / 256, 256, 0, stream>>>(rows, cols, cursor, perm, rowp, colp, E);

        wprep_kernel<<<32, 256, 0, stream>>>(we_w1, we_w2, wx_w1, we1t, we2t, wx1t);
        pre_mfma_kernel<<<(N + 63) / 64, 256, 0, stream>>>(h, we_b1, we1t, HrB, HcB, N);

        edge_mfma_kernel<<<(E + 63) / 64, 256, 0, stream>>>(
            x, eattr, perm, rowp, colp, HrB, HcB,
            we_w1, we2t, we_b2, wx1t, wx_b1, wx_w2, wx_b2,
            mij, t0p, t1p, t2p, E);

        agg_kernel<<<(N + 3) / 4, 256, 0, stream>>>(mij, t0p, t1p, t2p, offs, mi, agg, N);

        node4_kernel<<<(N + 63) / 64, 256, 0, stream>>>(
            h, x, vel,
            wh_w1, wh_b1, wh_w2, wh_b2,
            wv_w1, wv_b1, wv_w2, wv_b2,
            agg, mi, out_h, out_x, out_v, N);
    } else {
        // --- fallback: atomic path ---
        float* agg2 = (float*)d_ws;               // N*3
        float* cnt2 = agg2 + (size_t)N * 3;       // N
        float* mi2  = cnt2 + N;                   // N*64
        hipMemsetAsync(d_ws, 0, (size_t)N * 68 * sizeof(float), stream);

        edge_atomic_kernel<128><<<(E + 127) / 128, 128, 0, stream>>>(
            h, x, eattr, rows, cols,
            we_w1, we_b1, we_w2, we_b2,
            wx_w1, wx_b1, wx_w2, wx_b2,
            agg2, cnt2, mi2, E);

        node_fb_kernel<128><<<(N + 127) / 128, 128, 0, stream>>>(
            h, x, vel,
            wh_w1, wh_b1, wh_w2, wh_b2,
            wv_w1, wv_b1, wv_w2, wv_b2,
            agg2, cnt2, mi2, out_h, out_x, out_v, N);
    }
}

// Round 7
// 1027.264 us; speedup vs baseline: 6.1105x; 1.3868x over previous
//
#include <hip/hip_runtime.h>

// EGNN layer (CamadaEquivariante), round 7:
//  - pre_mfma: Hr/Hc bf16 MFMA GEMM (outputs in d_out scratch).       [r6, kept]
//  - edge_mfma: CSR-slot-order MFMA edge MLP, sequential mij/trans.   [r6, kept]
//  - aggnode (NEW): fused aggregation + node MLPs. 64 nodes/block:
//      phase1: wave w segment-sums nodes [w*16,w*16+16) -> mi tile in LDS (bf16)
//      phase2: phi_v / phi_h1(K=128) / phi_h2 as 16x16x32 bf16 MFMAs;
//      pv via shfl reduce; x/v update at end. mi never materialized in HBM.
//  - scatter writes perm+colp only; rowp filled sequentially (rowfill).
// ws ~= 235 MB. Fallback to atomic path if ws too small.

typedef unsigned int uint;
typedef unsigned short u16;
typedef __attribute__((ext_vector_type(8))) short short8;
typedef __attribute__((ext_vector_type(4))) float f32x4;

#define UB_LO(u) __uint_as_float((u) << 16)
#define UB_HI(u) __uint_as_float((u) & 0xffff0000u)

__device__ __forceinline__ float fast_tanh(float x) {
    float e = __expf(2.0f * x);
    return 1.0f - 2.0f * __builtin_amdgcn_rcpf(e + 1.0f);
}
__device__ __forceinline__ u16 bf16rne(float f) {
    uint u = __float_as_uint(f);
    return (u16)((u + 0x7fffu + ((u >> 16) & 1u)) >> 16);
}
__device__ __forceinline__ uint packbf(float a, float b) {
    return (uint)bf16rne(a) | ((uint)bf16rne(b) << 16);
}
// XOR-swizzle within a [64][64]-bf16 (128B-row) LDS tile: byte ^= ((row&7)<<4)
__device__ __forceinline__ int swzb(int b) { return b ^ ((b >> 3) & 0x70); }

// ------------------------------------------------- weight transpose (bf16) ---
__global__ void wprep_kernel(const float* __restrict__ we_w1, const float* __restrict__ we_w2,
                             const float* __restrict__ wx_w1, const float* __restrict__ wv_w1,
                             const float* __restrict__ wh_w1, const float* __restrict__ wh_w2,
                             u16* __restrict__ we1t, u16* __restrict__ we2t,
                             u16* __restrict__ wx1t, u16* __restrict__ wv1t,
                             u16* __restrict__ wh1t, u16* __restrict__ wh2t) {
    int t = blockIdx.x * 256 + threadIdx.x;
    if (t < 8192) {
        int j = t >> 7, k = t & 127;
        we1t[t] = bf16rne(we_w1[k * 64 + j]);
        wh1t[t] = bf16rne(wh_w1[k * 64 + j]);
    }
    if (t < 4096) {
        int n = t >> 6, k = t & 63;
        we2t[t] = bf16rne(we_w2[k * 64 + n]);
        wx1t[t] = bf16rne(wx_w1[k * 64 + n]);
        wv1t[t] = bf16rne(wv_w1[k * 64 + n]);
        wh2t[t] = bf16rne(wh_w2[k * 64 + n]);
    }
}

// --------------------------------------------------------- pre MFMA kernel ---
__global__ __launch_bounds__(256, 2)
void pre_mfma_kernel(const float* __restrict__ h, const float* __restrict__ we_b1,
                     const u16* __restrict__ we1t,
                     u16* __restrict__ HrB, u16* __restrict__ HcB, int N)
{
    __shared__ u16 X1[4096];
    __shared__ u16 X2[4096];
    const int tid = threadIdx.x, lane = tid & 63, wv = tid >> 6;
    const int nb = blockIdx.x * 64;
    const int el = tid >> 2, jg = tid & 3;
    const int fn = lane & 15, fk8 = (lane >> 4) * 8;

    {
        uint pk[8];
        if (nb + el < N) {
            const float4* h4 = (const float4*)(h + (size_t)(nb + el) * 64 + jg * 16);
            #pragma unroll
            for (int q = 0; q < 4; q++) {
                float4 v = h4[q];
                pk[2*q]   = packbf(v.x, v.y);
                pk[2*q+1] = packbf(v.z, v.w);
            }
        } else {
            #pragma unroll
            for (int q = 0; q < 8; q++) pk[q] = 0;
        }
        const int b0 = swzb(el * 128 + jg * 32), b1 = swzb(el * 128 + jg * 32 + 16);
        *(uint4*)(&X1[b0 >> 1]) = make_uint4(pk[0], pk[1], pk[2], pk[3]);
        *(uint4*)(&X1[b1 >> 1]) = make_uint4(pk[4], pk[5], pk[6], pk[7]);
    }
    __syncthreads();

    const int mb = wv * 16;
    short8 a0, a1;
    {
        const int ba = swzb((mb + fn) * 128 + fk8 * 2);
        const int bb = swzb((mb + fn) * 128 + 64 + fk8 * 2);
        a0 = *(const short8*)(&X1[ba >> 1]);
        a1 = *(const short8*)(&X1[bb >> 1]);
    }
    // Hr = h @ We1[0:64] + b1
    #pragma unroll
    for (int n0 = 0; n0 < 4; n0++) {
        uint4 bw0 = *(const uint4*)(we1t + (n0*16 + fn) * 128 + fk8);
        uint4 bw1 = *(const uint4*)(we1t + (n0*16 + fn) * 128 + 32 + fk8);
        const float bias = we_b1[n0 * 16 + fn];
        f32x4 q = {bias, bias, bias, bias};
        q = __builtin_amdgcn_mfma_f32_16x16x32_bf16(a0, __builtin_bit_cast(short8, bw0), q, 0, 0, 0);
        q = __builtin_amdgcn_mfma_f32_16x16x32_bf16(a1, __builtin_bit_cast(short8, bw1), q, 0, 0, 0);
        #pragma unroll
        for (int r2 = 0; r2 < 4; r2++) {
            const int m = mb + (lane >> 4) * 4 + r2;
            X2[swzb(m * 128 + (n0*16 + fn) * 2) >> 1] = bf16rne(q[r2]);
        }
    }
    __syncthreads();
    if (nb + el < N) {
        const int b0 = swzb(el * 128 + jg * 32), b1 = swzb(el * 128 + jg * 32 + 16);
        uint4 v0 = *(const uint4*)(&X2[b0 >> 1]);
        uint4 v1 = *(const uint4*)(&X2[b1 >> 1]);
        u16* o = HrB + (size_t)(nb + el) * 64 + jg * 16;
        *(uint4*)o = v0; *(uint4*)(o + 8) = v1;
    }
    __syncthreads();
    // Hc = h @ We1[64:128]
    #pragma unroll
    for (int n0 = 0; n0 < 4; n0++) {
        uint4 bw0 = *(const uint4*)(we1t + (n0*16 + fn) * 128 + 64 + fk8);
        uint4 bw1 = *(const uint4*)(we1t + (n0*16 + fn) * 128 + 96 + fk8);
        f32x4 q = {0.f, 0.f, 0.f, 0.f};
        q = __builtin_amdgcn_mfma_f32_16x16x32_bf16(a0, __builtin_bit_cast(short8, bw0), q, 0, 0, 0);
        q = __builtin_amdgcn_mfma_f32_16x16x32_bf16(a1, __builtin_bit_cast(short8, bw1), q, 0, 0, 0);
        #pragma unroll
        for (int r2 = 0; r2 < 4; r2++) {
            const int m = mb + (lane >> 4) * 4 + r2;
            X2[swzb(m * 128 + (n0*16 + fn) * 2) >> 1] = bf16rne(q[r2]);
        }
    }
    __syncthreads();
    if (nb + el < N) {
        const int b0 = swzb(el * 128 + jg * 32), b1 = swzb(el * 128 + jg * 32 + 16);
        uint4 v0 = *(const uint4*)(&X2[b0 >> 1]);
        uint4 v1 = *(const uint4*)(&X2[b1 >> 1]);
        u16* o = HcB + (size_t)(nb + el) * 64 + jg * 16;
        *(uint4*)o = v0; *(uint4*)(o + 8) = v1;
    }
}

// --------------------------------------------------------- edge MFMA kernel ---
__global__ __launch_bounds__(256, 2)
void edge_mfma_kernel(const float* __restrict__ x, const float* __restrict__ eattr,
                      const int* __restrict__ perm, const int* __restrict__ rowp,
                      const int* __restrict__ colp,
                      const u16* __restrict__ HrB, const u16* __restrict__ HcB,
                      const float* __restrict__ we_w1,
                      const u16* __restrict__ we2t, const float* __restrict__ we_b2,
                      const u16* __restrict__ wx1t, const float* __restrict__ wx_b1,
                      const float* __restrict__ wx_w2, const float* __restrict__ wx_b2,
                      u16* __restrict__ mij,
                      u16* __restrict__ t0p, u16* __restrict__ t1p, u16* __restrict__ t2p,
                      int E)
{
    __shared__ u16 X1[4096];
    __shared__ u16 X2[4096];
    __shared__ float dS[64][3];
    __shared__ float pxS[64];

    const int tid = threadIdx.x, lane = tid & 63, wv = tid >> 6;
    const int sb = blockIdx.x * 64;
    const int fn = lane & 15, fk8 = (lane >> 4) * 8;
    const int el = tid >> 2, jg = tid & 3;
    const int s = sb + el;

    float acc[16];
    if (s < E) {
        const int r = rowp[s], c = colp[s], e = perm[s];
        const float d0 = x[(size_t)r*3+0] - x[(size_t)c*3+0];
        const float d1 = x[(size_t)r*3+1] - x[(size_t)c*3+1];
        const float d2 = x[(size_t)r*3+2] - x[(size_t)c*3+2];
        const float rad = d0*d0 + d1*d1 + d2*d2;
        if (jg == 0) { dS[el][0] = d0; dS[el][1] = d1; dS[el][2] = d2; }

        uint4 ra = *(const uint4*)(HrB + (size_t)r * 64 + jg * 16);
        uint4 rb = *(const uint4*)(HrB + (size_t)r * 64 + jg * 16 + 8);
        uint4 ca = *(const uint4*)(HcB + (size_t)c * 64 + jg * 16);
        uint4 cb = *(const uint4*)(HcB + (size_t)c * 64 + jg * 16 + 8);
        uint rw[8] = {ra.x, ra.y, ra.z, ra.w, rb.x, rb.y, rb.z, rb.w};
        uint cw[8] = {ca.x, ca.y, ca.z, ca.w, cb.x, cb.y, cb.z, cb.w};
        const float* wrad = we_w1 + 128 * 64 + jg * 16;
        #pragma unroll
        for (int i = 0; i < 16; i++) {
            const float hr = (i & 1) ? UB_HI(rw[i >> 1]) : UB_LO(rw[i >> 1]);
            const float hc = (i & 1) ? UB_HI(cw[i >> 1]) : UB_LO(cw[i >> 1]);
            acc[i] = hr + hc + rad * wrad[i];
        }
        const float4* ea4 = (const float4*)(eattr + (size_t)e * 8);
        float4 v0 = ea4[0], v1 = ea4[1];
        float ea[8] = {v0.x, v0.y, v0.z, v0.w, v1.x, v1.y, v1.z, v1.w};
        #pragma unroll
        for (int k = 0; k < 8; k++) {
            const float* w = we_w1 + (129 + k) * 64 + jg * 16;
            #pragma unroll
            for (int i = 0; i < 16; i++) acc[i] += ea[k] * w[i];
        }
        #pragma unroll
        for (int i = 0; i < 16; i++) acc[i] = fast_tanh(acc[i]);
    } else {
        #pragma unroll
        for (int i = 0; i < 16; i++) acc[i] = 0.0f;
    }
    {
        uint pk[8];
        #pragma unroll
        for (int q = 0; q < 8; q++) pk[q] = packbf(acc[2*q], acc[2*q+1]);
        const int b0 = swzb(el * 128 + jg * 32), b1 = swzb(el * 128 + jg * 32 + 16);
        *(uint4*)(&X1[b0 >> 1]) = make_uint4(pk[0], pk[1], pk[2], pk[3]);
        *(uint4*)(&X1[b1 >> 1]) = make_uint4(pk[4], pk[5], pk[6], pk[7]);
    }
    __syncthreads();

    const int mb = wv * 16;
    short8 a0, a1;
    {
        const int ba = swzb((mb + fn) * 128 + fk8 * 2);
        const int bb = swzb((mb + fn) * 128 + 64 + fk8 * 2);
        a0 = *(const short8*)(&X1[ba >> 1]);
        a1 = *(const short8*)(&X1[bb >> 1]);
    }
    #pragma unroll
    for (int n0 = 0; n0 < 4; n0++) {
        uint4 bw0 = *(const uint4*)(we2t + (n0*16 + fn) * 64 + fk8);
        uint4 bw1 = *(const uint4*)(we2t + (n0*16 + fn) * 64 + 32 + fk8);
        const float bias = we_b2[n0 * 16 + fn];
        f32x4 q = {bias, bias, bias, bias};
        q = __builtin_amdgcn_mfma_f32_16x16x32_bf16(a0, __builtin_bit_cast(short8, bw0), q, 0, 0, 0);
        q = __builtin_amdgcn_mfma_f32_16x16x32_bf16(a1, __builtin_bit_cast(short8, bw1), q, 0, 0, 0);
        #pragma unroll
        for (int r2 = 0; r2 < 4; r2++) {
            const int m = mb + (lane >> 4) * 4 + r2;
            X2[swzb(m * 128 + (n0*16 + fn) * 2) >> 1] = bf16rne(fast_tanh(q[r2]));
        }
    }
    __syncthreads();

    {
        const int b0 = swzb(el * 128 + jg * 32), b1 = swzb(el * 128 + jg * 32 + 16);
        uint4 v0 = *(const uint4*)(&X2[b0 >> 1]);
        uint4 v1 = *(const uint4*)(&X2[b1 >> 1]);
        if (s < E) {
            u16* mo = mij + (size_t)s * 64 + jg * 16;
            *(uint4*)(mo) = v0;
            *(uint4*)(mo + 8) = v1;
        }
    }

    short8 c0, c1;
    {
        const int ba = swzb((mb + fn) * 128 + fk8 * 2);
        const int bb = swzb((mb + fn) * 128 + 64 + fk8 * 2);
        c0 = *(const short8*)(&X2[ba >> 1]);
        c1 = *(const short8*)(&X2[bb >> 1]);
    }
    float pxp[4] = {0.f, 0.f, 0.f, 0.f};
    #pragma unroll
    for (int n0 = 0; n0 < 4; n0++) {
        uint4 bw0 = *(const uint4*)(wx1t + (n0*16 + fn) * 64 + fk8);
        uint4 bw1 = *(const uint4*)(wx1t + (n0*16 + fn) * 64 + 32 + fk8);
        const float bias = wx_b1[n0 * 16 + fn];
        f32x4 q = {bias, bias, bias, bias};
        q = __builtin_amdgcn_mfma_f32_16x16x32_bf16(c0, __builtin_bit_cast(short8, bw0), q, 0, 0, 0);
        q = __builtin_amdgcn_mfma_f32_16x16x32_bf16(c1, __builtin_bit_cast(short8, bw1), q, 0, 0, 0);
        const float wqn = wx_w2[n0 * 16 + fn];
        #pragma unroll
        for (int r2 = 0; r2 < 4; r2++) pxp[r2] += fast_tanh(q[r2]) * wqn;
    }
    #pragma unroll
    for (int off = 1; off < 16; off <<= 1) {
        #pragma unroll
        for (int r2 = 0; r2 < 4; r2++) pxp[r2] += __shfl_xor(pxp[r2], off, 64);
    }
    if (fn == 0) {
        const float bx2 = wx_b2[0];
        #pragma unroll
        for (int r2 = 0; r2 < 4; r2++) {
            const int m = mb + (lane >> 4) * 4 + r2;
            pxS[m] = fast_tanh(pxp[r2] + bx2);
        }
    }
    __syncthreads();

    if (tid < 64 && sb + tid < E) {
        const float px = pxS[tid];
        t0p[sb + tid] = bf16rne(dS[tid][0] * px);
        t1p[sb + tid] = bf16rne(dS[tid][1] * px);
        t2p[sb + tid] = bf16rne(dS[tid][2] * px);
    }
}

// ---------------------------------------------- fused aggregation + node MLP ---
// 64 nodes/block, 4 waves. Phase1: wave w segment-sums nodes [w*16, w*16+16)
// (mij/t-plane reads sequential), mi -> LDS bf16 tile. Phase2: MFMA node MLPs.
__global__ __launch_bounds__(256, 2)
void aggnode_kernel(const float* __restrict__ h, const float* __restrict__ x,
                    const float* __restrict__ vel,
                    const u16* __restrict__ mij,
                    const u16* __restrict__ t0p, const u16* __restrict__ t1p,
                    const u16* __restrict__ t2p,
                    const int* __restrict__ offs,
                    const u16* __restrict__ wv1t, const float* __restrict__ wv_b1,
                    const float* __restrict__ wv_w2, const float* __restrict__ wv_b2,
                    const u16* __restrict__ wh1t, const float* __restrict__ wh_b1,
                    const u16* __restrict__ wh2t, const float* __restrict__ wh_b2,
                    float* __restrict__ out_h, float* __restrict__ out_x,
                    float* __restrict__ out_v, int N)
{
    __shared__ u16 Xh[4096];      // h tile, bf16 swizzled
    __shared__ u16 Xm[4096];      // mi tile, then reused for act tile
    __shared__ float aggM[64][3];
    __shared__ float pvS[64];

    const int tid = threadIdx.x, lane = tid & 63, wv = tid >> 6;
    const int nb = blockIdx.x * 64;
    const int el = tid >> 2, jg = tid & 3;
    const int fn = lane & 15, fk8 = (lane >> 4) * 8;

    // ---- stage h tile ----
    {
        uint pk[8];
        if (nb + el < N) {
            const float4* h4 = (const float4*)(h + (size_t)(nb + el) * 64 + jg * 16);
            #pragma unroll
            for (int q = 0; q < 4; q++) {
                float4 v = h4[q];
                pk[2*q]   = packbf(v.x, v.y);
                pk[2*q+1] = packbf(v.z, v.w);
            }
        } else {
            #pragma unroll
            for (int q = 0; q < 8; q++) pk[q] = 0;
        }
        const int b0 = swzb(el * 128 + jg * 32), b1 = swzb(el * 128 + jg * 32 + 16);
        *(uint4*)(&Xh[b0 >> 1]) = make_uint4(pk[0], pk[1], pk[2], pk[3]);
        *(uint4*)(&Xh[b1 >> 1]) = make_uint4(pk[4], pk[5], pk[6], pk[7]);
    }

    // ---- phase 1: aggregation (wave per 16 nodes, sequential reads) ----
    const u16* tp = (lane == 0) ? t0p : (lane == 1) ? t1p : t2p;
    for (int t = 0; t < 16; t++) {
        const int ln = wv * 16 + t;
        const int n = nb + ln;
        int beg = 0, end = 0;
        if (n < N) { beg = offs[n]; end = offs[n + 1]; }
        beg = __builtin_amdgcn_readfirstlane(beg);
        end = __builtin_amdgcn_readfirstlane(end);
        float msum = 0.0f, tsum = 0.0f;
        for (int i = beg; i < end; i++) {
            msum += UB_LO((uint)mij[(size_t)i * 64 + lane]);
            if (lane < 3) tsum += UB_LO((uint)tp[i]);
        }
        Xm[swzb(ln * 128 + lane * 2) >> 1] = bf16rne(msum);
        if (lane < 3) aggM[ln][lane] = tsum / fmaxf((float)(end - beg), 1.0f);
    }
    __syncthreads();

    // ---- frag loads ----
    const int mb = wv * 16;
    short8 a0, a1, b0, b1;
    {
        const int ba = swzb((mb + fn) * 128 + fk8 * 2);
        const int bb = swzb((mb + fn) * 128 + 64 + fk8 * 2);
        a0 = *(const short8*)(&Xh[ba >> 1]);
        a1 = *(const short8*)(&Xh[bb >> 1]);
        b0 = *(const short8*)(&Xm[ba >> 1]);
        b1 = *(const short8*)(&Xm[bb >> 1]);
    }

    // ---- phi_v: Sv = h @ Wv1 + b1; pv = sum tanh(Sv)*wv_w2 + b2 ----
    float pvp[4] = {0.f, 0.f, 0.f, 0.f};
    #pragma unroll
    for (int n0 = 0; n0 < 4; n0++) {
        uint4 bw0 = *(const uint4*)(wv1t + (n0*16 + fn) * 64 + fk8);
        uint4 bw1 = *(const uint4*)(wv1t + (n0*16 + fn) * 64 + 32 + fk8);
        const float bias = wv_b1[n0 * 16 + fn];
        f32x4 q = {bias, bias, bias, bias};
        q = __builtin_amdgcn_mfma_f32_16x16x32_bf16(a0, __builtin_bit_cast(short8, bw0), q, 0, 0, 0);
        q = __builtin_amdgcn_mfma_f32_16x16x32_bf16(a1, __builtin_bit_cast(short8, bw1), q, 0, 0, 0);
        const float wqn = wv_w2[n0 * 16 + fn];
        #pragma unroll
        for (int r2 = 0; r2 < 4; r2++) pvp[r2] += fast_tanh(q[r2]) * wqn;
    }
    #pragma unroll
    for (int off = 1; off < 16; off <<= 1) {
        #pragma unroll
        for (int r2 = 0; r2 < 4; r2++) pvp[r2] += __shfl_xor(pvp[r2], off, 64);
    }
    if (fn == 0) {
        const float bv2 = wv_b2[0];
        #pragma unroll
        for (int r2 = 0; r2 < 4; r2++) pvS[mb + (lane >> 4) * 4 + r2] = pvp[r2] + bv2;
    }
    __syncthreads();   // all frag loads done; Xm may now be overwritten

    // ---- phi_h layer 1 (K=128: [h | mi]) -> act tile (into Xm region) ----
    #pragma unroll
    for (int n0 = 0; n0 < 4; n0++) {
        const u16* base = wh1t + (n0*16 + fn) * 128;
        uint4 bw0 = *(const uint4*)(base + fk8);
        uint4 bw1 = *(const uint4*)(base + 32 + fk8);
        uint4 bw2 = *(const uint4*)(base + 64 + fk8);
        uint4 bw3 = *(const uint4*)(base + 96 + fk8);
        const float bias = wh_b1[n0 * 16 + fn];
        f32x4 q = {bias, bias, bias, bias};
        q = __builtin_amdgcn_mfma_f32_16x16x32_bf16(a0, __builtin_bit_cast(short8, bw0), q, 0, 0, 0);
        q = __builtin_amdgcn_mfma_f32_16x16x32_bf16(a1, __builtin_bit_cast(short8, bw1), q, 0, 0, 0);
        q = __builtin_amdgcn_mfma_f32_16x16x32_bf16(b0, __builtin_bit_cast(short8, bw2), q, 0, 0, 0);
        q = __builtin_amdgcn_mfma_f32_16x16x32_bf16(b1, __builtin_bit_cast(short8, bw3), q, 0, 0, 0);
        #pragma unroll
        for (int r2 = 0; r2 < 4; r2++) {
            const int m = mb + (lane >> 4) * 4 + r2;
            Xm[swzb(m * 128 + (n0*16 + fn) * 2) >> 1] = bf16rne(fast_tanh(q[r2]));
        }
    }
    __syncthreads();

    // ---- phi_h layer 2: act @ Wh2 + b2 -> out_h (no outer tanh) ----
    short8 c0, c1;
    {
        const int ba = swzb((mb + fn) * 128 + fk8 * 2);
        const int bb = swzb((mb + fn) * 128 + 64 + fk8 * 2);
        c0 = *(const short8*)(&Xm[ba >> 1]);
        c1 = *(const short8*)(&Xm[bb >> 1]);
    }
    #pragma unroll
    for (int n0 = 0; n0 < 4; n0++) {
        uint4 bw0 = *(const uint4*)(wh2t + (n0*16 + fn) * 64 + fk8);
        uint4 bw1 = *(const uint4*)(wh2t + (n0*16 + fn) * 64 + 32 + fk8);
        const float bias = wh_b2[n0 * 16 + fn];
        f32x4 q = {bias, bias, bias, bias};
        q = __builtin_amdgcn_mfma_f32_16x16x32_bf16(c0, __builtin_bit_cast(short8, bw0), q, 0, 0, 0);
        q = __builtin_amdgcn_mfma_f32_16x16x32_bf16(c1, __builtin_bit_cast(short8, bw1), q, 0, 0, 0);
        #pragma unroll
        for (int r2 = 0; r2 < 4; r2++) {
            const int m = mb + (lane >> 4) * 4 + r2;
            if (nb + m < N) out_h[(size_t)(nb + m) * 64 + n0 * 16 + fn] = q[r2];
        }
    }

    // ---- coordinate / velocity update ----
    if (tid < 64 && nb + tid < N) {
        const int n = nb + tid;
        const float pv = pvS[tid];
        #pragma unroll
        for (int d = 0; d < 3; d++) {
            const float am = aggM[tid][d];
            const float vn = vel[(size_t)n * 3 + d] * pv + am;
            out_v[(size_t)n * 3 + d] = vn;
            out_x[(size_t)n * 3 + d] = x[(size_t)n * 3 + d] + vn;
        }
    }
}

// ---------------------------------------------------------------- CSR build ---
__global__ void hist_kernel(const int* __restrict__ rows, int* __restrict__ hist, int E) {
    int e = blockIdx.x * blockDim.x + threadIdx.x;
    if (e < E) atomicAdd(&hist[rows[e]], 1);
}

__global__ __launch_bounds__(1024)
void scan_kernel(const int* __restrict__ hist, int* __restrict__ offs,
                 int* __restrict__ cursor, int N) {
    const int tid = threadIdx.x;
    const int chunk = (N + 1023) / 1024;
    const int beg = tid * chunk;
    const int end = (beg + chunk < N) ? beg + chunk : N;

    int s = 0;
    for (int i = beg; i < end; i++) s += hist[i];

    __shared__ int wsum[16];
    const int lane = tid & 63, wid = tid >> 6;
    int inc = s;
    #pragma unroll
    for (int off = 1; off < 64; off <<= 1) {
        int t = __shfl_up(inc, off, 64);
        if (lane >= off) inc += t;
    }
    if (lane == 63) wsum[wid] = inc;
    __syncthreads();
    if (wid == 0 && lane < 16) {
        int v = wsum[lane];
        #pragma unroll
        for (int off = 1; off < 16; off <<= 1) {
            int t = __shfl_up(v, off, 64);
            if (lane >= off) v += t;
        }
        wsum[lane] = v;
    }
    __syncthreads();
    const int wbase = (wid > 0) ? wsum[wid - 1] : 0;
    int run = wbase + inc - s;
    for (int i = beg; i < end; i++) {
        cursor[i] = run;
        run += hist[i];
        offs[i + 1] = run;
    }
    if (tid == 0) offs[0] = 0;
}

__global__ void scatter_kernel(const int* __restrict__ rows, const int* __restrict__ cols,
                               int* __restrict__ cursor,
                               int* __restrict__ perm, int* __restrict__ colp, int E) {
    int e = blockIdx.x * blockDim.x + threadIdx.x;
    if (e < E) {
        int p = atomicAdd(&cursor[rows[e]], 1);
        perm[p] = e;
        colp[p] = cols[e];
    }
}

__global__ void rowfill_kernel(const int* __restrict__ offs, int* __restrict__ rowp, int N) {
    int n = blockIdx.x * blockDim.x + threadIdx.x;
    if (n < N) {
        const int b = offs[n], e = offs[n + 1];
        for (int i = b; i < e; i++) rowp[i] = n;
    }
}

// ------------------------------------------- fallback kernels (atomic path) ---
template<int BLK>
__global__ __launch_bounds__(BLK)
void edge_atomic_kernel(const float* __restrict__ h, const float* __restrict__ x,
                 const float* __restrict__ eattr,
                 const int* __restrict__ rows, const int* __restrict__ cols,
                 const float* __restrict__ we_w1, const float* __restrict__ we_b1,
                 const float* __restrict__ we_w2, const float* __restrict__ we_b2,
                 const float* __restrict__ wx_w1, const float* __restrict__ wx_b1,
                 const float* __restrict__ wx_w2, const float* __restrict__ wx_b2,
                 float* __restrict__ agg, float* __restrict__ cnt, float* __restrict__ mi,
                 int E)
{
    __shared__ float act[64][BLK];
    const int tid = threadIdx.x;
    const int e = blockIdx.x * BLK + tid;
    if (e >= E) return;

    const int r = rows[e];
    const int c = cols[e];
    const float d0 = x[(size_t)r*3+0] - x[(size_t)c*3+0];
    const float d1 = x[(size_t)r*3+1] - x[(size_t)c*3+1];
    const float d2 = x[(size_t)r*3+2] - x[(size_t)c*3+2];
    const float rad = d0*d0 + d1*d1 + d2*d2;

    float A[64];
    #pragma unroll
    for (int j = 0; j < 64; j++) A[j] = we_b1[j];
    const float* hr = h + (size_t)r * 64;
    const float* hc = h + (size_t)c * 64;
    #pragma unroll 4
    for (int k = 0; k < 64; k++) {
        const float a0 = hr[k];
        const float a1 = hc[k];
        const float* w0 = we_w1 + k * 64;
        const float* w1 = we_w1 + (64 + k) * 64;
        #pragma unroll
        for (int j = 0; j < 64; j++) A[j] += a0 * w0[j] + a1 * w1[j];
    }
    {
        const float* w = we_w1 + 128 * 64;
        #pragma unroll
        for (int j = 0; j < 64; j++) A[j] += rad * w[j];
    }
    const float* ea = eattr + (size_t)e * 8;
    #pragma unroll
    for (int k = 0; k < 8; k++) {
        const float a = ea[k];
        const float* w = we_w1 + (129 + k) * 64;
        #pragma unroll
        for (int j = 0; j < 64; j++) A[j] += a * w[j];
    }
    #pragma unroll
    for (int j = 0; j < 64; j++) act[j][tid] = fast_tanh(A[j]);

    float B[64];
    #pragma unroll
    for (int j = 0; j < 64; j++) B[j] = we_b2[j];
    #pragma unroll 4
    for (int k = 0; k < 64; k++) {
        const float a = act[k][tid];
        const float* w = we_w2 + k * 64;
        #pragma unroll
        for (int j = 0; j < 64; j++) B[j] += a * w[j];
    }
    #pragma unroll
    for (int j = 0; j < 64; j++) act[j][tid] = fast_tanh(B[j]);

    #pragma unroll
    for (int j = 0; j < 64; j++) A[j] = wx_b1[j];
    #pragma unroll 4
    for (int k = 0; k < 64; k++) {
        const float a = act[k][tid];
        const float* w = wx_w1 + k * 64;
        #pragma unroll
        for (int j = 0; j < 64; j++) A[j] += a * w[j];
    }
    float px = wx_b2[0];
    #pragma unroll
    for (int j = 0; j < 64; j++) px += fast_tanh(A[j]) * wx_w2[j];
    px = fast_tanh(px);

    atomicAdd(&agg[(size_t)r*3+0], d0 * px);
    atomicAdd(&agg[(size_t)r*3+1], d1 * px);
    atomicAdd(&agg[(size_t)r*3+2], d2 * px);
    atomicAdd(&cnt[r], 1.0f);
    float* mir = mi + (size_t)r * 64;
    #pragma unroll
    for (int j = 0; j < 64; j++) atomicAdd(&mir[j], act[j][tid]);
}

template<int BLK>
__global__ __launch_bounds__(BLK, 2)
void node_fb_kernel(const float* __restrict__ h, const float* __restrict__ x,
                 const float* __restrict__ vel,
                 const float* __restrict__ wh_w1, const float* __restrict__ wh_b1,
                 const float* __restrict__ wh_w2, const float* __restrict__ wh_b2,
                 const float* __restrict__ wv_w1, const float* __restrict__ wv_b1,
                 const float* __restrict__ wv_w2, const float* __restrict__ wv_b2,
                 const float* __restrict__ agg, const float* __restrict__ cnt,
                 const float* __restrict__ mi,
                 float* __restrict__ out_h, float* __restrict__ out_x, float* __restrict__ out_v,
                 int N)
{
    const int n = blockIdx.x * BLK + threadIdx.x;
    if (n >= N) return;

    const float* hn = h + (size_t)n * 64;
    const float* mn = mi + (size_t)n * 64;

    float A[64];
    #pragma unroll
    for (int j = 0; j < 64; j++) A[j] = wv_b1[j];
    #pragma unroll
    for (int k = 0; k < 64; k++) {
        const float a = hn[k];
        const float* w = wv_w1 + k * 64;
        #pragma unroll
        for (int j = 0; j < 64; j++) A[j] += a * w[j];
    }
    float pv = wv_b2[0];
    #pragma unroll
    for (int j = 0; j < 64; j++) pv += fast_tanh(A[j]) * wv_w2[j];

    #pragma unroll
    for (int j = 0; j < 64; j++) A[j] = wh_b1[j];
    #pragma unroll
    for (int k = 0; k < 64; k++) {
        const float a0 = hn[k];
        const float a1 = mn[k];
        const float* w0 = wh_w1 + k * 64;
        const float* w1 = wh_w1 + (64 + k) * 64;
        #pragma unroll
        for (int j = 0; j < 64; j++) A[j] += a0 * w0[j] + a1 * w1[j];
    }
    #pragma unroll
    for (int j = 0; j < 64; j++) A[j] = fast_tanh(A[j]);

    float B[64];
    #pragma unroll
    for (int j = 0; j < 64; j++) B[j] = wh_b2[j];
    #pragma unroll
    for (int k = 0; k < 64; k++) {
        const float a = A[k];
        const float* w = wh_w2 + k * 64;
        #pragma unroll
        for (int j = 0; j < 64; j++) B[j] += a * w[j];
    }
    float* oh = out_h + (size_t)n * 64;
    #pragma unroll
    for (int j = 0; j < 64; j++) oh[j] = B[j];

    const float inv = 1.0f / fmaxf(cnt[n], 1.0f);
    #pragma unroll
    for (int d = 0; d < 3; d++) {
        const float am = agg[(size_t)n*3 + d] * inv;
        const float vn = vel[(size_t)n*3 + d] * pv + am;
        out_v[(size_t)n*3 + d] = vn;
        out_x[(size_t)n*3 + d] = x[(size_t)n*3 + d] + vn;
    }
}

// ------------------------------------------------------------------ launch ---
extern "C" void kernel_launch(void* const* d_in, const int* in_sizes, int n_in,
                              void* d_out, int out_size, void* d_ws, size_t ws_size,
                              hipStream_t stream) {
    const float* h      = (const float*)d_in[0];
    const float* x      = (const float*)d_in[1];
    const float* vel    = (const float*)d_in[2];
    const float* eattr  = (const float*)d_in[3];
    const float* we_w1  = (const float*)d_in[4];
    const float* we_b1  = (const float*)d_in[5];
    const float* we_w2  = (const float*)d_in[6];
    const float* we_b2  = (const float*)d_in[7];
    const float* wx_w1  = (const float*)d_in[8];
    const float* wx_b1  = (const float*)d_in[9];
    const float* wx_w2  = (const float*)d_in[10];
    const float* wx_b2  = (const float*)d_in[11];
    const float* wh_w1  = (const float*)d_in[12];
    const float* wh_b1  = (const float*)d_in[13];
    const float* wh_w2  = (const float*)d_in[14];
    const float* wh_b2  = (const float*)d_in[15];
    const float* wv_w1  = (const float*)d_in[16];
    const float* wv_b1  = (const float*)d_in[17];
    const float* wv_w2  = (const float*)d_in[18];
    const float* wv_b2  = (const float*)d_in[19];
    const int*   ar     = (const int*)d_in[20];

    const int N = in_sizes[0] / 64;
    const int E = in_sizes[20] / 2;
    const int* rows = ar;
    const int* cols = ar + E;

    float* out_h = (float*)d_out;            // N*64 (HrB/HcB bf16 scratch first)
    float* out_x = out_h + (size_t)N * 64;   // N*3
    float* out_v = out_x + (size_t)N * 3;    // N*3

    u16* HrB = (u16*)d_out;
    u16* HcB = HrB + (size_t)N * 64;

    // --- workspace layout: ~235 MB ---
    char* p = (char*)d_ws;
    auto align64 = [&]() { p = (char*)(((uintptr_t)p + 63) & ~(uintptr_t)63); };
    u16*  mij  = (u16*)p;   p += (size_t)E * 64 * sizeof(u16);
    u16*  t0p  = (u16*)p;   p += (size_t)E * sizeof(u16);
    u16*  t1p  = (u16*)p;   p += (size_t)E * sizeof(u16);
    u16*  t2p  = (u16*)p;   p += (size_t)E * sizeof(u16);
    int*  perm = (int*)p;   p += (size_t)E * sizeof(int);
    int*  rowp = (int*)p;   p += (size_t)E * sizeof(int);
    int*  colp = (int*)p;   p += (size_t)E * sizeof(int);
    int*  offs = (int*)p;   p += (size_t)(N + 1) * sizeof(int);
    int*  cursor = (int*)p; p += (size_t)N * sizeof(int);
    int*  hist = (int*)p;   p += (size_t)N * sizeof(int);
    align64();
    u16*  we1t = (u16*)p;   p += 64 * 128 * sizeof(u16);
    u16*  we2t = (u16*)p;   p += 64 * 64 * sizeof(u16);
    u16*  wx1t = (u16*)p;   p += 64 * 64 * sizeof(u16);
    u16*  wv1t = (u16*)p;   p += 64 * 64 * sizeof(u16);
    u16*  wh1t = (u16*)p;   p += 64 * 128 * sizeof(u16);
    u16*  wh2t = (u16*)p;   p += 64 * 64 * sizeof(u16);
    const size_t needed = (size_t)(p - (char*)d_ws);

    if (ws_size >= needed) {
        hipMemsetAsync(hist, 0, (size_t)N * sizeof(int), stream);
        hist_kernel<<<(E + 255) / 256, 256, 0, stream>>>(rows, hist, E);
        scan_kernel<<<1, 1024, 0, stream>>>(hist, offs, cursor, N);
        scatter_kernel<<<(E + 255) / 256, 256, 0, stream>>>(rows, cols, cursor, perm, colp, E);
        rowfill_kernel<<<(N + 255) / 256, 256, 0, stream>>>(offs, rowp, N);

        wprep_kernel<<<32, 256, 0, stream>>>(we_w1, we_w2, wx_w1, wv_w1, wh_w1, wh_w2,
                                             we1t, we2t, wx1t, wv1t, wh1t, wh2t);
        pre_mfma_kernel<<<(N + 63) / 64, 256, 0, stream>>>(h, we_b1, we1t, HrB, HcB, N);

        edge_mfma_kernel<<<(E + 63) / 64, 256, 0, stream>>>(
            x, eattr, perm, rowp, colp, HrB, HcB,
            we_w1, we2t, we_b2, wx1t, wx_b1, wx_w2, wx_b2,
            mij, t0p, t1p, t2p, E);

        aggnode_kernel<<<(N + 63) / 64, 256, 0, stream>>>(
            h, x, vel, mij, t0p, t1p, t2p, offs,
            wv1t, wv_b1, wv_w2, wv_b2,
            wh1t, wh_b1, wh2t, wh_b2,
            out_h, out_x, out_v, N);
    } else {
        // --- fallback: atomic path ---
        float* agg2 = (float*)d_ws;               // N*3
        float* cnt2 = agg2 + (size_t)N * 3;       // N
        float* mi2  = cnt2 + N;                   // N*64
        hipMemsetAsync(d_ws, 0, (size_t)N * 68 * sizeof(float), stream);

        edge_atomic_kernel<128><<<(E + 127) / 128, 128, 0, stream>>>(
            h, x, eattr, rows, cols,
            we_w1, we_b1, we_w2, we_b2,
            wx_w1, wx_b1, wx_w2, wx_b2,
            agg2, cnt2, mi2, E);

        node_fb_kernel<128><<<(N + 127) / 128, 128, 0, stream>>>(
            h, x, vel,
            wh_w1, wh_b1, wh_w2, wh_b2,
            wv_w1, wv_b1, wv_w2, wv_b2,
            agg2, cnt2, mi2, out_h, out_x, out_v, N);
    }
}

// Round 8
// 708.355 us; speedup vs baseline: 8.8615x; 1.4502x over previous
//
#include <hip/hip_runtime.h>

// EGNN layer (CamadaEquivariante), round 8:
//  - pre_mfma: Hr/Hc bf16 MFMA GEMM (outputs in d_out scratch).       [r6, kept]
//  - edge_mfma: CSR-slot-order MFMA edge MLP; NEW: in-kernel segment sum of
//    m_ij / trans over contiguous row-segments (LDS X2) + f32 atomicAdd partials
//    to miF/aggF/cntF. mij & trans never touch HBM (saves ~430 MB round-trip).
//  - aggnode: phase1 reads miF/aggF/cntF directly (27 MB), then MFMA node MLPs.
//  - CSR build: hist -> 3-kernel parallel scan -> scatter(perm,colp) -> rowfill.
// ws ~= 48 MB. Fallback to atomic path if ws too small.

typedef unsigned int uint;
typedef unsigned short u16;
typedef __attribute__((ext_vector_type(8))) short short8;
typedef __attribute__((ext_vector_type(4))) float f32x4;

#define UB_LO(u) __uint_as_float((u) << 16)
#define UB_HI(u) __uint_as_float((u) & 0xffff0000u)

__device__ __forceinline__ float fast_tanh(float x) {
    float e = __expf(2.0f * x);
    return 1.0f - 2.0f * __builtin_amdgcn_rcpf(e + 1.0f);
}
__device__ __forceinline__ u16 bf16rne(float f) {
    uint u = __float_as_uint(f);
    return (u16)((u + 0x7fffu + ((u >> 16) & 1u)) >> 16);
}
__device__ __forceinline__ uint packbf(float a, float b) {
    return (uint)bf16rne(a) | ((uint)bf16rne(b) << 16);
}
// XOR-swizzle within a [64][64]-bf16 (128B-row) LDS tile: byte ^= ((row&7)<<4)
__device__ __forceinline__ int swzb(int b) { return b ^ ((b >> 3) & 0x70); }

// ------------------------------------------------- weight transpose (bf16) ---
__global__ void wprep_kernel(const float* __restrict__ we_w1, const float* __restrict__ we_w2,
                             const float* __restrict__ wx_w1, const float* __restrict__ wv_w1,
                             const float* __restrict__ wh_w1, const float* __restrict__ wh_w2,
                             u16* __restrict__ we1t, u16* __restrict__ we2t,
                             u16* __restrict__ wx1t, u16* __restrict__ wv1t,
                             u16* __restrict__ wh1t, u16* __restrict__ wh2t) {
    int t = blockIdx.x * 256 + threadIdx.x;
    if (t < 8192) {
        int j = t >> 7, k = t & 127;
        we1t[t] = bf16rne(we_w1[k * 64 + j]);
        wh1t[t] = bf16rne(wh_w1[k * 64 + j]);
    }
    if (t < 4096) {
        int n = t >> 6, k = t & 63;
        we2t[t] = bf16rne(we_w2[k * 64 + n]);
        wx1t[t] = bf16rne(wx_w1[k * 64 + n]);
        wv1t[t] = bf16rne(wv_w1[k * 64 + n]);
        wh2t[t] = bf16rne(wh_w2[k * 64 + n]);
    }
}

// --------------------------------------------------------- pre MFMA kernel ---
__global__ __launch_bounds__(256, 2)
void pre_mfma_kernel(const float* __restrict__ h, const float* __restrict__ we_b1,
                     const u16* __restrict__ we1t,
                     u16* __restrict__ HrB, u16* __restrict__ HcB, int N)
{
    __shared__ u16 X1[4096];
    __shared__ u16 X2[4096];
    const int tid = threadIdx.x, lane = tid & 63, wv = tid >> 6;
    const int nb = blockIdx.x * 64;
    const int el = tid >> 2, jg = tid & 3;
    const int fn = lane & 15, fk8 = (lane >> 4) * 8;

    {
        uint pk[8];
        if (nb + el < N) {
            const float4* h4 = (const float4*)(h + (size_t)(nb + el) * 64 + jg * 16);
            #pragma unroll
            for (int q = 0; q < 4; q++) {
                float4 v = h4[q];
                pk[2*q]   = packbf(v.x, v.y);
                pk[2*q+1] = packbf(v.z, v.w);
            }
        } else {
            #pragma unroll
            for (int q = 0; q < 8; q++) pk[q] = 0;
        }
        const int b0 = swzb(el * 128 + jg * 32), b1 = swzb(el * 128 + jg * 32 + 16);
        *(uint4*)(&X1[b0 >> 1]) = make_uint4(pk[0], pk[1], pk[2], pk[3]);
        *(uint4*)(&X1[b1 >> 1]) = make_uint4(pk[4], pk[5], pk[6], pk[7]);
    }
    __syncthreads();

    const int mb = wv * 16;
    short8 a0, a1;
    {
        const int ba = swzb((mb + fn) * 128 + fk8 * 2);
        const int bb = swzb((mb + fn) * 128 + 64 + fk8 * 2);
        a0 = *(const short8*)(&X1[ba >> 1]);
        a1 = *(const short8*)(&X1[bb >> 1]);
    }
    // Hr = h @ We1[0:64] + b1
    #pragma unroll
    for (int n0 = 0; n0 < 4; n0++) {
        uint4 bw0 = *(const uint4*)(we1t + (n0*16 + fn) * 128 + fk8);
        uint4 bw1 = *(const uint4*)(we1t + (n0*16 + fn) * 128 + 32 + fk8);
        const float bias = we_b1[n0 * 16 + fn];
        f32x4 q = {bias, bias, bias, bias};
        q = __builtin_amdgcn_mfma_f32_16x16x32_bf16(a0, __builtin_bit_cast(short8, bw0), q, 0, 0, 0);
        q = __builtin_amdgcn_mfma_f32_16x16x32_bf16(a1, __builtin_bit_cast(short8, bw1), q, 0, 0, 0);
        #pragma unroll
        for (int r2 = 0; r2 < 4; r2++) {
            const int m = mb + (lane >> 4) * 4 + r2;
            X2[swzb(m * 128 + (n0*16 + fn) * 2) >> 1] = bf16rne(q[r2]);
        }
    }
    __syncthreads();
    if (nb + el < N) {
        const int b0 = swzb(el * 128 + jg * 32), b1 = swzb(el * 128 + jg * 32 + 16);
        uint4 v0 = *(const uint4*)(&X2[b0 >> 1]);
        uint4 v1 = *(const uint4*)(&X2[b1 >> 1]);
        u16* o = HrB + (size_t)(nb + el) * 64 + jg * 16;
        *(uint4*)o = v0; *(uint4*)(o + 8) = v1;
    }
    __syncthreads();
    // Hc = h @ We1[64:128]
    #pragma unroll
    for (int n0 = 0; n0 < 4; n0++) {
        uint4 bw0 = *(const uint4*)(we1t + (n0*16 + fn) * 128 + 64 + fk8);
        uint4 bw1 = *(const uint4*)(we1t + (n0*16 + fn) * 128 + 96 + fk8);
        f32x4 q = {0.f, 0.f, 0.f, 0.f};
        q = __builtin_amdgcn_mfma_f32_16x16x32_bf16(a0, __builtin_bit_cast(short8, bw0), q, 0, 0, 0);
        q = __builtin_amdgcn_mfma_f32_16x16x32_bf16(a1, __builtin_bit_cast(short8, bw1), q, 0, 0, 0);
        #pragma unroll
        for (int r2 = 0; r2 < 4; r2++) {
            const int m = mb + (lane >> 4) * 4 + r2;
            X2[swzb(m * 128 + (n0*16 + fn) * 2) >> 1] = bf16rne(q[r2]);
        }
    }
    __syncthreads();
    if (nb + el < N) {
        const int b0 = swzb(el * 128 + jg * 32), b1 = swzb(el * 128 + jg * 32 + 16);
        uint4 v0 = *(const uint4*)(&X2[b0 >> 1]);
        uint4 v1 = *(const uint4*)(&X2[b1 >> 1]);
        u16* o = HcB + (size_t)(nb + el) * 64 + jg * 16;
        *(uint4*)o = v0; *(uint4*)(o + 8) = v1;
    }
}

// --------------------------------------------------------- edge MFMA kernel ---
// Slot order; fused segment-sum: partial sums of m_ij / trans per contiguous
// row-segment within the block, atomicAdd f32 into miF/aggF/cntF.
__global__ __launch_bounds__(256, 2)
void edge_mfma_kernel(const float* __restrict__ x, const float* __restrict__ eattr,
                      const int* __restrict__ perm, const int* __restrict__ rowp,
                      const int* __restrict__ colp,
                      const u16* __restrict__ HrB, const u16* __restrict__ HcB,
                      const float* __restrict__ we_w1,
                      const u16* __restrict__ we2t, const float* __restrict__ we_b2,
                      const u16* __restrict__ wx1t, const float* __restrict__ wx_b1,
                      const float* __restrict__ wx_w2, const float* __restrict__ wx_b2,
                      float* __restrict__ miF, float* __restrict__ aggF,
                      float* __restrict__ cntF, int E)
{
    __shared__ u16 X1[4096];
    __shared__ u16 X2[4096];
    __shared__ float dS[64][3];
    __shared__ float pxS[64];
    __shared__ int rS[64];

    const int tid = threadIdx.x, lane = tid & 63, wv = tid >> 6;
    const int sb = blockIdx.x * 64;
    const int fn = lane & 15, fk8 = (lane >> 4) * 8;
    const int el = tid >> 2, jg = tid & 3;
    const int s = sb + el;

    int r = -1, c = 0, e = 0;
    if (s < E) { r = rowp[s]; c = colp[s]; e = perm[s]; }
    if (jg == 0) rS[el] = r;

    float acc[16];
    if (s < E) {
        const float d0 = x[(size_t)r*3+0] - x[(size_t)c*3+0];
        const float d1 = x[(size_t)r*3+1] - x[(size_t)c*3+1];
        const float d2 = x[(size_t)r*3+2] - x[(size_t)c*3+2];
        const float rad = d0*d0 + d1*d1 + d2*d2;
        if (jg == 0) { dS[el][0] = d0; dS[el][1] = d1; dS[el][2] = d2; }

        uint4 ra = *(const uint4*)(HrB + (size_t)r * 64 + jg * 16);
        uint4 rb = *(const uint4*)(HrB + (size_t)r * 64 + jg * 16 + 8);
        uint4 ca = *(const uint4*)(HcB + (size_t)c * 64 + jg * 16);
        uint4 cb = *(const uint4*)(HcB + (size_t)c * 64 + jg * 16 + 8);
        uint rw[8] = {ra.x, ra.y, ra.z, ra.w, rb.x, rb.y, rb.z, rb.w};
        uint cw[8] = {ca.x, ca.y, ca.z, ca.w, cb.x, cb.y, cb.z, cb.w};
        const float* wrad = we_w1 + 128 * 64 + jg * 16;
        #pragma unroll
        for (int i = 0; i < 16; i++) {
            const float hr = (i & 1) ? UB_HI(rw[i >> 1]) : UB_LO(rw[i >> 1]);
            const float hc = (i & 1) ? UB_HI(cw[i >> 1]) : UB_LO(cw[i >> 1]);
            acc[i] = hr + hc + rad * wrad[i];
        }
        const float4* ea4 = (const float4*)(eattr + (size_t)e * 8);
        float4 v0 = ea4[0], v1 = ea4[1];
        float ea[8] = {v0.x, v0.y, v0.z, v0.w, v1.x, v1.y, v1.z, v1.w};
        #pragma unroll
        for (int k = 0; k < 8; k++) {
            const float* w = we_w1 + (129 + k) * 64 + jg * 16;
            #pragma unroll
            for (int i = 0; i < 16; i++) acc[i] += ea[k] * w[i];
        }
        #pragma unroll
        for (int i = 0; i < 16; i++) acc[i] = fast_tanh(acc[i]);
    } else {
        #pragma unroll
        for (int i = 0; i < 16; i++) acc[i] = 0.0f;
    }
    {
        uint pk[8];
        #pragma unroll
        for (int q = 0; q < 8; q++) pk[q] = packbf(acc[2*q], acc[2*q+1]);
        const int b0 = swzb(el * 128 + jg * 32), b1 = swzb(el * 128 + jg * 32 + 16);
        *(uint4*)(&X1[b0 >> 1]) = make_uint4(pk[0], pk[1], pk[2], pk[3]);
        *(uint4*)(&X1[b1 >> 1]) = make_uint4(pk[4], pk[5], pk[6], pk[7]);
    }
    __syncthreads();

    const int mb = wv * 16;
    short8 a0, a1;
    {
        const int ba = swzb((mb + fn) * 128 + fk8 * 2);
        const int bb = swzb((mb + fn) * 128 + 64 + fk8 * 2);
        a0 = *(const short8*)(&X1[ba >> 1]);
        a1 = *(const short8*)(&X1[bb >> 1]);
    }
    #pragma unroll
    for (int n0 = 0; n0 < 4; n0++) {
        uint4 bw0 = *(const uint4*)(we2t + (n0*16 + fn) * 64 + fk8);
        uint4 bw1 = *(const uint4*)(we2t + (n0*16 + fn) * 64 + 32 + fk8);
        const float bias = we_b2[n0 * 16 + fn];
        f32x4 q = {bias, bias, bias, bias};
        q = __builtin_amdgcn_mfma_f32_16x16x32_bf16(a0, __builtin_bit_cast(short8, bw0), q, 0, 0, 0);
        q = __builtin_amdgcn_mfma_f32_16x16x32_bf16(a1, __builtin_bit_cast(short8, bw1), q, 0, 0, 0);
        #pragma unroll
        for (int r2 = 0; r2 < 4; r2++) {
            const int m = mb + (lane >> 4) * 4 + r2;
            X2[swzb(m * 128 + (n0*16 + fn) * 2) >> 1] = bf16rne(fast_tanh(q[r2]));
        }
    }
    __syncthreads();

    // ---- phi_x: S = X2 @ Wx1 + b1; px = tanh(tanh(S) @ wx2 + b2) ----
    short8 c0, c1;
    {
        const int ba = swzb((mb + fn) * 128 + fk8 * 2);
        const int bb = swzb((mb + fn) * 128 + 64 + fk8 * 2);
        c0 = *(const short8*)(&X2[ba >> 1]);
        c1 = *(const short8*)(&X2[bb >> 1]);
    }
    float pxp[4] = {0.f, 0.f, 0.f, 0.f};
    #pragma unroll
    for (int n0 = 0; n0 < 4; n0++) {
        uint4 bw0 = *(const uint4*)(wx1t + (n0*16 + fn) * 64 + fk8);
        uint4 bw1 = *(const uint4*)(wx1t + (n0*16 + fn) * 64 + 32 + fk8);
        const float bias = wx_b1[n0 * 16 + fn];
        f32x4 q = {bias, bias, bias, bias};
        q = __builtin_amdgcn_mfma_f32_16x16x32_bf16(c0, __builtin_bit_cast(short8, bw0), q, 0, 0, 0);
        q = __builtin_amdgcn_mfma_f32_16x16x32_bf16(c1, __builtin_bit_cast(short8, bw1), q, 0, 0, 0);
        const float wqn = wx_w2[n0 * 16 + fn];
        #pragma unroll
        for (int r2 = 0; r2 < 4; r2++) pxp[r2] += fast_tanh(q[r2]) * wqn;
    }
    #pragma unroll
    for (int off = 1; off < 16; off <<= 1) {
        #pragma unroll
        for (int r2 = 0; r2 < 4; r2++) pxp[r2] += __shfl_xor(pxp[r2], off, 64);
    }
    if (fn == 0) {
        const float bx2 = wx_b2[0];
        #pragma unroll
        for (int r2 = 0; r2 < 4; r2++) {
            const int m = mb + (lane >> 4) * 4 + r2;
            pxS[m] = fast_tanh(pxp[r2] + bx2);
        }
    }
    __syncthreads();

    // ---- fused segment sum: wave w owns segments STARTING in [w*16, w*16+16) ----
    const int w16 = wv * 16;
    for (int s0 = w16; s0 < w16 + 16; s0++) {
        const int r0 = rS[s0];
        if (r0 < 0) continue;
        if (s0 > 0 && rS[s0 - 1] == r0) continue;   // not a segment start
        int s1 = s0 + 1;
        while (s1 < 64 && rS[s1] == r0) s1++;
        float msum = 0.0f, tsum = 0.0f;
        for (int t = s0; t < s1; t++) {
            msum += UB_LO((uint)X2[swzb(t * 128 + lane * 2) >> 1]);
            if (lane < 3) tsum += dS[t][lane] * pxS[t];
        }
        atomicAdd(&miF[(size_t)r0 * 64 + lane], msum);
        if (lane < 3) atomicAdd(&aggF[(size_t)r0 * 3 + lane], tsum);
        if (lane == 3) atomicAdd(&cntF[r0], (float)(s1 - s0));
    }
}

// ---------------------------------------------- fused aggregation + node MLP ---
__global__ __launch_bounds__(256, 2)
void aggnode_kernel(const float* __restrict__ h, const float* __restrict__ x,
                    const float* __restrict__ vel,
                    const float* __restrict__ miF, const float* __restrict__ aggF,
                    const float* __restrict__ cntF,
                    const u16* __restrict__ wv1t, const float* __restrict__ wv_b1,
                    const float* __restrict__ wv_w2, const float* __restrict__ wv_b2,
                    const u16* __restrict__ wh1t, const float* __restrict__ wh_b1,
                    const u16* __restrict__ wh2t, const float* __restrict__ wh_b2,
                    float* __restrict__ out_h, float* __restrict__ out_x,
                    float* __restrict__ out_v, int N)
{
    __shared__ u16 Xh[4096];      // h tile, bf16 swizzled
    __shared__ u16 Xm[4096];      // mi tile, then reused for act tile
    __shared__ float aggM[64][3];
    __shared__ float pvS[64];

    const int tid = threadIdx.x, lane = tid & 63, wv = tid >> 6;
    const int nb = blockIdx.x * 64;
    const int el = tid >> 2, jg = tid & 3;
    const int fn = lane & 15, fk8 = (lane >> 4) * 8;

    // ---- stage h tile ----
    {
        uint pk[8];
        if (nb + el < N) {
            const float4* h4 = (const float4*)(h + (size_t)(nb + el) * 64 + jg * 16);
            #pragma unroll
            for (int q = 0; q < 4; q++) {
                float4 v = h4[q];
                pk[2*q]   = packbf(v.x, v.y);
                pk[2*q+1] = packbf(v.z, v.w);
            }
        } else {
            #pragma unroll
            for (int q = 0; q < 8; q++) pk[q] = 0;
        }
        const int b0 = swzb(el * 128 + jg * 32), b1 = swzb(el * 128 + jg * 32 + 16);
        *(uint4*)(&Xh[b0 >> 1]) = make_uint4(pk[0], pk[1], pk[2], pk[3]);
        *(uint4*)(&Xh[b1 >> 1]) = make_uint4(pk[4], pk[5], pk[6], pk[7]);
    }

    // ---- stage mi tile from miF (coalesced f32) + agg means ----
    for (int t = 0; t < 16; t++) {
        const int ln = wv * 16 + t;
        const int n = nb + ln;
        float val = 0.0f;
        if (n < N) val = miF[(size_t)n * 64 + lane];
        Xm[swzb(ln * 128 + lane * 2) >> 1] = bf16rne(val);
        if (lane < 3 && n < N) {
            const float cf = cntF[n];
            aggM[ln][lane] = aggF[(size_t)n * 3 + lane] / fmaxf(cf, 1.0f);
        }
    }
    __syncthreads();

    // ---- frag loads ----
    const int mb = wv * 16;
    short8 a0, a1, b0, b1;
    {
        const int ba = swzb((mb + fn) * 128 + fk8 * 2);
        const int bb = swzb((mb + fn) * 128 + 64 + fk8 * 2);
        a0 = *(const short8*)(&Xh[ba >> 1]);
        a1 = *(const short8*)(&Xh[bb >> 1]);
        b0 = *(const short8*)(&Xm[ba >> 1]);
        b1 = *(const short8*)(&Xm[bb >> 1]);
    }

    // ---- phi_v ----
    float pvp[4] = {0.f, 0.f, 0.f, 0.f};
    #pragma unroll
    for (int n0 = 0; n0 < 4; n0++) {
        uint4 bw0 = *(const uint4*)(wv1t + (n0*16 + fn) * 64 + fk8);
        uint4 bw1 = *(const uint4*)(wv1t + (n0*16 + fn) * 64 + 32 + fk8);
        const float bias = wv_b1[n0 * 16 + fn];
        f32x4 q = {bias, bias, bias, bias};
        q = __builtin_amdgcn_mfma_f32_16x16x32_bf16(a0, __builtin_bit_cast(short8, bw0), q, 0, 0, 0);
        q = __builtin_amdgcn_mfma_f32_16x16x32_bf16(a1, __builtin_bit_cast(short8, bw1), q, 0, 0, 0);
        const float wqn = wv_w2[n0 * 16 + fn];
        #pragma unroll
        for (int r2 = 0; r2 < 4; r2++) pvp[r2] += fast_tanh(q[r2]) * wqn;
    }
    #pragma unroll
    for (int off = 1; off < 16; off <<= 1) {
        #pragma unroll
        for (int r2 = 0; r2 < 4; r2++) pvp[r2] += __shfl_xor(pvp[r2], off, 64);
    }
    if (fn == 0) {
        const float bv2 = wv_b2[0];
        #pragma unroll
        for (int r2 = 0; r2 < 4; r2++) pvS[mb + (lane >> 4) * 4 + r2] = pvp[r2] + bv2;
    }
    __syncthreads();   // all frag loads done; Xm may now be overwritten

    // ---- phi_h layer 1 (K=128: [h | mi]) -> act tile (into Xm region) ----
    #pragma unroll
    for (int n0 = 0; n0 < 4; n0++) {
        const u16* base = wh1t + (n0*16 + fn) * 128;
        uint4 bw0 = *(const uint4*)(base + fk8);
        uint4 bw1 = *(const uint4*)(base + 32 + fk8);
        uint4 bw2 = *(const uint4*)(base + 64 + fk8);
        uint4 bw3 = *(const uint4*)(base + 96 + fk8);
        const float bias = wh_b1[n0 * 16 + fn];
        f32x4 q = {bias, bias, bias, bias};
        q = __builtin_amdgcn_mfma_f32_16x16x32_bf16(a0, __builtin_bit_cast(short8, bw0), q, 0, 0, 0);
        q = __builtin_amdgcn_mfma_f32_16x16x32_bf16(a1, __builtin_bit_cast(short8, bw1), q, 0, 0, 0);
        q = __builtin_amdgcn_mfma_f32_16x16x32_bf16(b0, __builtin_bit_cast(short8, bw2), q, 0, 0, 0);
        q = __builtin_amdgcn_mfma_f32_16x16x32_bf16(b1, __builtin_bit_cast(short8, bw3), q, 0, 0, 0);
        #pragma unroll
        for (int r2 = 0; r2 < 4; r2++) {
            const int m = mb + (lane >> 4) * 4 + r2;
            Xm[swzb(m * 128 + (n0*16 + fn) * 2) >> 1] = bf16rne(fast_tanh(q[r2]));
        }
    }
    __syncthreads();

    // ---- phi_h layer 2 -> out_h ----
    short8 c0, c1;
    {
        const int ba = swzb((mb + fn) * 128 + fk8 * 2);
        const int bb = swzb((mb + fn) * 128 + 64 + fk8 * 2);
        c0 = *(const short8*)(&Xm[ba >> 1]);
        c1 = *(const short8*)(&Xm[bb >> 1]);
    }
    #pragma unroll
    for (int n0 = 0; n0 < 4; n0++) {
        uint4 bw0 = *(const uint4*)(wh2t + (n0*16 + fn) * 64 + fk8);
        uint4 bw1 = *(const uint4*)(wh2t + (n0*16 + fn) * 64 + 32 + fk8);
        const float bias = wh_b2[n0 * 16 + fn];
        f32x4 q = {bias, bias, bias, bias};
        q = __builtin_amdgcn_mfma_f32_16x16x32_bf16(c0, __builtin_bit_cast(short8, bw0), q, 0, 0, 0);
        q = __builtin_amdgcn_mfma_f32_16x16x32_bf16(c1, __builtin_bit_cast(short8, bw1), q, 0, 0, 0);
        #pragma unroll
        for (int r2 = 0; r2 < 4; r2++) {
            const int m = mb + (lane >> 4) * 4 + r2;
            if (nb + m < N) out_h[(size_t)(nb + m) * 64 + n0 * 16 + fn] = q[r2];
        }
    }

    // ---- coordinate / velocity update ----
    if (tid < 64 && nb + tid < N) {
        const int n = nb + tid;
        const float pv = pvS[tid];
        #pragma unroll
        for (int d = 0; d < 3; d++) {
            const float am = aggM[tid][d];
            const float vn = vel[(size_t)n * 3 + d] * pv + am;
            out_v[(size_t)n * 3 + d] = vn;
            out_x[(size_t)n * 3 + d] = x[(size_t)n * 3 + d] + vn;
        }
    }
}

// ---------------------------------------------------------------- CSR build ---
__global__ void hist_kernel(const int* __restrict__ rows, int* __restrict__ hist, int E) {
    int e = blockIdx.x * blockDim.x + threadIdx.x;
    if (e < E) atomicAdd(&hist[rows[e]], 1);
}

// ---- 3-kernel parallel scan: 1024 elements per block, 256 threads x 4 ----
__global__ __launch_bounds__(256)
void scan1_kernel(const int* __restrict__ hist, int* __restrict__ bsum, int N) {
    const int t = threadIdx.x, b = blockIdx.x;
    const int base = b * 1024 + t * 4;
    int s = 0;
    #pragma unroll
    for (int q = 0; q < 4; q++) s += (base + q < N) ? hist[base + q] : 0;
    #pragma unroll
    for (int off = 1; off < 64; off <<= 1) s += __shfl_xor(s, off, 64);
    __shared__ int ws[4];
    if ((t & 63) == 0) ws[t >> 6] = s;
    __syncthreads();
    if (t == 0) bsum[b] = ws[0] + ws[1] + ws[2] + ws[3];
}

__global__ __launch_bounds__(256)
void scan2_kernel(int* __restrict__ bsum, int nb) {
    __shared__ int buf[1024];
    const int t = threadIdx.x;
    for (int i = t; i < nb; i += 256) buf[i] = bsum[i];
    __syncthreads();
    if (t == 0) {
        int run = 0;
        for (int i = 0; i < nb; i++) { int v = buf[i]; buf[i] = run; run += v; }
    }
    __syncthreads();
    for (int i = t; i < nb; i += 256) bsum[i] = buf[i];
}

__global__ __launch_bounds__(256)
void scan3_kernel(const int* __restrict__ hist, const int* __restrict__ bbase,
                  int* __restrict__ offs, int* __restrict__ cursor, int N) {
    const int t = threadIdx.x, b = blockIdx.x;
    const int base = b * 1024 + t * 4;
    int v[4];
    #pragma unroll
    for (int q = 0; q < 4; q++) v[q] = (base + q < N) ? hist[base + q] : 0;
    const int s = v[0] + v[1] + v[2] + v[3];
    const int lane = t & 63, wid = t >> 6;
    int inc = s;
    #pragma unroll
    for (int off = 1; off < 64; off <<= 1) {
        int u = __shfl_up(inc, off, 64);
        if (lane >= off) inc += u;
    }
    __shared__ int wtot[4];
    if (lane == 63) wtot[wid] = inc;
    __syncthreads();
    int wbase = 0;
    #pragma unroll
    for (int wq = 0; wq < 3; wq++) if (wq < wid) wbase += wtot[wq];
    int run = bbase[b] + wbase + (inc - s);
    #pragma unroll
    for (int q = 0; q < 4; q++) {
        const int i = base + q;
        if (i < N) { cursor[i] = run; run += v[q]; offs[i + 1] = run; }
    }
    if (b == 0 && t == 0) offs[0] = 0;
}

__global__ void scatter_kernel(const int* __restrict__ rows, const int* __restrict__ cols,
                               int* __restrict__ cursor,
                               int* __restrict__ perm, int* __restrict__ colp, int E) {
    int e = blockIdx.x * blockDim.x + threadIdx.x;
    if (e < E) {
        int p = atomicAdd(&cursor[rows[e]], 1);
        perm[p] = e;
        colp[p] = cols[e];
    }
}

__global__ void rowfill_kernel(const int* __restrict__ offs, int* __restrict__ rowp, int N) {
    int n = blockIdx.x * blockDim.x + threadIdx.x;
    if (n < N) {
        const int b = offs[n], e = offs[n + 1];
        for (int i = b; i < e; i++) rowp[i] = n;
    }
}

// ------------------------------------------- fallback kernels (atomic path) ---
template<int BLK>
__global__ __launch_bounds__(BLK)
void edge_atomic_kernel(const float* __restrict__ h, const float* __restrict__ x,
                 const float* __restrict__ eattr,
                 const int* __restrict__ rows, const int* __restrict__ cols,
                 const float* __restrict__ we_w1, const float* __restrict__ we_b1,
                 const float* __restrict__ we_w2, const float* __restrict__ we_b2,
                 const float* __restrict__ wx_w1, const float* __restrict__ wx_b1,
                 const float* __restrict__ wx_w2, const float* __restrict__ wx_b2,
                 float* __restrict__ agg, float* __restrict__ cnt, float* __restrict__ mi,
                 int E)
{
    __shared__ float act[64][BLK];
    const int tid = threadIdx.x;
    const int e = blockIdx.x * BLK + tid;
    if (e >= E) return;

    const int r = rows[e];
    const int c = cols[e];
    const float d0 = x[(size_t)r*3+0] - x[(size_t)c*3+0];
    const float d1 = x[(size_t)r*3+1] - x[(size_t)c*3+1];
    const float d2 = x[(size_t)r*3+2] - x[(size_t)c*3+2];
    const float rad = d0*d0 + d1*d1 + d2*d2;

    float A[64];
    #pragma unroll
    for (int j = 0; j < 64; j++) A[j] = we_b1[j];
    const float* hr = h + (size_t)r * 64;
    const float* hc = h + (size_t)c * 64;
    #pragma unroll 4
    for (int k = 0; k < 64; k++) {
        const float a0 = hr[k];
        const float a1 = hc[k];
        const float* w0 = we_w1 + k * 64;
        const float* w1 = we_w1 + (64 + k) * 64;
        #pragma unroll
        for (int j = 0; j < 64; j++) A[j] += a0 * w0[j] + a1 * w1[j];
    }
    {
        const float* w = we_w1 + 128 * 64;
        #pragma unroll
        for (int j = 0; j < 64; j++) A[j] += rad * w[j];
    }
    const float* ea = eattr + (size_t)e * 8;
    #pragma unroll
    for (int k = 0; k < 8; k++) {
        const float a = ea[k];
        const float* w = we_w1 + (129 + k) * 64;
        #pragma unroll
        for (int j = 0; j < 64; j++) A[j] += a * w[j];
    }
    #pragma unroll
    for (int j = 0; j < 64; j++) act[j][tid] = fast_tanh(A[j]);

    float B[64];
    #pragma unroll
    for (int j = 0; j < 64; j++) B[j] = we_b2[j];
    #pragma unroll 4
    for (int k = 0; k < 64; k++) {
        const float a = act[k][tid];
        const float* w = we_w2 + k * 64;
        #pragma unroll
        for (int j = 0; j < 64; j++) B[j] += a * w[j];
    }
    #pragma unroll
    for (int j = 0; j < 64; j++) act[j][tid] = fast_tanh(B[j]);

    #pragma unroll
    for (int j = 0; j < 64; j++) A[j] = wx_b1[j];
    #pragma unroll 4
    for (int k = 0; k < 64; k++) {
        const float a = act[k][tid];
        const float* w = wx_w1 + k * 64;
        #pragma unroll
        for (int j = 0; j < 64; j++) A[j] += a * w[j];
    }
    float px = wx_b2[0];
    #pragma unroll
    for (int j = 0; j < 64; j++) px += fast_tanh(A[j]) * wx_w2[j];
    px = fast_tanh(px);

    atomicAdd(&agg[(size_t)r*3+0], d0 * px);
    atomicAdd(&agg[(size_t)r*3+1], d1 * px);
    atomicAdd(&agg[(size_t)r*3+2], d2 * px);
    atomicAdd(&cnt[r], 1.0f);
    float* mir = mi + (size_t)r * 64;
    #pragma unroll
    for (int j = 0; j < 64; j++) atomicAdd(&mir[j], act[j][tid]);
}

template<int BLK>
__global__ __launch_bounds__(BLK, 2)
void node_fb_kernel(const float* __restrict__ h, const float* __restrict__ x,
                 const float* __restrict__ vel,
                 const float* __restrict__ wh_w1, const float* __restrict__ wh_b1,
                 const float* __restrict__ wh_w2, const float* __restrict__ wh_b2,
                 const float* __restrict__ wv_w1, const float* __restrict__ wv_b1,
                 const float* __restrict__ wv_w2, const float* __restrict__ wv_b2,
                 const float* __restrict__ agg, const float* __restrict__ cnt,
                 const float* __restrict__ mi,
                 float* __restrict__ out_h, float* __restrict__ out_x, float* __restrict__ out_v,
                 int N)
{
    const int n = blockIdx.x * BLK + threadIdx.x;
    if (n >= N) return;

    const float* hn = h + (size_t)n * 64;
    const float* mn = mi + (size_t)n * 64;

    float A[64];
    #pragma unroll
    for (int j = 0; j < 64; j++) A[j] = wv_b1[j];
    #pragma unroll
    for (int k = 0; k < 64; k++) {
        const float a = hn[k];
        const float* w = wv_w1 + k * 64;
        #pragma unroll
        for (int j = 0; j < 64; j++) A[j] += a * w[j];
    }
    float pv = wv_b2[0];
    #pragma unroll
    for (int j = 0; j < 64; j++) pv += fast_tanh(A[j]) * wv_w2[j];

    #pragma unroll
    for (int j = 0; j < 64; j++) A[j] = wh_b1[j];
    #pragma unroll
    for (int k = 0; k < 64; k++) {
        const float a0 = hn[k];
        const float a1 = mn[k];
        const float* w0 = wh_w1 + k * 64;
        const float* w1 = wh_w1 + (64 + k) * 64;
        #pragma unroll
        for (int j = 0; j < 64; j++) A[j] += a0 * w0[j] + a1 * w1[j];
    }
    #pragma unroll
    for (int j = 0; j < 64; j++) A[j] = fast_tanh(A[j]);

    float B[64];
    #pragma unroll
    for (int j = 0; j < 64; j++) B[j] = wh_b2[j];
    #pragma unroll
    for (int k = 0; k < 64; k++) {
        const float a = A[k];
        const float* w = wh_w2 + k * 64;
        #pragma unroll
        for (int j = 0; j < 64; j++) B[j] += a * w[j];
    }
    float* oh = out_h + (size_t)n * 64;
    #pragma unroll
    for (int j = 0; j < 64; j++) oh[j] = B[j];

    const float inv = 1.0f / fmaxf(cnt[n], 1.0f);
    #pragma unroll
    for (int d = 0; d < 3; d++) {
        const float am = agg[(size_t)n*3 + d] * inv;
        const float vn = vel[(size_t)n*3 + d] * pv + am;
        out_v[(size_t)n*3 + d] = vn;
        out_x[(size_t)n*3 + d] = x[(size_t)n*3 + d] + vn;
    }
}

// ------------------------------------------------------------------ launch ---
extern "C" void kernel_launch(void* const* d_in, const int* in_sizes, int n_in,
                              void* d_out, int out_size, void* d_ws, size_t ws_size,
                              hipStream_t stream) {
    const float* h      = (const float*)d_in[0];
    const float* x      = (const float*)d_in[1];
    const float* vel    = (const float*)d_in[2];
    const float* eattr  = (const float*)d_in[3];
    const float* we_w1  = (const float*)d_in[4];
    const float* we_b1  = (const float*)d_in[5];
    const float* we_w2  = (const float*)d_in[6];
    const float* we_b2  = (const float*)d_in[7];
    const float* wx_w1  = (const float*)d_in[8];
    const float* wx_b1  = (const float*)d_in[9];
    const float* wx_w2  = (const float*)d_in[10];
    const float* wx_b2  = (const float*)d_in[11];
    const float* wh_w1  = (const float*)d_in[12];
    const float* wh_b1  = (const float*)d_in[13];
    const float* wh_w2  = (const float*)d_in[14];
    const float* wh_b2  = (const float*)d_in[15];
    const float* wv_w1  = (const float*)d_in[16];
    const float* wv_b1  = (const float*)d_in[17];
    const float* wv_w2  = (const float*)d_in[18];
    const float* wv_b2  = (const float*)d_in[19];
    const int*   ar     = (const int*)d_in[20];

    const int N = in_sizes[0] / 64;
    const int E = in_sizes[20] / 2;
    const int* rows = ar;
    const int* cols = ar + E;

    float* out_h = (float*)d_out;            // N*64 (HrB/HcB bf16 scratch first)
    float* out_x = out_h + (size_t)N * 64;   // N*3
    float* out_v = out_x + (size_t)N * 3;    // N*3

    u16* HrB = (u16*)d_out;
    u16* HcB = HrB + (size_t)N * 64;

    const int nbScan = (N + 1023) / 1024;

    // --- workspace layout: ~48 MB. miF..hist contiguous -> ONE memset ---
    char* p = (char*)d_ws;
    float* miF  = (float*)p; p += (size_t)N * 64 * sizeof(float);
    float* aggF = (float*)p; p += (size_t)N * 3 * sizeof(float);
    float* cntF = (float*)p; p += (size_t)N * sizeof(float);
    int*  hist  = (int*)p;   p += (size_t)N * sizeof(int);
    const size_t zero_bytes = (size_t)(p - (char*)d_ws);
    int*  offs  = (int*)p;   p += (size_t)(N + 1) * sizeof(int);
    int*  cursor= (int*)p;   p += (size_t)N * sizeof(int);
    int*  bsum  = (int*)p;   p += (size_t)(nbScan > 0 ? nbScan : 1) * sizeof(int);
    int*  perm  = (int*)p;   p += (size_t)E * sizeof(int);
    int*  rowp  = (int*)p;   p += (size_t)E * sizeof(int);
    int*  colp  = (int*)p;   p += (size_t)E * sizeof(int);
    p = (char*)(((uintptr_t)p + 63) & ~(uintptr_t)63);
    u16*  we1t = (u16*)p;   p += 64 * 128 * sizeof(u16);
    u16*  we2t = (u16*)p;   p += 64 * 64 * sizeof(u16);
    u16*  wx1t = (u16*)p;   p += 64 * 64 * sizeof(u16);
    u16*  wv1t = (u16*)p;   p += 64 * 64 * sizeof(u16);
    u16*  wh1t = (u16*)p;   p += 64 * 128 * sizeof(u16);
    u16*  wh2t = (u16*)p;   p += 64 * 64 * sizeof(u16);
    const size_t needed = (size_t)(p - (char*)d_ws);

    if (ws_size >= needed && nbScan <= 1024) {
        hipMemsetAsync(d_ws, 0, zero_bytes, stream);
        hist_kernel<<<(E + 255) / 256, 256, 0, stream>>>(rows, hist, E);
        scan1_kernel<<<nbScan, 256, 0, stream>>>(hist, bsum, N);
        scan2_kernel<<<1, 256, 0, stream>>>(bsum, nbScan);
        scan3_kernel<<<nbScan, 256, 0, stream>>>(hist, bsum, offs, cursor, N);
        scatter_kernel<<<(E + 255) / 256, 256, 0, stream>>>(rows, cols, cursor, perm, colp, E);
        rowfill_kernel<<<(N + 255) / 256, 256, 0, stream>>>(offs, rowp, N);

        wprep_kernel<<<32, 256, 0, stream>>>(we_w1, we_w2, wx_w1, wv_w1, wh_w1, wh_w2,
                                             we1t, we2t, wx1t, wv1t, wh1t, wh2t);
        pre_mfma_kernel<<<(N + 63) / 64, 256, 0, stream>>>(h, we_b1, we1t, HrB, HcB, N);

        edge_mfma_kernel<<<(E + 63) / 64, 256, 0, stream>>>(
            x, eattr, perm, rowp, colp, HrB, HcB,
            we_w1, we2t, we_b2, wx1t, wx_b1, wx_w2, wx_b2,
            miF, aggF, cntF, E);

        aggnode_kernel<<<(N + 63) / 64, 256, 0, stream>>>(
            h, x, vel, miF, aggF, cntF,
            wv1t, wv_b1, wv_w2, wv_b2,
            wh1t, wh_b1, wh2t, wh_b2,
            out_h, out_x, out_v, N);
    } else {
        // --- fallback: atomic path ---
        float* agg2 = (float*)d_ws;               // N*3
        float* cnt2 = agg2 + (size_t)N * 3;       // N
        float* mi2  = cnt2 + N;                   // N*64
        hipMemsetAsync(d_ws, 0, (size_t)N * 68 * sizeof(float), stream);

        edge_atomic_kernel<128><<<(E + 127) / 128, 128, 0, stream>>>(
            h, x, eattr, rows, cols,
            we_w1, we_b1, we_w2, we_b2,
            wx_w1, wx_b1, wx_w2, wx_b2,
            agg2, cnt2, mi2, E);

        node_fb_kernel<128><<<(N + 127) / 128, 128, 0, stream>>>(
            h, x, vel,
            wh_w1, wh_b1, wh_w2, wh_b2,
            wv_w1, wv_b1, wv_w2, wv_b2,
            agg2, cnt2, mi2, out_h, out_x, out_v, N);
    }
}

// Round 9
// 578.738 us; speedup vs baseline: 10.8461x; 1.2240x over previous
//
#include <hip/hip_runtime.h>

// EGNN layer (CamadaEquivariante), round 9:
//  - pre_mfma: Hr/Hc bf16 MFMA GEMM (outputs in d_out scratch).       [r6, kept]
//  - edge_mfma: rad+eattr contribution now a 4-MFMA (K=32) with wert table;
//    phase A = Hr+Hc sum only; v_perm 1-inst bf16 packs; XCD-chunked swizzle.
//    Fused segment-sum -> f32 atomics to miF/aggF/cntF.                [r8 base]
//  - aggnode: reads miF/aggF/cntF, MFMA node MLPs.                     [r8, kept]
//  - CSR build: hist -> 3-kernel parallel scan -> scatter -> rowfill.  [r8, kept]
// ws ~= 48 MB. Fallback to atomic path if ws too small.

typedef unsigned int uint;
typedef unsigned short u16;
typedef __attribute__((ext_vector_type(8))) short short8;
typedef __attribute__((ext_vector_type(4))) float f32x4;

#define UB_LO(u) __uint_as_float((u) << 16)
#define UB_HI(u) __uint_as_float((u) & 0xffff0000u)

__device__ __forceinline__ float fast_tanh(float x) {
    float e = __expf(2.0f * x);
    return 1.0f - 2.0f * __builtin_amdgcn_rcpf(e + 1.0f);
}
__device__ __forceinline__ u16 bf16rne(float f) {
    uint u = __float_as_uint(f);
    return (u16)((u + 0x7fffu + ((u >> 16) & 1u)) >> 16);
}
__device__ __forceinline__ uint packbf(float a, float b) {
    return (uint)bf16rne(a) | ((uint)bf16rne(b) << 16);
}
// 1-inst truncating bf16x2 pack: lo16 = hi16(a), hi16 = hi16(b)
__device__ __forceinline__ uint packbf_fast(float a, float b) {
    return __builtin_amdgcn_perm(__float_as_uint(b), __float_as_uint(a), 0x07060302u);
}
__device__ __forceinline__ u16 trunc16(float f) {
    return (u16)(__float_as_uint(f) >> 16);
}
// XOR-swizzle within a [64][64]-bf16 (128B-row) LDS tile: byte ^= ((row&7)<<4)
__device__ __forceinline__ int swzb(int b) { return b ^ ((b >> 3) & 0x70); }

// ------------------------------------------------- weight transpose (bf16) ---
__global__ void wprep_kernel(const float* __restrict__ we_w1, const float* __restrict__ we_w2,
                             const float* __restrict__ wx_w1, const float* __restrict__ wv_w1,
                             const float* __restrict__ wh_w1, const float* __restrict__ wh_w2,
                             u16* __restrict__ we1t, u16* __restrict__ we2t,
                             u16* __restrict__ wx1t, u16* __restrict__ wv1t,
                             u16* __restrict__ wh1t, u16* __restrict__ wh2t,
                             u16* __restrict__ wert) {
    int t = blockIdx.x * 256 + threadIdx.x;
    if (t < 8192) {
        int j = t >> 7, k = t & 127;
        we1t[t] = bf16rne(we_w1[k * 64 + j]);
        wh1t[t] = bf16rne(wh_w1[k * 64 + j]);
    }
    if (t < 4096) {
        int n = t >> 6, k = t & 63;
        we2t[t] = bf16rne(we_w2[k * 64 + n]);
        wx1t[t] = bf16rne(wx_w1[k * 64 + n]);
        wv1t[t] = bf16rne(wv_w1[k * 64 + n]);
        wh2t[t] = bf16rne(wh_w2[k * 64 + n]);
    }
    if (t < 2048) {          // wert[n][k], k=0 -> rad row (128), k=1..8 -> rows 129..136
        int n = t >> 5, k = t & 31;
        float v = 0.0f;
        if (k == 0) v = we_w1[128 * 64 + n];
        else if (k <= 8) v = we_w1[(128 + k) * 64 + n];
        wert[t] = bf16rne(v);
    }
}

// --------------------------------------------------------- pre MFMA kernel ---
__global__ __launch_bounds__(256, 2)
void pre_mfma_kernel(const float* __restrict__ h, const float* __restrict__ we_b1,
                     const u16* __restrict__ we1t,
                     u16* __restrict__ HrB, u16* __restrict__ HcB, int N)
{
    __shared__ u16 X1[4096];
    __shared__ u16 X2[4096];
    const int tid = threadIdx.x, lane = tid & 63, wv = tid >> 6;
    const int nb = blockIdx.x * 64;
    const int el = tid >> 2, jg = tid & 3;
    const int fn = lane & 15, fk8 = (lane >> 4) * 8;

    {
        uint pk[8];
        if (nb + el < N) {
            const float4* h4 = (const float4*)(h + (size_t)(nb + el) * 64 + jg * 16);
            #pragma unroll
            for (int q = 0; q < 4; q++) {
                float4 v = h4[q];
                pk[2*q]   = packbf_fast(v.x, v.y);
                pk[2*q+1] = packbf_fast(v.z, v.w);
            }
        } else {
            #pragma unroll
            for (int q = 0; q < 8; q++) pk[q] = 0;
        }
        const int b0 = swzb(el * 128 + jg * 32), b1 = swzb(el * 128 + jg * 32 + 16);
        *(uint4*)(&X1[b0 >> 1]) = make_uint4(pk[0], pk[1], pk[2], pk[3]);
        *(uint4*)(&X1[b1 >> 1]) = make_uint4(pk[4], pk[5], pk[6], pk[7]);
    }
    __syncthreads();

    const int mb = wv * 16;
    short8 a0, a1;
    {
        const int ba = swzb((mb + fn) * 128 + fk8 * 2);
        const int bb = swzb((mb + fn) * 128 + 64 + fk8 * 2);
        a0 = *(const short8*)(&X1[ba >> 1]);
        a1 = *(const short8*)(&X1[bb >> 1]);
    }
    // Hr = h @ We1[0:64] + b1
    #pragma unroll
    for (int n0 = 0; n0 < 4; n0++) {
        uint4 bw0 = *(const uint4*)(we1t + (n0*16 + fn) * 128 + fk8);
        uint4 bw1 = *(const uint4*)(we1t + (n0*16 + fn) * 128 + 32 + fk8);
        const float bias = we_b1[n0 * 16 + fn];
        f32x4 q = {bias, bias, bias, bias};
        q = __builtin_amdgcn_mfma_f32_16x16x32_bf16(a0, __builtin_bit_cast(short8, bw0), q, 0, 0, 0);
        q = __builtin_amdgcn_mfma_f32_16x16x32_bf16(a1, __builtin_bit_cast(short8, bw1), q, 0, 0, 0);
        #pragma unroll
        for (int r2 = 0; r2 < 4; r2++) {
            const int m = mb + (lane >> 4) * 4 + r2;
            X2[swzb(m * 128 + (n0*16 + fn) * 2) >> 1] = bf16rne(q[r2]);
        }
    }
    __syncthreads();
    if (nb + el < N) {
        const int b0 = swzb(el * 128 + jg * 32), b1 = swzb(el * 128 + jg * 32 + 16);
        uint4 v0 = *(const uint4*)(&X2[b0 >> 1]);
        uint4 v1 = *(const uint4*)(&X2[b1 >> 1]);
        u16* o = HrB + (size_t)(nb + el) * 64 + jg * 16;
        *(uint4*)o = v0; *(uint4*)(o + 8) = v1;
    }
    __syncthreads();
    // Hc = h @ We1[64:128]
    #pragma unroll
    for (int n0 = 0; n0 < 4; n0++) {
        uint4 bw0 = *(const uint4*)(we1t + (n0*16 + fn) * 128 + 64 + fk8);
        uint4 bw1 = *(const uint4*)(we1t + (n0*16 + fn) * 128 + 96 + fk8);
        f32x4 q = {0.f, 0.f, 0.f, 0.f};
        q = __builtin_amdgcn_mfma_f32_16x16x32_bf16(a0, __builtin_bit_cast(short8, bw0), q, 0, 0, 0);
        q = __builtin_amdgcn_mfma_f32_16x16x32_bf16(a1, __builtin_bit_cast(short8, bw1), q, 0, 0, 0);
        #pragma unroll
        for (int r2 = 0; r2 < 4; r2++) {
            const int m = mb + (lane >> 4) * 4 + r2;
            X2[swzb(m * 128 + (n0*16 + fn) * 2) >> 1] = bf16rne(q[r2]);
        }
    }
    __syncthreads();
    if (nb + el < N) {
        const int b0 = swzb(el * 128 + jg * 32), b1 = swzb(el * 128 + jg * 32 + 16);
        uint4 v0 = *(const uint4*)(&X2[b0 >> 1]);
        uint4 v1 = *(const uint4*)(&X2[b1 >> 1]);
        u16* o = HcB + (size_t)(nb + el) * 64 + jg * 16;
        *(uint4*)o = v0; *(uint4*)(o + 8) = v1;
    }
}

// --------------------------------------------------------- edge MFMA kernel ---
// Slot order + XCD-chunked swizzle. Layer1 = (Hr+Hc from LDS Xp) + MFMA(rad,ea).
__global__ __launch_bounds__(256, 2)
void edge_mfma_kernel(const float* __restrict__ x, const float* __restrict__ eattr,
                      const int* __restrict__ perm, const int* __restrict__ rowp,
                      const int* __restrict__ colp,
                      const u16* __restrict__ HrB, const u16* __restrict__ HcB,
                      const u16* __restrict__ wert,
                      const u16* __restrict__ we2t, const float* __restrict__ we_b2,
                      const u16* __restrict__ wx1t, const float* __restrict__ wx_b1,
                      const float* __restrict__ wx_w2, const float* __restrict__ wx_b2,
                      float* __restrict__ miF, float* __restrict__ aggF,
                      float* __restrict__ cntF, int E)
{
    __shared__ u16 Xp[4096];   // Hr+Hc pre-sum (bf16, swizzled)
    __shared__ u16 X1[4096];
    __shared__ u16 X2[4096];
    __shared__ float dS[64][3];
    __shared__ float pxS[64];
    __shared__ int rS[64];

    const int tid = threadIdx.x, lane = tid & 63, wv = tid >> 6;
    int bid = blockIdx.x;
    const int nwg = gridDim.x;
    if ((nwg & 7) == 0) bid = (bid & 7) * (nwg >> 3) + (bid >> 3);  // XCD-chunked
    const int sb = bid * 64;
    const int fn = lane & 15, fk8 = (lane >> 4) * 8;
    const int el = tid >> 2, jg = tid & 3;
    const int s = sb + el;
    const int mb = wv * 16;

    // ---- phase A: Xp = Hr[r] + Hc[c] (bf16), dS, rS ----
    {
        int r = -1, c = 0;
        if (s < E) { r = rowp[s]; c = colp[s]; }
        if (jg == 0) rS[el] = r;
        uint pk[8];
        if (s < E) {
            if (jg == 0) {
                dS[el][0] = x[(size_t)r*3+0] - x[(size_t)c*3+0];
                dS[el][1] = x[(size_t)r*3+1] - x[(size_t)c*3+1];
                dS[el][2] = x[(size_t)r*3+2] - x[(size_t)c*3+2];
            }
            uint4 ra = *(const uint4*)(HrB + (size_t)r * 64 + jg * 16);
            uint4 rb = *(const uint4*)(HrB + (size_t)r * 64 + jg * 16 + 8);
            uint4 ca = *(const uint4*)(HcB + (size_t)c * 64 + jg * 16);
            uint4 cb = *(const uint4*)(HcB + (size_t)c * 64 + jg * 16 + 8);
            uint rw[8] = {ra.x, ra.y, ra.z, ra.w, rb.x, rb.y, rb.z, rb.w};
            uint cw[8] = {ca.x, ca.y, ca.z, ca.w, cb.x, cb.y, cb.z, cb.w};
            #pragma unroll
            for (int q = 0; q < 8; q++) {
                const float lo = UB_LO(rw[q]) + UB_LO(cw[q]);
                const float hi = UB_HI(rw[q]) + UB_HI(cw[q]);
                pk[q] = packbf_fast(lo, hi);
            }
        } else {
            #pragma unroll
            for (int q = 0; q < 8; q++) pk[q] = 0;
        }
        const int b0 = swzb(el * 128 + jg * 32), b1 = swzb(el * 128 + jg * 32 + 16);
        *(uint4*)(&Xp[b0 >> 1]) = make_uint4(pk[0], pk[1], pk[2], pk[3]);
        *(uint4*)(&Xp[b1 >> 1]) = make_uint4(pk[4], pk[5], pk[6], pk[7]);
    }

    // ---- ea/rad A-frag: lane fn = edge (mb+fn), k-chunk = lane>>4 ----
    uint ae[4] = {0, 0, 0, 0};
    {
        const int kc = lane >> 4;
        const int s2 = sb + mb + fn;
        if (kc < 2 && s2 < E) {
            const int e2 = perm[s2];
            const float4* ea4 = (const float4*)(eattr + (size_t)e2 * 8);
            float4 u0 = ea4[0], u1 = ea4[1];
            if (kc == 0) {
                const int r2_ = rowp[s2], c2_ = colp[s2];
                const float dd0 = x[(size_t)r2_*3+0] - x[(size_t)c2_*3+0];
                const float dd1 = x[(size_t)r2_*3+1] - x[(size_t)c2_*3+1];
                const float dd2 = x[(size_t)r2_*3+2] - x[(size_t)c2_*3+2];
                const float rad = dd0*dd0 + dd1*dd1 + dd2*dd2;
                ae[0] = packbf_fast(rad,  u0.x);   // k0=rad, k1=ea0
                ae[1] = packbf_fast(u0.y, u0.z);   // ea1, ea2
                ae[2] = packbf_fast(u0.w, u1.x);   // ea3, ea4
                ae[3] = packbf_fast(u1.y, u1.z);   // ea5, ea6
            } else {
                ae[0] = packbf_fast(u1.w, 0.0f);   // k8=ea7
            }
        }
    }
    const short8 a_e = __builtin_bit_cast(short8, *(uint4*)ae);
    __syncthreads();

    // ---- layer 1: q = MFMA(ea, wert); X1 = tanh(q + Xp) ----
    #pragma unroll
    for (int n0 = 0; n0 < 4; n0++) {
        uint4 bw = *(const uint4*)(wert + (n0*16 + fn) * 32 + fk8);
        f32x4 q = {0.f, 0.f, 0.f, 0.f};
        q = __builtin_amdgcn_mfma_f32_16x16x32_bf16(a_e, __builtin_bit_cast(short8, bw), q, 0, 0, 0);
        #pragma unroll
        for (int r2 = 0; r2 < 4; r2++) {
            const int idx = swzb((mb + (lane >> 4) * 4 + r2) * 128 + (n0*16 + fn) * 2) >> 1;
            const float pre = q[r2] + UB_LO((uint)Xp[idx]);
            X1[idx] = trunc16(fast_tanh(pre));
        }
    }
    __syncthreads();

    // ---- layer 2 MFMA: X2 = tanh(X1 @ We2 + b2) ----
    short8 a0, a1;
    {
        const int ba = swzb((mb + fn) * 128 + fk8 * 2);
        const int bb = swzb((mb + fn) * 128 + 64 + fk8 * 2);
        a0 = *(const short8*)(&X1[ba >> 1]);
        a1 = *(const short8*)(&X1[bb >> 1]);
    }
    #pragma unroll
    for (int n0 = 0; n0 < 4; n0++) {
        uint4 bw0 = *(const uint4*)(we2t + (n0*16 + fn) * 64 + fk8);
        uint4 bw1 = *(const uint4*)(we2t + (n0*16 + fn) * 64 + 32 + fk8);
        const float bias = we_b2[n0 * 16 + fn];
        f32x4 q = {bias, bias, bias, bias};
        q = __builtin_amdgcn_mfma_f32_16x16x32_bf16(a0, __builtin_bit_cast(short8, bw0), q, 0, 0, 0);
        q = __builtin_amdgcn_mfma_f32_16x16x32_bf16(a1, __builtin_bit_cast(short8, bw1), q, 0, 0, 0);
        #pragma unroll
        for (int r2 = 0; r2 < 4; r2++) {
            const int m = mb + (lane >> 4) * 4 + r2;
            X2[swzb(m * 128 + (n0*16 + fn) * 2) >> 1] = bf16rne(fast_tanh(q[r2]));
        }
    }
    __syncthreads();

    // ---- phi_x: S = X2 @ Wx1 + b1; px = tanh(tanh(S) @ wx2 + b2) ----
    short8 c0, c1;
    {
        const int ba = swzb((mb + fn) * 128 + fk8 * 2);
        const int bb = swzb((mb + fn) * 128 + 64 + fk8 * 2);
        c0 = *(const short8*)(&X2[ba >> 1]);
        c1 = *(const short8*)(&X2[bb >> 1]);
    }
    float pxp[4] = {0.f, 0.f, 0.f, 0.f};
    #pragma unroll
    for (int n0 = 0; n0 < 4; n0++) {
        uint4 bw0 = *(const uint4*)(wx1t + (n0*16 + fn) * 64 + fk8);
        uint4 bw1 = *(const uint4*)(wx1t + (n0*16 + fn) * 64 + 32 + fk8);
        const float bias = wx_b1[n0 * 16 + fn];
        f32x4 q = {bias, bias, bias, bias};
        q = __builtin_amdgcn_mfma_f32_16x16x32_bf16(c0, __builtin_bit_cast(short8, bw0), q, 0, 0, 0);
        q = __builtin_amdgcn_mfma_f32_16x16x32_bf16(c1, __builtin_bit_cast(short8, bw1), q, 0, 0, 0);
        const float wqn = wx_w2[n0 * 16 + fn];
        #pragma unroll
        for (int r2 = 0; r2 < 4; r2++) pxp[r2] += fast_tanh(q[r2]) * wqn;
    }
    #pragma unroll
    for (int off = 1; off < 16; off <<= 1) {
        #pragma unroll
        for (int r2 = 0; r2 < 4; r2++) pxp[r2] += __shfl_xor(pxp[r2], off, 64);
    }
    if (fn == 0) {
        const float bx2 = wx_b2[0];
        #pragma unroll
        for (int r2 = 0; r2 < 4; r2++) {
            const int m = mb + (lane >> 4) * 4 + r2;
            pxS[m] = fast_tanh(pxp[r2] + bx2);
        }
    }
    __syncthreads();

    // ---- fused segment sum: wave w owns segments STARTING in [w*16, w*16+16) ----
    const int w16 = wv * 16;
    for (int s0 = w16; s0 < w16 + 16; s0++) {
        const int r0 = rS[s0];
        if (r0 < 0) continue;
        if (s0 > 0 && rS[s0 - 1] == r0) continue;   // not a segment start
        int s1 = s0 + 1;
        while (s1 < 64 && rS[s1] == r0) s1++;
        float msum = 0.0f, tsum = 0.0f;
        for (int t = s0; t < s1; t++) {
            msum += UB_LO((uint)X2[swzb(t * 128 + lane * 2) >> 1]);
            if (lane < 3) tsum += dS[t][lane] * pxS[t];
        }
        atomicAdd(&miF[(size_t)r0 * 64 + lane], msum);
        if (lane < 3) atomicAdd(&aggF[(size_t)r0 * 3 + lane], tsum);
        if (lane == 3) atomicAdd(&cntF[r0], (float)(s1 - s0));
    }
}

// ---------------------------------------------- fused aggregation + node MLP ---
__global__ __launch_bounds__(256, 2)
void aggnode_kernel(const float* __restrict__ h, const float* __restrict__ x,
                    const float* __restrict__ vel,
                    const float* __restrict__ miF, const float* __restrict__ aggF,
                    const float* __restrict__ cntF,
                    const u16* __restrict__ wv1t, const float* __restrict__ wv_b1,
                    const float* __restrict__ wv_w2, const float* __restrict__ wv_b2,
                    const u16* __restrict__ wh1t, const float* __restrict__ wh_b1,
                    const u16* __restrict__ wh2t, const float* __restrict__ wh_b2,
                    float* __restrict__ out_h, float* __restrict__ out_x,
                    float* __restrict__ out_v, int N)
{
    __shared__ u16 Xh[4096];      // h tile, bf16 swizzled
    __shared__ u16 Xm[4096];      // mi tile, then reused for act tile
    __shared__ float aggM[64][3];
    __shared__ float pvS[64];

    const int tid = threadIdx.x, lane = tid & 63, wv = tid >> 6;
    const int nb = blockIdx.x * 64;
    const int el = tid >> 2, jg = tid & 3;
    const int fn = lane & 15, fk8 = (lane >> 4) * 8;

    // ---- stage h tile ----
    {
        uint pk[8];
        if (nb + el < N) {
            const float4* h4 = (const float4*)(h + (size_t)(nb + el) * 64 + jg * 16);
            #pragma unroll
            for (int q = 0; q < 4; q++) {
                float4 v = h4[q];
                pk[2*q]   = packbf_fast(v.x, v.y);
                pk[2*q+1] = packbf_fast(v.z, v.w);
            }
        } else {
            #pragma unroll
            for (int q = 0; q < 8; q++) pk[q] = 0;
        }
        const int b0 = swzb(el * 128 + jg * 32), b1 = swzb(el * 128 + jg * 32 + 16);
        *(uint4*)(&Xh[b0 >> 1]) = make_uint4(pk[0], pk[1], pk[2], pk[3]);
        *(uint4*)(&Xh[b1 >> 1]) = make_uint4(pk[4], pk[5], pk[6], pk[7]);
    }

    // ---- stage mi tile from miF (coalesced f32) + agg means ----
    for (int t = 0; t < 16; t++) {
        const int ln = wv * 16 + t;
        const int n = nb + ln;
        float val = 0.0f;
        if (n < N) val = miF[(size_t)n * 64 + lane];
        Xm[swzb(ln * 128 + lane * 2) >> 1] = bf16rne(val);
        if (lane < 3 && n < N) {
            const float cf = cntF[n];
            aggM[ln][lane] = aggF[(size_t)n * 3 + lane] / fmaxf(cf, 1.0f);
        }
    }
    __syncthreads();

    // ---- frag loads ----
    const int mb = wv * 16;
    short8 a0, a1, b0, b1;
    {
        const int ba = swzb((mb + fn) * 128 + fk8 * 2);
        const int bb = swzb((mb + fn) * 128 + 64 + fk8 * 2);
        a0 = *(const short8*)(&Xh[ba >> 1]);
        a1 = *(const short8*)(&Xh[bb >> 1]);
        b0 = *(const short8*)(&Xm[ba >> 1]);
        b1 = *(const short8*)(&Xm[bb >> 1]);
    }

    // ---- phi_v ----
    float pvp[4] = {0.f, 0.f, 0.f, 0.f};
    #pragma unroll
    for (int n0 = 0; n0 < 4; n0++) {
        uint4 bw0 = *(const uint4*)(wv1t + (n0*16 + fn) * 64 + fk8);
        uint4 bw1 = *(const uint4*)(wv1t + (n0*16 + fn) * 64 + 32 + fk8);
        const float bias = wv_b1[n0 * 16 + fn];
        f32x4 q = {bias, bias, bias, bias};
        q = __builtin_amdgcn_mfma_f32_16x16x32_bf16(a0, __builtin_bit_cast(short8, bw0), q, 0, 0, 0);
        q = __builtin_amdgcn_mfma_f32_16x16x32_bf16(a1, __builtin_bit_cast(short8, bw1), q, 0, 0, 0);
        const float wqn = wv_w2[n0 * 16 + fn];
        #pragma unroll
        for (int r2 = 0; r2 < 4; r2++) pvp[r2] += fast_tanh(q[r2]) * wqn;
    }
    #pragma unroll
    for (int off = 1; off < 16; off <<= 1) {
        #pragma unroll
        for (int r2 = 0; r2 < 4; r2++) pvp[r2] += __shfl_xor(pvp[r2], off, 64);
    }
    if (fn == 0) {
        const float bv2 = wv_b2[0];
        #pragma unroll
        for (int r2 = 0; r2 < 4; r2++) pvS[mb + (lane >> 4) * 4 + r2] = pvp[r2] + bv2;
    }
    __syncthreads();   // all frag loads done; Xm may now be overwritten

    // ---- phi_h layer 1 (K=128: [h | mi]) -> act tile (into Xm region) ----
    #pragma unroll
    for (int n0 = 0; n0 < 4; n0++) {
        const u16* base = wh1t + (n0*16 + fn) * 128;
        uint4 bw0 = *(const uint4*)(base + fk8);
        uint4 bw1 = *(const uint4*)(base + 32 + fk8);
        uint4 bw2 = *(const uint4*)(base + 64 + fk8);
        uint4 bw3 = *(const uint4*)(base + 96 + fk8);
        const float bias = wh_b1[n0 * 16 + fn];
        f32x4 q = {bias, bias, bias, bias};
        q = __builtin_amdgcn_mfma_f32_16x16x32_bf16(a0, __builtin_bit_cast(short8, bw0), q, 0, 0, 0);
        q = __builtin_amdgcn_mfma_f32_16x16x32_bf16(a1, __builtin_bit_cast(short8, bw1), q, 0, 0, 0);
        q = __builtin_amdgcn_mfma_f32_16x16x32_bf16(b0, __builtin_bit_cast(short8, bw2), q, 0, 0, 0);
        q = __builtin_amdgcn_mfma_f32_16x16x32_bf16(b1, __builtin_bit_cast(short8, bw3), q, 0, 0, 0);
        #pragma unroll
        for (int r2 = 0; r2 < 4; r2++) {
            const int m = mb + (lane >> 4) * 4 + r2;
            Xm[swzb(m * 128 + (n0*16 + fn) * 2) >> 1] = bf16rne(fast_tanh(q[r2]));
        }
    }
    __syncthreads();

    // ---- phi_h layer 2 -> out_h ----
    short8 c0, c1;
    {
        const int ba = swzb((mb + fn) * 128 + fk8 * 2);
        const int bb = swzb((mb + fn) * 128 + 64 + fk8 * 2);
        c0 = *(const short8*)(&Xm[ba >> 1]);
        c1 = *(const short8*)(&Xm[bb >> 1]);
    }
    #pragma unroll
    for (int n0 = 0; n0 < 4; n0++) {
        uint4 bw0 = *(const uint4*)(wh2t + (n0*16 + fn) * 64 + fk8);
        uint4 bw1 = *(const uint4*)(wh2t + (n0*16 + fn) * 64 + 32 + fk8);
        const float bias = wh_b2[n0 * 16 + fn];
        f32x4 q = {bias, bias, bias, bias};
        q = __builtin_amdgcn_mfma_f32_16x16x32_bf16(c0, __builtin_bit_cast(short8, bw0), q, 0, 0, 0);
        q = __builtin_amdgcn_mfma_f32_16x16x32_bf16(c1, __builtin_bit_cast(short8, bw1), q, 0, 0, 0);
        #pragma unroll
        for (int r2 = 0; r2 < 4; r2++) {
            const int m = mb + (lane >> 4) * 4 + r2;
            if (nb + m < N) out_h[(size_t)(nb + m) * 64 + n0 * 16 + fn] = q[r2];
        }
    }

    // ---- coordinate / velocity update ----
    if (tid < 64 && nb + tid < N) {
        const int n = nb + tid;
        const float pv = pvS[tid];
        #pragma unroll
        for (int d = 0; d < 3; d++) {
            const float am = aggM[tid][d];
            const float vn = vel[(size_t)n * 3 + d] * pv + am;
            out_v[(size_t)n * 3 + d] = vn;
            out_x[(size_t)n * 3 + d] = x[(size_t)n * 3 + d] + vn;
        }
    }
}

// ---------------------------------------------------------------- CSR build ---
__global__ void hist_kernel(const int* __restrict__ rows, int* __restrict__ hist, int E) {
    int e = blockIdx.x * blockDim.x + threadIdx.x;
    if (e < E) atomicAdd(&hist[rows[e]], 1);
}

__global__ __launch_bounds__(256)
void scan1_kernel(const int* __restrict__ hist, int* __restrict__ bsum, int N) {
    const int t = threadIdx.x, b = blockIdx.x;
    const int base = b * 1024 + t * 4;
    int s = 0;
    #pragma unroll
    for (int q = 0; q < 4; q++) s += (base + q < N) ? hist[base + q] : 0;
    #pragma unroll
    for (int off = 1; off < 64; off <<= 1) s += __shfl_xor(s, off, 64);
    __shared__ int ws[4];
    if ((t & 63) == 0) ws[t >> 6] = s;
    __syncthreads();
    if (t == 0) bsum[b] = ws[0] + ws[1] + ws[2] + ws[3];
}

__global__ __launch_bounds__(256)
void scan2_kernel(int* __restrict__ bsum, int nb) {
    __shared__ int buf[1024];
    const int t = threadIdx.x;
    for (int i = t; i < nb; i += 256) buf[i] = bsum[i];
    __syncthreads();
    if (t == 0) {
        int run = 0;
        for (int i = 0; i < nb; i++) { int v = buf[i]; buf[i] = run; run += v; }
    }
    __syncthreads();
    for (int i = t; i < nb; i += 256) bsum[i] = buf[i];
}

__global__ __launch_bounds__(256)
void scan3_kernel(const int* __restrict__ hist, const int* __restrict__ bbase,
                  int* __restrict__ offs, int* __restrict__ cursor, int N) {
    const int t = threadIdx.x, b = blockIdx.x;
    const int base = b * 1024 + t * 4;
    int v[4];
    #pragma unroll
    for (int q = 0; q < 4; q++) v[q] = (base + q < N) ? hist[base + q] : 0;
    const int s = v[0] + v[1] + v[2] + v[3];
    const int lane = t & 63, wid = t >> 6;
    int inc = s;
    #pragma unroll
    for (int off = 1; off < 64; off <<= 1) {
        int u = __shfl_up(inc, off, 64);
        if (lane >= off) inc += u;
    }
    __shared__ int wtot[4];
    if (lane == 63) wtot[wid] = inc;
    __syncthreads();
    int wbase = 0;
    #pragma unroll
    for (int wq = 0; wq < 3; wq++) if (wq < wid) wbase += wtot[wq];
    int run = bbase[b] + wbase + (inc - s);
    #pragma unroll
    for (int q = 0; q < 4; q++) {
        const int i = base + q;
        if (i < N) { cursor[i] = run; run += v[q]; offs[i + 1] = run; }
    }
    if (b == 0 && t == 0) offs[0] = 0;
}

__global__ void scatter_kernel(const int* __restrict__ rows, const int* __restrict__ cols,
                               int* __restrict__ cursor,
                               int* __restrict__ perm, int* __restrict__ colp, int E) {
    int e = blockIdx.x * blockDim.x + threadIdx.x;
    if (e < E) {
        int p = atomicAdd(&cursor[rows[e]], 1);
        perm[p] = e;
        colp[p] = cols[e];
    }
}

__global__ void rowfill_kernel(const int* __restrict__ offs, int* __restrict__ rowp, int N) {
    int n = blockIdx.x * blockDim.x + threadIdx.x;
    if (n < N) {
        const int b = offs[n], e = offs[n + 1];
        for (int i = b; i < e; i++) rowp[i] = n;
    }
}

// ------------------------------------------- fallback kernels (atomic path) ---
template<int BLK>
__global__ __launch_bounds__(BLK)
void edge_atomic_kernel(const float* __restrict__ h, const float* __restrict__ x,
                 const float* __restrict__ eattr,
                 const int* __restrict__ rows, const int* __restrict__ cols,
                 const float* __restrict__ we_w1, const float* __restrict__ we_b1,
                 const float* __restrict__ we_w2, const float* __restrict__ we_b2,
                 const float* __restrict__ wx_w1, const float* __restrict__ wx_b1,
                 const float* __restrict__ wx_w2, const float* __restrict__ wx_b2,
                 float* __restrict__ agg, float* __restrict__ cnt, float* __restrict__ mi,
                 int E)
{
    __shared__ float act[64][BLK];
    const int tid = threadIdx.x;
    const int e = blockIdx.x * BLK + tid;
    if (e >= E) return;

    const int r = rows[e];
    const int c = cols[e];
    const float d0 = x[(size_t)r*3+0] - x[(size_t)c*3+0];
    const float d1 = x[(size_t)r*3+1] - x[(size_t)c*3+1];
    const float d2 = x[(size_t)r*3+2] - x[(size_t)c*3+2];
    const float rad = d0*d0 + d1*d1 + d2*d2;

    float A[64];
    #pragma unroll
    for (int j = 0; j < 64; j++) A[j] = we_b1[j];
    const float* hr = h + (size_t)r * 64;
    const float* hc = h + (size_t)c * 64;
    #pragma unroll 4
    for (int k = 0; k < 64; k++) {
        const float a0 = hr[k];
        const float a1 = hc[k];
        const float* w0 = we_w1 + k * 64;
        const float* w1 = we_w1 + (64 + k) * 64;
        #pragma unroll
        for (int j = 0; j < 64; j++) A[j] += a0 * w0[j] + a1 * w1[j];
    }
    {
        const float* w = we_w1 + 128 * 64;
        #pragma unroll
        for (int j = 0; j < 64; j++) A[j] += rad * w[j];
    }
    const float* ea = eattr + (size_t)e * 8;
    #pragma unroll
    for (int k = 0; k < 8; k++) {
        const float a = ea[k];
        const float* w = we_w1 + (129 + k) * 64;
        #pragma unroll
        for (int j = 0; j < 64; j++) A[j] += a * w[j];
    }
    #pragma unroll
    for (int j = 0; j < 64; j++) act[j][tid] = fast_tanh(A[j]);

    float B[64];
    #pragma unroll
    for (int j = 0; j < 64; j++) B[j] = we_b2[j];
    #pragma unroll 4
    for (int k = 0; k < 64; k++) {
        const float a = act[k][tid];
        const float* w = we_w2 + k * 64;
        #pragma unroll
        for (int j = 0; j < 64; j++) B[j] += a * w[j];
    }
    #pragma unroll
    for (int j = 0; j < 64; j++) act[j][tid] = fast_tanh(B[j]);

    #pragma unroll
    for (int j = 0; j < 64; j++) A[j] = wx_b1[j];
    #pragma unroll 4
    for (int k = 0; k < 64; k++) {
        const float a = act[k][tid];
        const float* w = wx_w1 + k * 64;
        #pragma unroll
        for (int j = 0; j < 64; j++) A[j] += a * w[j];
    }
    float px = wx_b2[0];
    #pragma unroll
    for (int j = 0; j < 64; j++) px += fast_tanh(A[j]) * wx_w2[j];
    px = fast_tanh(px);

    atomicAdd(&agg[(size_t)r*3+0], d0 * px);
    atomicAdd(&agg[(size_t)r*3+1], d1 * px);
    atomicAdd(&agg[(size_t)r*3+2], d2 * px);
    atomicAdd(&cnt[r], 1.0f);
    float* mir = mi + (size_t)r * 64;
    #pragma unroll
    for (int j = 0; j < 64; j++) atomicAdd(&mir[j], act[j][tid]);
}

template<int BLK>
__global__ __launch_bounds__(BLK, 2)
void node_fb_kernel(const float* __restrict__ h, const float* __restrict__ x,
                 const float* __restrict__ vel,
                 const float* __restrict__ wh_w1, const float* __restrict__ wh_b1,
                 const float* __restrict__ wh_w2, const float* __restrict__ wh_b2,
                 const float* __restrict__ wv_w1, const float* __restrict__ wv_b1,
                 const float* __restrict__ wv_w2, const float* __restrict__ wv_b2,
                 const float* __restrict__ agg, const float* __restrict__ cnt,
                 const float* __restrict__ mi,
                 float* __restrict__ out_h, float* __restrict__ out_x, float* __restrict__ out_v,
                 int N)
{
    const int n = blockIdx.x * BLK + threadIdx.x;
    if (n >= N) return;

    const float* hn = h + (size_t)n * 64;
    const float* mn = mi + (size_t)n * 64;

    float A[64];
    #pragma unroll
    for (int j = 0; j < 64; j++) A[j] = wv_b1[j];
    #pragma unroll
    for (int k = 0; k < 64; k++) {
        const float a = hn[k];
        const float* w = wv_w1 + k * 64;
        #pragma unroll
        for (int j = 0; j < 64; j++) A[j] += a * w[j];
    }
    float pv = wv_b2[0];
    #pragma unroll
    for (int j = 0; j < 64; j++) pv += fast_tanh(A[j]) * wv_w2[j];

    #pragma unroll
    for (int j = 0; j < 64; j++) A[j] = wh_b1[j];
    #pragma unroll
    for (int k = 0; k < 64; k++) {
        const float a0 = hn[k];
        const float a1 = mn[k];
        const float* w0 = wh_w1 + k * 64;
        const float* w1 = wh_w1 + (64 + k) * 64;
        #pragma unroll
        for (int j = 0; j < 64; j++) A[j] += a0 * w0[j] + a1 * w1[j];
    }
    #pragma unroll
    for (int j = 0; j < 64; j++) A[j] = fast_tanh(A[j]);

    float B[64];
    #pragma unroll
    for (int j = 0; j < 64; j++) B[j] = wh_b2[j];
    #pragma unroll
    for (int k = 0; k < 64; k++) {
        const float a = A[k];
        const float* w = wh_w2 + k * 64;
        #pragma unroll
        for (int j = 0; j < 64; j++) B[j] += a * w[j];
    }
    float* oh = out_h + (size_t)n * 64;
    #pragma unroll
    for (int j = 0; j < 64; j++) oh[j] = B[j];

    const float inv = 1.0f / fmaxf(cnt[n], 1.0f);
    #pragma unroll
    for (int d = 0; d < 3; d++) {
        const float am = agg[(size_t)n*3 + d] * inv;
        const float vn = vel[(size_t)n*3 + d] * pv + am;
        out_v[(size_t)n*3 + d] = vn;
        out_x[(size_t)n*3 + d] = x[(size_t)n*3 + d] + vn;
    }
}

// ------------------------------------------------------------------ launch ---
extern "C" void kernel_launch(void* const* d_in, const int* in_sizes, int n_in,
                              void* d_out, int out_size, void* d_ws, size_t ws_size,
                              hipStream_t stream) {
    const float* h      = (const float*)d_in[0];
    const float* x      = (const float*)d_in[1];
    const float* vel    = (const float*)d_in[2];
    const float* eattr  = (const float*)d_in[3];
    const float* we_w1  = (const float*)d_in[4];
    const float* we_b1  = (const float*)d_in[5];
    const float* we_w2  = (const float*)d_in[6];
    const float* we_b2  = (const float*)d_in[7];
    const float* wx_w1  = (const float*)d_in[8];
    const float* wx_b1  = (const float*)d_in[9];
    const float* wx_w2  = (const float*)d_in[10];
    const float* wx_b2  = (const float*)d_in[11];
    const float* wh_w1  = (const float*)d_in[12];
    const float* wh_b1  = (const float*)d_in[13];
    const float* wh_w2  = (const float*)d_in[14];
    const float* wh_b2  = (const float*)d_in[15];
    const float* wv_w1  = (const float*)d_in[16];
    const float* wv_b1  = (const float*)d_in[17];
    const float* wv_w2  = (const float*)d_in[18];
    const float* wv_b2  = (const float*)d_in[19];
    const int*   ar     = (const int*)d_in[20];

    const int N = in_sizes[0] / 64;
    const int E = in_sizes[20] / 2;
    const int* rows = ar;
    const int* cols = ar + E;

    float* out_h = (float*)d_out;            // N*64 (HrB/HcB bf16 scratch first)
    float* out_x = out_h + (size_t)N * 64;   // N*3
    float* out_v = out_x + (size_t)N * 3;    // N*3

    u16* HrB = (u16*)d_out;
    u16* HcB = HrB + (size_t)N * 64;

    const int nbScan = (N + 1023) / 1024;

    // --- workspace layout: ~48 MB. miF..hist contiguous -> ONE memset ---
    char* p = (char*)d_ws;
    float* miF  = (float*)p; p += (size_t)N * 64 * sizeof(float);
    float* aggF = (float*)p; p += (size_t)N * 3 * sizeof(float);
    float* cntF = (float*)p; p += (size_t)N * sizeof(float);
    int*  hist  = (int*)p;   p += (size_t)N * sizeof(int);
    const size_t zero_bytes = (size_t)(p - (char*)d_ws);
    int*  offs  = (int*)p;   p += (size_t)(N + 1) * sizeof(int);
    int*  cursor= (int*)p;   p += (size_t)N * sizeof(int);
    int*  bsum  = (int*)p;   p += (size_t)(nbScan > 0 ? nbScan : 1) * sizeof(int);
    int*  perm  = (int*)p;   p += (size_t)E * sizeof(int);
    int*  rowp  = (int*)p;   p += (size_t)E * sizeof(int);
    int*  colp  = (int*)p;   p += (size_t)E * sizeof(int);
    p = (char*)(((uintptr_t)p + 63) & ~(uintptr_t)63);
    u16*  we1t = (u16*)p;   p += 64 * 128 * sizeof(u16);
    u16*  we2t = (u16*)p;   p += 64 * 64 * sizeof(u16);
    u16*  wx1t = (u16*)p;   p += 64 * 64 * sizeof(u16);
    u16*  wv1t = (u16*)p;   p += 64 * 64 * sizeof(u16);
    u16*  wh1t = (u16*)p;   p += 64 * 128 * sizeof(u16);
    u16*  wh2t = (u16*)p;   p += 64 * 64 * sizeof(u16);
    u16*  wert = (u16*)p;   p += 64 * 32 * sizeof(u16);
    const size_t needed = (size_t)(p - (char*)d_ws);

    if (ws_size >= needed && nbScan <= 1024) {
        hipMemsetAsync(d_ws, 0, zero_bytes, stream);
        hist_kernel<<<(E + 255) / 256, 256, 0, stream>>>(rows, hist, E);
        scan1_kernel<<<nbScan, 256, 0, stream>>>(hist, bsum, N);
        scan2_kernel<<<1, 256, 0, stream>>>(bsum, nbScan);
        scan3_kernel<<<nbScan, 256, 0, stream>>>(hist, bsum, offs, cursor, N);
        scatter_kernel<<<(E + 255) / 256, 256, 0, stream>>>(rows, cols, cursor, perm, colp, E);
        rowfill_kernel<<<(N + 255) / 256, 256, 0, stream>>>(offs, rowp, N);

        wprep_kernel<<<32, 256, 0, stream>>>(we_w1, we_w2, wx_w1, wv_w1, wh_w1, wh_w2,
                                             we1t, we2t, wx1t, wv1t, wh1t, wh2t, wert);
        pre_mfma_kernel<<<(N + 63) / 64, 256, 0, stream>>>(h, we_b1, we1t, HrB, HcB, N);

        edge_mfma_kernel<<<(E + 63) / 64, 256, 0, stream>>>(
            x, eattr, perm, rowp, colp, HrB, HcB,
            wert, we2t, we_b2, wx1t, wx_b1, wx_w2, wx_b2,
            miF, aggF, cntF, E);

        aggnode_kernel<<<(N + 63) / 64, 256, 0, stream>>>(
            h, x, vel, miF, aggF, cntF,
            wv1t, wv_b1, wv_w2, wv_b2,
            wh1t, wh_b1, wh2t, wh_b2,
            out_h, out_x, out_v, N);
    } else {
        // --- fallback: atomic path ---
        float* agg2 = (float*)d_ws;               // N*3
        float* cnt2 = agg2 + (size_t)N * 3;       // N
        float* mi2  = cnt2 + N;                   // N*64
        hipMemsetAsync(d_ws, 0, (size_t)N * 68 * sizeof(float), stream);

        edge_atomic_kernel<128><<<(E + 127) / 128, 128, 0, stream>>>(
            h, x, eattr, rows, cols,
            we_w1, we_b1, we_w2, we_b2,
            wx_w1, wx_b1, wx_w2, wx_b2,
            agg2, cnt2, mi2, E);

        node_fb_kernel<128><<<(N + 127) / 128, 128, 0, stream>>>(
            h, x, vel,
            wh_w1, wh_b1, wh_w2, wh_b2,
            wv_w1, wv_b1, wv_w2, wv_b2,
            agg2, cnt2, mi2, out_h, out_x, out_v, N);
    }
}

// Round 10
// 551.977 us; speedup vs baseline: 11.3720x; 1.0485x over previous
//
#include <hip/hip_runtime.h>

// EGNN layer (CamadaEquivariante), round 10:
//  - edge_mfma: single in-place LDS tile T (Xp -> X1 -> X2), 2 barriers,
//    radS reuse, rc int2 loads, occupancy 8 blocks/CU.  [r9 logic, restructured]
//  - scatter writes rc=(r,c) int2 + perm; rowfill/rowp deleted.
//  - pre_mfma / aggnode / CSR scan unchanged from r9 (known-good).
// ws ~= 48 MB. Fallback to atomic path if ws too small.

typedef unsigned int uint;
typedef unsigned short u16;
typedef __attribute__((ext_vector_type(8))) short short8;
typedef __attribute__((ext_vector_type(4))) float f32x4;

#define UB_LO(u) __uint_as_float((u) << 16)
#define UB_HI(u) __uint_as_float((u) & 0xffff0000u)

__device__ __forceinline__ float fast_tanh(float x) {
    float e = __expf(2.0f * x);
    return 1.0f - 2.0f * __builtin_amdgcn_rcpf(e + 1.0f);
}
__device__ __forceinline__ u16 bf16rne(float f) {
    uint u = __float_as_uint(f);
    return (u16)((u + 0x7fffu + ((u >> 16) & 1u)) >> 16);
}
__device__ __forceinline__ uint packbf(float a, float b) {
    return (uint)bf16rne(a) | ((uint)bf16rne(b) << 16);
}
// 1-inst truncating bf16x2 pack: lo16 = hi16(a), hi16 = hi16(b)
__device__ __forceinline__ uint packbf_fast(float a, float b) {
    return __builtin_amdgcn_perm(__float_as_uint(b), __float_as_uint(a), 0x07060302u);
}
__device__ __forceinline__ u16 trunc16(float f) {
    return (u16)(__float_as_uint(f) >> 16);
}
// XOR-swizzle within a [64][64]-bf16 (128B-row) LDS tile: byte ^= ((row&7)<<4)
__device__ __forceinline__ int swzb(int b) { return b ^ ((b >> 3) & 0x70); }

// ------------------------------------------------- weight transpose (bf16) ---
__global__ void wprep_kernel(const float* __restrict__ we_w1, const float* __restrict__ we_w2,
                             const float* __restrict__ wx_w1, const float* __restrict__ wv_w1,
                             const float* __restrict__ wh_w1, const float* __restrict__ wh_w2,
                             u16* __restrict__ we1t, u16* __restrict__ we2t,
                             u16* __restrict__ wx1t, u16* __restrict__ wv1t,
                             u16* __restrict__ wh1t, u16* __restrict__ wh2t,
                             u16* __restrict__ wert) {
    int t = blockIdx.x * 256 + threadIdx.x;
    if (t < 8192) {
        int j = t >> 7, k = t & 127;
        we1t[t] = bf16rne(we_w1[k * 64 + j]);
        wh1t[t] = bf16rne(wh_w1[k * 64 + j]);
    }
    if (t < 4096) {
        int n = t >> 6, k = t & 63;
        we2t[t] = bf16rne(we_w2[k * 64 + n]);
        wx1t[t] = bf16rne(wx_w1[k * 64 + n]);
        wv1t[t] = bf16rne(wv_w1[k * 64 + n]);
        wh2t[t] = bf16rne(wh_w2[k * 64 + n]);
    }
    if (t < 2048) {          // wert[n][k], k=0 -> rad row (128), k=1..8 -> rows 129..136
        int n = t >> 5, k = t & 31;
        float v = 0.0f;
        if (k == 0) v = we_w1[128 * 64 + n];
        else if (k <= 8) v = we_w1[(128 + k) * 64 + n];
        wert[t] = bf16rne(v);
    }
}

// --------------------------------------------------------- pre MFMA kernel ---
__global__ __launch_bounds__(256, 2)
void pre_mfma_kernel(const float* __restrict__ h, const float* __restrict__ we_b1,
                     const u16* __restrict__ we1t,
                     u16* __restrict__ HrB, u16* __restrict__ HcB, int N)
{
    __shared__ u16 X1[4096];
    __shared__ u16 X2[4096];
    const int tid = threadIdx.x, lane = tid & 63, wv = tid >> 6;
    const int nb = blockIdx.x * 64;
    const int el = tid >> 2, jg = tid & 3;
    const int fn = lane & 15, fk8 = (lane >> 4) * 8;

    {
        uint pk[8];
        if (nb + el < N) {
            const float4* h4 = (const float4*)(h + (size_t)(nb + el) * 64 + jg * 16);
            #pragma unroll
            for (int q = 0; q < 4; q++) {
                float4 v = h4[q];
                pk[2*q]   = packbf_fast(v.x, v.y);
                pk[2*q+1] = packbf_fast(v.z, v.w);
            }
        } else {
            #pragma unroll
            for (int q = 0; q < 8; q++) pk[q] = 0;
        }
        const int b0 = swzb(el * 128 + jg * 32), b1 = swzb(el * 128 + jg * 32 + 16);
        *(uint4*)(&X1[b0 >> 1]) = make_uint4(pk[0], pk[1], pk[2], pk[3]);
        *(uint4*)(&X1[b1 >> 1]) = make_uint4(pk[4], pk[5], pk[6], pk[7]);
    }
    __syncthreads();

    const int mb = wv * 16;
    short8 a0, a1;
    {
        const int ba = swzb((mb + fn) * 128 + fk8 * 2);
        const int bb = swzb((mb + fn) * 128 + 64 + fk8 * 2);
        a0 = *(const short8*)(&X1[ba >> 1]);
        a1 = *(const short8*)(&X1[bb >> 1]);
    }
    // Hr = h @ We1[0:64] + b1
    #pragma unroll
    for (int n0 = 0; n0 < 4; n0++) {
        uint4 bw0 = *(const uint4*)(we1t + (n0*16 + fn) * 128 + fk8);
        uint4 bw1 = *(const uint4*)(we1t + (n0*16 + fn) * 128 + 32 + fk8);
        const float bias = we_b1[n0 * 16 + fn];
        f32x4 q = {bias, bias, bias, bias};
        q = __builtin_amdgcn_mfma_f32_16x16x32_bf16(a0, __builtin_bit_cast(short8, bw0), q, 0, 0, 0);
        q = __builtin_amdgcn_mfma_f32_16x16x32_bf16(a1, __builtin_bit_cast(short8, bw1), q, 0, 0, 0);
        #pragma unroll
        for (int r2 = 0; r2 < 4; r2++) {
            const int m = mb + (lane >> 4) * 4 + r2;
            X2[swzb(m * 128 + (n0*16 + fn) * 2) >> 1] = bf16rne(q[r2]);
        }
    }
    __syncthreads();
    if (nb + el < N) {
        const int b0 = swzb(el * 128 + jg * 32), b1 = swzb(el * 128 + jg * 32 + 16);
        uint4 v0 = *(const uint4*)(&X2[b0 >> 1]);
        uint4 v1 = *(const uint4*)(&X2[b1 >> 1]);
        u16* o = HrB + (size_t)(nb + el) * 64 + jg * 16;
        *(uint4*)o = v0; *(uint4*)(o + 8) = v1;
    }
    __syncthreads();
    // Hc = h @ We1[64:128]
    #pragma unroll
    for (int n0 = 0; n0 < 4; n0++) {
        uint4 bw0 = *(const uint4*)(we1t + (n0*16 + fn) * 128 + 64 + fk8);
        uint4 bw1 = *(const uint4*)(we1t + (n0*16 + fn) * 128 + 96 + fk8);
        f32x4 q = {0.f, 0.f, 0.f, 0.f};
        q = __builtin_amdgcn_mfma_f32_16x16x32_bf16(a0, __builtin_bit_cast(short8, bw0), q, 0, 0, 0);
        q = __builtin_amdgcn_mfma_f32_16x16x32_bf16(a1, __builtin_bit_cast(short8, bw1), q, 0, 0, 0);
        #pragma unroll
        for (int r2 = 0; r2 < 4; r2++) {
            const int m = mb + (lane >> 4) * 4 + r2;
            X2[swzb(m * 128 + (n0*16 + fn) * 2) >> 1] = bf16rne(q[r2]);
        }
    }
    __syncthreads();
    if (nb + el < N) {
        const int b0 = swzb(el * 128 + jg * 32), b1 = swzb(el * 128 + jg * 32 + 16);
        uint4 v0 = *(const uint4*)(&X2[b0 >> 1]);
        uint4 v1 = *(const uint4*)(&X2[b1 >> 1]);
        u16* o = HcB + (size_t)(nb + el) * 64 + jg * 16;
        *(uint4*)o = v0; *(uint4*)(o + 8) = v1;
    }
}

// --------------------------------------------------------- edge MFMA kernel ---
// Slot order + XCD-chunked swizzle. Single in-place tile T: Xp -> X1 -> X2.
// Band ownership: each wave's MFMA frag reads/writes touch only rows
// [wv*16, wv*16+16); cross-wave accesses only at phase A (write) and
// segment-sum (read) -> exactly 2 barriers.
__global__ __launch_bounds__(256, 8)
void edge_mfma_kernel(const float* __restrict__ x, const float* __restrict__ eattr,
                      const int* __restrict__ perm, const int2* __restrict__ rc,
                      const u16* __restrict__ HrB, const u16* __restrict__ HcB,
                      const u16* __restrict__ wert,
                      const u16* __restrict__ we2t, const float* __restrict__ we_b2,
                      const u16* __restrict__ wx1t, const float* __restrict__ wx_b1,
                      const float* __restrict__ wx_w2, const float* __restrict__ wx_b2,
                      float* __restrict__ miF, float* __restrict__ aggF,
                      float* __restrict__ cntF, int E)
{
    __shared__ u16 T[4096];        // Xp -> X1 -> X2 (in place)
    __shared__ float dS[64][3];
    __shared__ float pxS[64];
    __shared__ float radS[64];
    __shared__ int rS[64];

    const int tid = threadIdx.x, lane = tid & 63, wv = tid >> 6;
    int bid = blockIdx.x;
    const int nwg = gridDim.x;
    if ((nwg & 7) == 0) bid = (bid & 7) * (nwg >> 3) + (bid >> 3);  // XCD-chunked
    const int sb = bid * 64;
    const int fn = lane & 15, fk8 = (lane >> 4) * 8;
    const int el = tid >> 2, jg = tid & 3;
    const int s = sb + el;
    const int mb = wv * 16;

    // ---- phase A: T = Hr[r] + Hc[c] (bf16); dS/radS/rS ----
    {
        int r = -1, c = 0;
        if (s < E) { int2 p2 = rc[s]; r = p2.x; c = p2.y; }
        if (jg == 0) rS[el] = r;
        uint pk[8];
        if (s < E) {
            if (jg == 0) {
                const float d0 = x[(size_t)r*3+0] - x[(size_t)c*3+0];
                const float d1 = x[(size_t)r*3+1] - x[(size_t)c*3+1];
                const float d2 = x[(size_t)r*3+2] - x[(size_t)c*3+2];
                dS[el][0] = d0; dS[el][1] = d1; dS[el][2] = d2;
                radS[el] = d0*d0 + d1*d1 + d2*d2;
            }
            uint4 ra = *(const uint4*)(HrB + (size_t)r * 64 + jg * 16);
            uint4 rb = *(const uint4*)(HrB + (size_t)r * 64 + jg * 16 + 8);
            uint4 ca = *(const uint4*)(HcB + (size_t)c * 64 + jg * 16);
            uint4 cb = *(const uint4*)(HcB + (size_t)c * 64 + jg * 16 + 8);
            uint rw[8] = {ra.x, ra.y, ra.z, ra.w, rb.x, rb.y, rb.z, rb.w};
            uint cw[8] = {ca.x, ca.y, ca.z, ca.w, cb.x, cb.y, cb.z, cb.w};
            #pragma unroll
            for (int q = 0; q < 8; q++) {
                const float lo = UB_LO(rw[q]) + UB_LO(cw[q]);
                const float hi = UB_HI(rw[q]) + UB_HI(cw[q]);
                pk[q] = packbf_fast(lo, hi);
            }
        } else {
            #pragma unroll
            for (int q = 0; q < 8; q++) pk[q] = 0;
        }
        const int b0 = swzb(el * 128 + jg * 32), b1 = swzb(el * 128 + jg * 32 + 16);
        *(uint4*)(&T[b0 >> 1]) = make_uint4(pk[0], pk[1], pk[2], pk[3]);
        *(uint4*)(&T[b1 >> 1]) = make_uint4(pk[4], pk[5], pk[6], pk[7]);
    }
    __syncthreads();   // barrier 1: T(Xp)/dS/radS/rS visible

    // ---- ea/rad A-frag: lane fn = edge (mb+fn), k-chunk = lane>>4 ----
    uint ae[4] = {0, 0, 0, 0};
    {
        const int kc = lane >> 4;
        const int s2 = sb + mb + fn;
        if (kc < 2 && s2 < E) {
            const int e2 = perm[s2];
            const float4* ea4 = (const float4*)(eattr + (size_t)e2 * 8);
            if (kc == 0) {
                float4 u0 = ea4[0], u1 = ea4[1];
                const float rad = radS[mb + fn];
                ae[0] = packbf_fast(rad,  u0.x);   // k0=rad, k1=ea0
                ae[1] = packbf_fast(u0.y, u0.z);   // ea1, ea2
                ae[2] = packbf_fast(u0.w, u1.x);   // ea3, ea4
                ae[3] = packbf_fast(u1.y, u1.z);   // ea5, ea6
            } else {
                float4 u1 = ea4[1];
                ae[0] = packbf_fast(u1.w, 0.0f);   // k8=ea7
            }
        }
    }
    const short8 a_e = __builtin_bit_cast(short8, *(uint4*)ae);

    // ---- layer 1 (in place): q = MFMA(ea, wert); T = tanh(q + T) ----
    #pragma unroll
    for (int n0 = 0; n0 < 4; n0++) {
        uint4 bw = *(const uint4*)(wert + (n0*16 + fn) * 32 + fk8);
        f32x4 q = {0.f, 0.f, 0.f, 0.f};
        q = __builtin_amdgcn_mfma_f32_16x16x32_bf16(a_e, __builtin_bit_cast(short8, bw), q, 0, 0, 0);
        #pragma unroll
        for (int r2 = 0; r2 < 4; r2++) {
            const int idx = swzb((mb + (lane >> 4) * 4 + r2) * 128 + (n0*16 + fn) * 2) >> 1;
            const float pre = q[r2] + UB_LO((uint)T[idx]);
            T[idx] = trunc16(fast_tanh(pre));
        }
    }

    // ---- layer 2 (in place): read own-band frags, write X2 over X1 ----
    short8 a0, a1;
    {
        const int ba = swzb((mb + fn) * 128 + fk8 * 2);
        const int bb = swzb((mb + fn) * 128 + 64 + fk8 * 2);
        a0 = *(const short8*)(&T[ba >> 1]);
        a1 = *(const short8*)(&T[bb >> 1]);
    }
    #pragma unroll
    for (int n0 = 0; n0 < 4; n0++) {
        uint4 bw0 = *(const uint4*)(we2t + (n0*16 + fn) * 64 + fk8);
        uint4 bw1 = *(const uint4*)(we2t + (n0*16 + fn) * 64 + 32 + fk8);
        const float bias = we_b2[n0 * 16 + fn];
        f32x4 q = {bias, bias, bias, bias};
        q = __builtin_amdgcn_mfma_f32_16x16x32_bf16(a0, __builtin_bit_cast(short8, bw0), q, 0, 0, 0);
        q = __builtin_amdgcn_mfma_f32_16x16x32_bf16(a1, __builtin_bit_cast(short8, bw1), q, 0, 0, 0);
        #pragma unroll
        for (int r2 = 0; r2 < 4; r2++) {
            const int m = mb + (lane >> 4) * 4 + r2;
            T[swzb(m * 128 + (n0*16 + fn) * 2) >> 1] = bf16rne(fast_tanh(q[r2]));
        }
    }

    // ---- phi_x: S = X2 @ Wx1 + b1; px = tanh(tanh(S) @ wx2 + b2) ----
    short8 c0, c1;
    {
        const int ba = swzb((mb + fn) * 128 + fk8 * 2);
        const int bb = swzb((mb + fn) * 128 + 64 + fk8 * 2);
        c0 = *(const short8*)(&T[ba >> 1]);
        c1 = *(const short8*)(&T[bb >> 1]);
    }
    float pxp[4] = {0.f, 0.f, 0.f, 0.f};
    #pragma unroll
    for (int n0 = 0; n0 < 4; n0++) {
        uint4 bw0 = *(const uint4*)(wx1t + (n0*16 + fn) * 64 + fk8);
        uint4 bw1 = *(const uint4*)(wx1t + (n0*16 + fn) * 64 + 32 + fk8);
        const float bias = wx_b1[n0 * 16 + fn];
        f32x4 q = {bias, bias, bias, bias};
        q = __builtin_amdgcn_mfma_f32_16x16x32_bf16(c0, __builtin_bit_cast(short8, bw0), q, 0, 0, 0);
        q = __builtin_amdgcn_mfma_f32_16x16x32_bf16(c1, __builtin_bit_cast(short8, bw1), q, 0, 0, 0);
        const float wqn = wx_w2[n0 * 16 + fn];
        #pragma unroll
        for (int r2 = 0; r2 < 4; r2++) pxp[r2] += fast_tanh(q[r2]) * wqn;
    }
    #pragma unroll
    for (int off = 1; off < 16; off <<= 1) {
        #pragma unroll
        for (int r2 = 0; r2 < 4; r2++) pxp[r2] += __shfl_xor(pxp[r2], off, 64);
    }
    if (fn == 0) {
        const float bx2 = wx_b2[0];
        #pragma unroll
        for (int r2 = 0; r2 < 4; r2++) {
            const int m = mb + (lane >> 4) * 4 + r2;
            pxS[m] = fast_tanh(pxp[r2] + bx2);
        }
    }
    __syncthreads();   // barrier 2: T(X2)/pxS complete for cross-wave read

    // ---- fused segment sum: wave w owns segments STARTING in [w*16, w*16+16) ----
    const int w16 = wv * 16;
    for (int s0 = w16; s0 < w16 + 16; s0++) {
        const int r0 = rS[s0];
        if (r0 < 0) continue;
        if (s0 > 0 && rS[s0 - 1] == r0) continue;   // not a segment start
        int s1 = s0 + 1;
        while (s1 < 64 && rS[s1] == r0) s1++;
        float msum = 0.0f, tsum = 0.0f;
        for (int t = s0; t < s1; t++) {
            msum += UB_LO((uint)T[swzb(t * 128 + lane * 2) >> 1]);
            if (lane < 3) tsum += dS[t][lane] * pxS[t];
        }
        atomicAdd(&miF[(size_t)r0 * 64 + lane], msum);
        if (lane < 3) atomicAdd(&aggF[(size_t)r0 * 3 + lane], tsum);
        if (lane == 3) atomicAdd(&cntF[r0], (float)(s1 - s0));
    }
}

// ---------------------------------------------- fused aggregation + node MLP ---
__global__ __launch_bounds__(256, 2)
void aggnode_kernel(const float* __restrict__ h, const float* __restrict__ x,
                    const float* __restrict__ vel,
                    const float* __restrict__ miF, const float* __restrict__ aggF,
                    const float* __restrict__ cntF,
                    const u16* __restrict__ wv1t, const float* __restrict__ wv_b1,
                    const float* __restrict__ wv_w2, const float* __restrict__ wv_b2,
                    const u16* __restrict__ wh1t, const float* __restrict__ wh_b1,
                    const u16* __restrict__ wh2t, const float* __restrict__ wh_b2,
                    float* __restrict__ out_h, float* __restrict__ out_x,
                    float* __restrict__ out_v, int N)
{
    __shared__ u16 Xh[4096];      // h tile, bf16 swizzled
    __shared__ u16 Xm[4096];      // mi tile, then reused for act tile
    __shared__ float aggM[64][3];
    __shared__ float pvS[64];

    const int tid = threadIdx.x, lane = tid & 63, wv = tid >> 6;
    const int nb = blockIdx.x * 64;
    const int el = tid >> 2, jg = tid & 3;
    const int fn = lane & 15, fk8 = (lane >> 4) * 8;

    // ---- stage h tile ----
    {
        uint pk[8];
        if (nb + el < N) {
            const float4* h4 = (const float4*)(h + (size_t)(nb + el) * 64 + jg * 16);
            #pragma unroll
            for (int q = 0; q < 4; q++) {
                float4 v = h4[q];
                pk[2*q]   = packbf_fast(v.x, v.y);
                pk[2*q+1] = packbf_fast(v.z, v.w);
            }
        } else {
            #pragma unroll
            for (int q = 0; q < 8; q++) pk[q] = 0;
        }
        const int b0 = swzb(el * 128 + jg * 32), b1 = swzb(el * 128 + jg * 32 + 16);
        *(uint4*)(&Xh[b0 >> 1]) = make_uint4(pk[0], pk[1], pk[2], pk[3]);
        *(uint4*)(&Xh[b1 >> 1]) = make_uint4(pk[4], pk[5], pk[6], pk[7]);
    }

    // ---- stage mi tile from miF (coalesced f32) + agg means ----
    for (int t = 0; t < 16; t++) {
        const int ln = wv * 16 + t;
        const int n = nb + ln;
        float val = 0.0f;
        if (n < N) val = miF[(size_t)n * 64 + lane];
        Xm[swzb(ln * 128 + lane * 2) >> 1] = bf16rne(val);
        if (lane < 3 && n < N) {
            const float cf = cntF[n];
            aggM[ln][lane] = aggF[(size_t)n * 3 + lane] / fmaxf(cf, 1.0f);
        }
    }
    __syncthreads();

    // ---- frag loads ----
    const int mb = wv * 16;
    short8 a0, a1, b0, b1;
    {
        const int ba = swzb((mb + fn) * 128 + fk8 * 2);
        const int bb = swzb((mb + fn) * 128 + 64 + fk8 * 2);
        a0 = *(const short8*)(&Xh[ba >> 1]);
        a1 = *(const short8*)(&Xh[bb >> 1]);
        b0 = *(const short8*)(&Xm[ba >> 1]);
        b1 = *(const short8*)(&Xm[bb >> 1]);
    }

    // ---- phi_v ----
    float pvp[4] = {0.f, 0.f, 0.f, 0.f};
    #pragma unroll
    for (int n0 = 0; n0 < 4; n0++) {
        uint4 bw0 = *(const uint4*)(wv1t + (n0*16 + fn) * 64 + fk8);
        uint4 bw1 = *(const uint4*)(wv1t + (n0*16 + fn) * 64 + 32 + fk8);
        const float bias = wv_b1[n0 * 16 + fn];
        f32x4 q = {bias, bias, bias, bias};
        q = __builtin_amdgcn_mfma_f32_16x16x32_bf16(a0, __builtin_bit_cast(short8, bw0), q, 0, 0, 0);
        q = __builtin_amdgcn_mfma_f32_16x16x32_bf16(a1, __builtin_bit_cast(short8, bw1), q, 0, 0, 0);
        const float wqn = wv_w2[n0 * 16 + fn];
        #pragma unroll
        for (int r2 = 0; r2 < 4; r2++) pvp[r2] += fast_tanh(q[r2]) * wqn;
    }
    #pragma unroll
    for (int off = 1; off < 16; off <<= 1) {
        #pragma unroll
        for (int r2 = 0; r2 < 4; r2++) pvp[r2] += __shfl_xor(pvp[r2], off, 64);
    }
    if (fn == 0) {
        const float bv2 = wv_b2[0];
        #pragma unroll
        for (int r2 = 0; r2 < 4; r2++) pvS[mb + (lane >> 4) * 4 + r2] = pvp[r2] + bv2;
    }
    __syncthreads();   // all frag loads done; Xm may now be overwritten

    // ---- phi_h layer 1 (K=128: [h | mi]) -> act tile (into Xm region) ----
    #pragma unroll
    for (int n0 = 0; n0 < 4; n0++) {
        const u16* base = wh1t + (n0*16 + fn) * 128;
        uint4 bw0 = *(const uint4*)(base + fk8);
        uint4 bw1 = *(const uint4*)(base + 32 + fk8);
        uint4 bw2 = *(const uint4*)(base + 64 + fk8);
        uint4 bw3 = *(const uint4*)(base + 96 + fk8);
        const float bias = wh_b1[n0 * 16 + fn];
        f32x4 q = {bias, bias, bias, bias};
        q = __builtin_amdgcn_mfma_f32_16x16x32_bf16(a0, __builtin_bit_cast(short8, bw0), q, 0, 0, 0);
        q = __builtin_amdgcn_mfma_f32_16x16x32_bf16(a1, __builtin_bit_cast(short8, bw1), q, 0, 0, 0);
        q = __builtin_amdgcn_mfma_f32_16x16x32_bf16(b0, __builtin_bit_cast(short8, bw2), q, 0, 0, 0);
        q = __builtin_amdgcn_mfma_f32_16x16x32_bf16(b1, __builtin_bit_cast(short8, bw3), q, 0, 0, 0);
        #pragma unroll
        for (int r2 = 0; r2 < 4; r2++) {
            const int m = mb + (lane >> 4) * 4 + r2;
            Xm[swzb(m * 128 + (n0*16 + fn) * 2) >> 1] = bf16rne(fast_tanh(q[r2]));
        }
    }
    __syncthreads();

    // ---- phi_h layer 2 -> out_h ----
    short8 c0, c1;
    {
        const int ba = swzb((mb + fn) * 128 + fk8 * 2);
        const int bb = swzb((mb + fn) * 128 + 64 + fk8 * 2);
        c0 = *(const short8*)(&Xm[ba >> 1]);
        c1 = *(const short8*)(&Xm[bb >> 1]);
    }
    #pragma unroll
    for (int n0 = 0; n0 < 4; n0++) {
        uint4 bw0 = *(const uint4*)(wh2t + (n0*16 + fn) * 64 + fk8);
        uint4 bw1 = *(const uint4*)(wh2t + (n0*16 + fn) * 64 + 32 + fk8);
        const float bias = wh_b2[n0 * 16 + fn];
        f32x4 q = {bias, bias, bias, bias};
        q = __builtin_amdgcn_mfma_f32_16x16x32_bf16(c0, __builtin_bit_cast(short8, bw0), q, 0, 0, 0);
        q = __builtin_amdgcn_mfma_f32_16x16x32_bf16(c1, __builtin_bit_cast(short8, bw1), q, 0, 0, 0);
        #pragma unroll
        for (int r2 = 0; r2 < 4; r2++) {
            const int m = mb + (lane >> 4) * 4 + r2;
            if (nb + m < N) out_h[(size_t)(nb + m) * 64 + n0 * 16 + fn] = q[r2];
        }
    }

    // ---- coordinate / velocity update ----
    if (tid < 64 && nb + tid < N) {
        const int n = nb + tid;
        const float pv = pvS[tid];
        #pragma unroll
        for (int d = 0; d < 3; d++) {
            const float am = aggM[tid][d];
            const float vn = vel[(size_t)n * 3 + d] * pv + am;
            out_v[(size_t)n * 3 + d] = vn;
            out_x[(size_t)n * 3 + d] = x[(size_t)n * 3 + d] + vn;
        }
    }
}

// ---------------------------------------------------------------- CSR build ---
__global__ void hist_kernel(const int* __restrict__ rows, int* __restrict__ hist, int E) {
    int e = blockIdx.x * blockDim.x + threadIdx.x;
    if (e < E) atomicAdd(&hist[rows[e]], 1);
}

__global__ __launch_bounds__(256)
void scan1_kernel(const int* __restrict__ hist, int* __restrict__ bsum, int N) {
    const int t = threadIdx.x, b = blockIdx.x;
    const int base = b * 1024 + t * 4;
    int s = 0;
    #pragma unroll
    for (int q = 0; q < 4; q++) s += (base + q < N) ? hist[base + q] : 0;
    #pragma unroll
    for (int off = 1; off < 64; off <<= 1) s += __shfl_xor(s, off, 64);
    __shared__ int ws[4];
    if ((t & 63) == 0) ws[t >> 6] = s;
    __syncthreads();
    if (t == 0) bsum[b] = ws[0] + ws[1] + ws[2] + ws[3];
}

__global__ __launch_bounds__(256)
void scan2_kernel(int* __restrict__ bsum, int nb) {
    __shared__ int buf[1024];
    const int t = threadIdx.x;
    for (int i = t; i < nb; i += 256) buf[i] = bsum[i];
    __syncthreads();
    if (t == 0) {
        int run = 0;
        for (int i = 0; i < nb; i++) { int v = buf[i]; buf[i] = run; run += v; }
    }
    __syncthreads();
    for (int i = t; i < nb; i += 256) bsum[i] = buf[i];
}

__global__ __launch_bounds__(256)
void scan3_kernel(const int* __restrict__ hist, const int* __restrict__ bbase,
                  int* __restrict__ offs, int* __restrict__ cursor, int N) {
    const int t = threadIdx.x, b = blockIdx.x;
    const int base = b * 1024 + t * 4;
    int v[4];
    #pragma unroll
    for (int q = 0; q < 4; q++) v[q] = (base + q < N) ? hist[base + q] : 0;
    const int s = v[0] + v[1] + v[2] + v[3];
    const int lane = t & 63, wid = t >> 6;
    int inc = s;
    #pragma unroll
    for (int off = 1; off < 64; off <<= 1) {
        int u = __shfl_up(inc, off, 64);
        if (lane >= off) inc += u;
    }
    __shared__ int wtot[4];
    if (lane == 63) wtot[wid] = inc;
    __syncthreads();
    int wbase = 0;
    #pragma unroll
    for (int wq = 0; wq < 3; wq++) if (wq < wid) wbase += wtot[wq];
    int run = bbase[b] + wbase + (inc - s);
    #pragma unroll
    for (int q = 0; q < 4; q++) {
        const int i = base + q;
        if (i < N) { cursor[i] = run; run += v[q]; offs[i + 1] = run; }
    }
    if (b == 0 && t == 0) offs[0] = 0;
}

// scatter: rc[slot]=(r,c) single 8B scatter + perm[slot]=e
__global__ void scatter_kernel(const int* __restrict__ rows, const int* __restrict__ cols,
                               int* __restrict__ cursor,
                               int* __restrict__ perm, int2* __restrict__ rc, int E) {
    int e = blockIdx.x * blockDim.x + threadIdx.x;
    if (e < E) {
        int r = rows[e];
        int p = atomicAdd(&cursor[r], 1);
        perm[p] = e;
        rc[p] = make_int2(r, cols[e]);
    }
}

// ------------------------------------------- fallback kernels (atomic path) ---
template<int BLK>
__global__ __launch_bounds__(BLK)
void edge_atomic_kernel(const float* __restrict__ h, const float* __restrict__ x,
                 const float* __restrict__ eattr,
                 const int* __restrict__ rows, const int* __restrict__ cols,
                 const float* __restrict__ we_w1, const float* __restrict__ we_b1,
                 const float* __restrict__ we_w2, const float* __restrict__ we_b2,
                 const float* __restrict__ wx_w1, const float* __restrict__ wx_b1,
                 const float* __restrict__ wx_w2, const float* __restrict__ wx_b2,
                 float* __restrict__ agg, float* __restrict__ cnt, float* __restrict__ mi,
                 int E)
{
    __shared__ float act[64][BLK];
    const int tid = threadIdx.x;
    const int e = blockIdx.x * BLK + tid;
    if (e >= E) return;

    const int r = rows[e];
    const int c = cols[e];
    const float d0 = x[(size_t)r*3+0] - x[(size_t)c*3+0];
    const float d1 = x[(size_t)r*3+1] - x[(size_t)c*3+1];
    const float d2 = x[(size_t)r*3+2] - x[(size_t)c*3+2];
    const float rad = d0*d0 + d1*d1 + d2*d2;

    float A[64];
    #pragma unroll
    for (int j = 0; j < 64; j++) A[j] = we_b1[j];
    const float* hr = h + (size_t)r * 64;
    const float* hc = h + (size_t)c * 64;
    #pragma unroll 4
    for (int k = 0; k < 64; k++) {
        const float a0 = hr[k];
        const float a1 = hc[k];
        const float* w0 = we_w1 + k * 64;
        const float* w1 = we_w1 + (64 + k) * 64;
        #pragma unroll
        for (int j = 0; j < 64; j++) A[j] += a0 * w0[j] + a1 * w1[j];
    }
    {
        const float* w = we_w1 + 128 * 64;
        #pragma unroll
        for (int j = 0; j < 64; j++) A[j] += rad * w[j];
    }
    const float* ea = eattr + (size_t)e * 8;
    #pragma unroll
    for (int k = 0; k < 8; k++) {
        const float a = ea[k];
        const float* w = we_w1 + (129 + k) * 64;
        #pragma unroll
        for (int j = 0; j < 64; j++) A[j] += a * w[j];
    }
    #pragma unroll
    for (int j = 0; j < 64; j++) act[j][tid] = fast_tanh(A[j]);

    float B[64];
    #pragma unroll
    for (int j = 0; j < 64; j++) B[j] = we_b2[j];
    #pragma unroll 4
    for (int k = 0; k < 64; k++) {
        const float a = act[k][tid];
        const float* w = we_w2 + k * 64;
        #pragma unroll
        for (int j = 0; j < 64; j++) B[j] += a * w[j];
    }
    #pragma unroll
    for (int j = 0; j < 64; j++) act[j][tid] = fast_tanh(B[j]);

    #pragma unroll
    for (int j = 0; j < 64; j++) A[j] = wx_b1[j];
    #pragma unroll 4
    for (int k = 0; k < 64; k++) {
        const float a = act[k][tid];
        const float* w = wx_w1 + k * 64;
        #pragma unroll
        for (int j = 0; j < 64; j++) A[j] += a * w[j];
    }
    float px = wx_b2[0];
    #pragma unroll
    for (int j = 0; j < 64; j++) px += fast_tanh(A[j]) * wx_w2[j];
    px = fast_tanh(px);

    atomicAdd(&agg[(size_t)r*3+0], d0 * px);
    atomicAdd(&agg[(size_t)r*3+1], d1 * px);
    atomicAdd(&agg[(size_t)r*3+2], d2 * px);
    atomicAdd(&cnt[r], 1.0f);
    float* mir = mi + (size_t)r * 64;
    #pragma unroll
    for (int j = 0; j < 64; j++) atomicAdd(&mir[j], act[j][tid]);
}

template<int BLK>
__global__ __launch_bounds__(BLK, 2)
void node_fb_kernel(const float* __restrict__ h, const float* __restrict__ x,
                 const float* __restrict__ vel,
                 const float* __restrict__ wh_w1, const float* __restrict__ wh_b1,
                 const float* __restrict__ wh_w2, const float* __restrict__ wh_b2,
                 const float* __restrict__ wv_w1, const float* __restrict__ wv_b1,
                 const float* __restrict__ wv_w2, const float* __restrict__ wv_b2,
                 const float* __restrict__ agg, const float* __restrict__ cnt,
                 const float* __restrict__ mi,
                 float* __restrict__ out_h, float* __restrict__ out_x, float* __restrict__ out_v,
                 int N)
{
    const int n = blockIdx.x * BLK + threadIdx.x;
    if (n >= N) return;

    const float* hn = h + (size_t)n * 64;
    const float* mn = mi + (size_t)n * 64;

    float A[64];
    #pragma unroll
    for (int j = 0; j < 64; j++) A[j] = wv_b1[j];
    #pragma unroll
    for (int k = 0; k < 64; k++) {
        const float a = hn[k];
        const float* w = wv_w1 + k * 64;
        #pragma unroll
        for (int j = 0; j < 64; j++) A[j] += a * w[j];
    }
    float pv = wv_b2[0];
    #pragma unroll
    for (int j = 0; j < 64; j++) pv += fast_tanh(A[j]) * wv_w2[j];

    #pragma unroll
    for (int j = 0; j < 64; j++) A[j] = wh_b1[j];
    #pragma unroll
    for (int k = 0; k < 64; k++) {
        const float a0 = hn[k];
        const float a1 = mn[k];
        const float* w0 = wh_w1 + k * 64;
        const float* w1 = wh_w1 + (64 + k) * 64;
        #pragma unroll
        for (int j = 0; j < 64; j++) A[j] += a0 * w0[j] + a1 * w1[j];
    }
    #pragma unroll
    for (int j = 0; j < 64; j++) A[j] = fast_tanh(A[j]);

    float B[64];
    #pragma unroll
    for (int j = 0; j < 64; j++) B[j] = wh_b2[j];
    #pragma unroll
    for (int k = 0; k < 64; k++) {
        const float a = A[k];
        const float* w = wh_w2 + k * 64;
        #pragma unroll
        for (int j = 0; j < 64; j++) B[j] += a * w[j];
    }
    float* oh = out_h + (size_t)n * 64;
    #pragma unroll
    for (int j = 0; j < 64; j++) oh[j] = B[j];

    const float inv = 1.0f / fmaxf(cnt[n], 1.0f);
    #pragma unroll
    for (int d = 0; d < 3; d++) {
        const float am = agg[(size_t)n*3 + d] * inv;
        const float vn = vel[(size_t)n*3 + d] * pv + am;
        out_v[(size_t)n*3 + d] = vn;
        out_x[(size_t)n*3 + d] = x[(size_t)n*3 + d] + vn;
    }
}

// ------------------------------------------------------------------ launch ---
extern "C" void kernel_launch(void* const* d_in, const int* in_sizes, int n_in,
                              void* d_out, int out_size, void* d_ws, size_t ws_size,
                              hipStream_t stream) {
    const float* h      = (const float*)d_in[0];
    const float* x      = (const float*)d_in[1];
    const float* vel    = (const float*)d_in[2];
    const float* eattr  = (const float*)d_in[3];
    const float* we_w1  = (const float*)d_in[4];
    const float* we_b1  = (const float*)d_in[5];
    const float* we_w2  = (const float*)d_in[6];
    const float* we_b2  = (const float*)d_in[7];
    const float* wx_w1  = (const float*)d_in[8];
    const float* wx_b1  = (const float*)d_in[9];
    const float* wx_w2  = (const float*)d_in[10];
    const float* wx_b2  = (const float*)d_in[11];
    const float* wh_w1  = (const float*)d_in[12];
    const float* wh_b1  = (const float*)d_in[13];
    const float* wh_w2  = (const float*)d_in[14];
    const float* wh_b2  = (const float*)d_in[15];
    const float* wv_w1  = (const float*)d_in[16];
    const float* wv_b1  = (const float*)d_in[17];
    const float* wv_w2  = (const float*)d_in[18];
    const float* wv_b2  = (const float*)d_in[19];
    const int*   ar     = (const int*)d_in[20];

    const int N = in_sizes[0] / 64;
    const int E = in_sizes[20] / 2;
    const int* rows = ar;
    const int* cols = ar + E;

    float* out_h = (float*)d_out;            // N*64 (HrB/HcB bf16 scratch first)
    float* out_x = out_h + (size_t)N * 64;   // N*3
    float* out_v = out_x + (size_t)N * 3;    // N*3

    u16* HrB = (u16*)d_out;
    u16* HcB = HrB + (size_t)N * 64;

    const int nbScan = (N + 1023) / 1024;

    // --- workspace layout: ~48 MB. miF..hist contiguous -> ONE memset ---
    char* p = (char*)d_ws;
    float* miF  = (float*)p; p += (size_t)N * 64 * sizeof(float);
    float* aggF = (float*)p; p += (size_t)N * 3 * sizeof(float);
    float* cntF = (float*)p; p += (size_t)N * sizeof(float);
    int*  hist  = (int*)p;   p += (size_t)N * sizeof(int);
    const size_t zero_bytes = (size_t)(p - (char*)d_ws);
    int*  offs  = (int*)p;   p += (size_t)(N + 1) * sizeof(int);
    int*  cursor= (int*)p;   p += (size_t)N * sizeof(int);
    int*  bsum  = (int*)p;   p += (size_t)(nbScan > 0 ? nbScan : 1) * sizeof(int);
    int*  perm  = (int*)p;   p += (size_t)E * sizeof(int);
    p = (char*)(((uintptr_t)p + 7) & ~(uintptr_t)7);
    int2* rc    = (int2*)p;  p += (size_t)E * sizeof(int2);
    p = (char*)(((uintptr_t)p + 63) & ~(uintptr_t)63);
    u16*  we1t = (u16*)p;   p += 64 * 128 * sizeof(u16);
    u16*  we2t = (u16*)p;   p += 64 * 64 * sizeof(u16);
    u16*  wx1t = (u16*)p;   p += 64 * 64 * sizeof(u16);
    u16*  wv1t = (u16*)p;   p += 64 * 64 * sizeof(u16);
    u16*  wh1t = (u16*)p;   p += 64 * 128 * sizeof(u16);
    u16*  wh2t = (u16*)p;   p += 64 * 64 * sizeof(u16);
    u16*  wert = (u16*)p;   p += 64 * 32 * sizeof(u16);
    const size_t needed = (size_t)(p - (char*)d_ws);

    if (ws_size >= needed && nbScan <= 1024) {
        hipMemsetAsync(d_ws, 0, zero_bytes, stream);
        hist_kernel<<<(E + 255) / 256, 256, 0, stream>>>(rows, hist, E);
        scan1_kernel<<<nbScan, 256, 0, stream>>>(hist, bsum, N);
        scan2_kernel<<<1, 256, 0, stream>>>(bsum, nbScan);
        scan3_kernel<<<nbScan, 256, 0, stream>>>(hist, bsum, offs, cursor, N);
        scatter_kernel<<<(E + 255) / 256, 256, 0, stream>>>(rows, cols, cursor, perm, rc, E);

        wprep_kernel<<<32, 256, 0, stream>>>(we_w1, we_w2, wx_w1, wv_w1, wh_w1, wh_w2,
                                             we1t, we2t, wx1t, wv1t, wh1t, wh2t, wert);
        pre_mfma_kernel<<<(N + 63) / 64, 256, 0, stream>>>(h, we_b1, we1t, HrB, HcB, N);

        edge_mfma_kernel<<<(E + 63) / 64, 256, 0, stream>>>(
            x, eattr, perm, rc, HrB, HcB,
            wert, we2t, we_b2, wx1t, wx_b1, wx_w2, wx_b2,
            miF, aggF, cntF, E);

        aggnode_kernel<<<(N + 63) / 64, 256, 0, stream>>>(
            h, x, vel, miF, aggF, cntF,
            wv1t, wv_b1, wv_w2, wv_b2,
            wh1t, wh_b1, wh2t, wh_b2,
            out_h, out_x, out_v, N);
    } else {
        // --- fallback: atomic path ---
        float* agg2 = (float*)d_ws;               // N*3
        float* cnt2 = agg2 + (size_t)N * 3;       // N
        float* mi2  = cnt2 + N;                   // N*64
        hipMemsetAsync(d_ws, 0, (size_t)N * 68 * sizeof(float), stream);

        edge_atomic_kernel<128><<<(E + 127) / 128, 128, 0, stream>>>(
            h, x, eattr, rows, cols,
            we_w1, we_b1, we_w2, we_b2,
            wx_w1, wx_b1, wx_w2, wx_b2,
            agg2, cnt2, mi2, E);

        node_fb_kernel<128><<<(N + 127) / 128, 128, 0, stream>>>(
            h, x, vel,
            wh_w1, wh_b1, wh_w2, wh_b2,
            wv_w1, wv_b1, wv_w2, wv_b2,
            agg2, cnt2, mi2, out_h, out_x, out_v, N);
    }
}